// Round 17
// baseline (471.889 us; speedup 1.0000x reference)
//
#include <hip/hip_runtime.h>

#define F1 62400
#define O1 800
#define O2N 100
#define TT 300
#define BB 2
#define NWRD 975        /* 64-bit f-words */
#define KSRM 77
#define KREF 11
#define MB 25           /* M-blocks of 32 o */
#define NPAD 640        /* n = b*320 + t */
#define NDIG 4          /* base-256 digits of rint(w1 * 2^31) — exact (R4-proven) */
#define KSPL 10         /* k-splits */
#define WPS 98          /* words per split (last split: 93) */
#define ASTRIDE ((size_t)MB * NDIG * 2048)
#define BSTRIDE ((size_t)NPAD * 4)

typedef unsigned long long u64;
typedef int i32x4 __attribute__((ext_vector_type(4)));

/* ---- ws layout (bytes); NEED ~218.8 MB (proven available) ---- */
#define OFF_CONST 0ull
#define OFF_Z1I  1024ull
#define OFF_S1T  (OFF_Z1I + 4096000ull)
#define OFF_XBW  (OFF_S1T + 1920000ull)          /* 975*640*8 (320-stride, pad stored 0) */
#define OFF_Z1F  (OFF_XBW + 4992000ull)
#define OFF_U1   (OFF_Z1F + 3840000ull)
#define OFF_U2   (OFF_U1 + 3840000ull)
#define OFF_AQ   (OFF_U2 + 480000ull)            /* 975*25*4*2048 = 199,680,000 */
#define NEED_SPARSE (OFF_AQ + 199680000ull)

#define GLOAD_LDS16(g, s) __builtin_amdgcn_global_load_lds( \
    (const __attribute__((address_space(1))) unsigned int*)(g), \
    (__attribute__((address_space(3))) unsigned int*)(s), 16, 0, 0)

/* K0: SRM/REF kernels, fp64 rounded through fp32 (matches np.float32). */
__global__ void k0_init(double* c) {
    int k = threadIdx.x;
    if (k < KSRM) {
        double v = ((double)k / 10.0) * exp(1.0 - (double)k / 10.0);
        c[k] = (double)(float)v;
    }
    if (k < KREF) {
        double v = -20.0 * (double)k * exp(1.0 - (double)k);
        c[80 + k] = (double)(float)v;
    }
}

/* K1: bitmask xbw[w][b*320+t]: bit j = (x[b][w*64+j][t] > 0.5). Pad t -> 0. */
__global__ __launch_bounds__(256) void k1_xbw(const float* __restrict__ x,
                                              u64* __restrict__ xbw) {
    const int NTG = 5;
    int gw = (blockIdx.x * 256 + threadIdx.x) >> 6;
    int lane = threadIdx.x & 63;
    if (gw >= BB * NWRD * NTG) return;
    int b  = gw / (NWRD * NTG);
    int r  = gw % (NWRD * NTG);
    int fw = r / NTG;
    int tg = r % NTG;
    int t = tg * 64 + lane;
    bool act = (t < TT);
    int tc = act ? t : 0;
    const float* xp = x + ((size_t)(b * F1 + (fw << 6))) * TT + tc;
    unsigned lo = 0, hi = 0;
    #pragma unroll
    for (int j = 0; j < 32; ++j)
        lo |= (xp[(size_t)j * TT] > 0.5f ? 1u : 0u) << j;
    #pragma unroll
    for (int j = 0; j < 32; ++j)
        hi |= (xp[(size_t)(j + 32) * TT] > 0.5f ? 1u : 0u) << j;
    u64 mval = act ? (((u64)hi << 32) | lo) : 0ull;
    xbw[(size_t)fw * NPAD + b * 320 + t] = mval;
}

/* K_QA: quantize all w1 words -> 4 digit planes (scale 2^31, exact), lane-
   linear fragment order (conflict-free ds_read_b128 in k3m2). */
__global__ __launch_bounds__(256) void k_qa(const float* __restrict__ w1,
                                            char* __restrict__ aq) {
    int tid = blockIdx.x * 256 + threadIdx.x;
    if (tid >= NWRD * 3200) return;
    int kc = tid & 3;
    int o  = (tid >> 2) & 31;
    int m  = (tid >> 7) % MB;
    int wl = tid / 3200;
    const float* src = w1 + (size_t)(m * 32 + o) * F1 + (size_t)wl * 64 + kc * 16;
    unsigned dw[NDIG][4];
    #pragma unroll
    for (int g = 0; g < 4; ++g) {
        float4 f4 = *(const float4*)(src + g * 4);
        float ff[4] = {f4.x, f4.y, f4.z, f4.w};
        unsigned w0 = 0, w1_ = 0, w2 = 0, w3 = 0;
        #pragma unroll
        for (int e = 0; e < 4; ++e) {
            int v = (int)rint((double)ff[e] * 2147483648.0);   /* 2^31, exact */
            int d0 = (v << 24) >> 24;  int v1 = (v - d0) >> 8;
            int d1 = (v1 << 24) >> 24; int v2 = (v1 - d1) >> 8;
            int d2 = (v2 << 24) >> 24; int d3 = (v2 - d2) >> 8;
            w0 |= (unsigned)(d0 & 0xFF) << (8 * e);
            w1_ |= (unsigned)(d1 & 0xFF) << (8 * e);
            w2 |= (unsigned)(d2 & 0xFF) << (8 * e);
            w3 |= (unsigned)(d3 & 0xFF) << (8 * e);
        }
        dw[0][g] = w0; dw[1][g] = w1_; dw[2][g] = w2; dw[3][g] = w3;
    }
    char* dst = aq + (((size_t)wl * MB + m) * NDIG) * 2048
                + (o >> 4) * 1024 + (size_t)(kc * 16 + (o & 15)) * 16;
    #pragma unroll
    for (int d = 0; d < NDIG; ++d)
        *(i32x4*)(dst + (size_t)d * 2048) =
            (i32x4){(int)dw[d][0], (int)dw[d][1], (int)dw[d][2], (int)dw[d][3]};
}

/* unpack 16 mask bits -> 16 i8 (R4-verified byte order) + 4 digit MFMAs */
#define K3_COMPUTE(A0, A1, A2, A3, BV, TTI)                                        \
    {                                                                              \
        i32x4 bf;                                                                  \
        _Pragma("unroll")                                                          \
        for (int i_ = 0; i_ < 4; ++i_)                                             \
            bf[i_] = (int)((((BV >> (4 * i_)) & 0xFu) * 0x00204081u) & 0x01010101u); \
        acc[TTI][0] = __builtin_amdgcn_mfma_i32_16x16x64_i8(A0, bf, acc[TTI][0], 0, 0, 0); \
        acc[TTI][1] = __builtin_amdgcn_mfma_i32_16x16x64_i8(A1, bf, acc[TTI][1], 0, 0, 0); \
        acc[TTI][2] = __builtin_amdgcn_mfma_i32_16x16x64_i8(A2, bf, acc[TTI][2], 0, 0, 0); \
        acc[TTI][3] = __builtin_amdgcn_mfma_i32_16x16x64_i8(A3, bf, acc[TTI][3], 0, 0, 0); \
    }

/* issue DMA (A tile -> slot) + 5 B loads for step PF (clamped) */
#define K3_ISSUE(PF, SLOT, R0, R1, R2, R3, R4)                                     \
    {                                                                              \
        int pf_ = (PF); if (pf_ > steps - 1) pf_ = steps - 1;                      \
        GLOAD_LDS16(abase + (size_t)pf_ * ASTRIDE, &Abuf[(SLOT)][tid * 16]);       \
        const unsigned short* bq_ = bp0 + (size_t)pf_ * BSTRIDE;                   \
        R0 = bq_[0]; R1 = bq_[64]; R2 = bq_[128]; R3 = bq_[192]; R4 = bq_[256];    \
    }

/* one pipeline stage: wait step S's 6 ops (leave 12 in flight), barrier,
   consume buffer S&3 + B regs, then issue step S+3 into the same regs. */
#define K3_BODY(S, R0, R1, R2, R3, R4)                                             \
    {                                                                              \
        __builtin_amdgcn_sched_barrier(0);                                         \
        asm volatile("s_waitcnt vmcnt(12)" ::: "memory");                          \
        __builtin_amdgcn_s_barrier();                                              \
        __builtin_amdgcn_sched_barrier(0);                                         \
        const char* lp_ = &Abuf[(S) & 3][0] + lofs;                                \
        i32x4 a0 = *(const i32x4*)(lp_);                                           \
        i32x4 a1 = *(const i32x4*)(lp_ + 2048);                                    \
        i32x4 a2 = *(const i32x4*)(lp_ + 4096);                                    \
        i32x4 a3 = *(const i32x4*)(lp_ + 6144);                                    \
        unsigned v0_ = R0, v1_ = R1, v2_ = R2, v3_ = R3, v4_ = R4;                 \
        K3_ISSUE((S) + 3, ((S) + 3) & 3, R0, R1, R2, R3, R4)                       \
        if ((S) < steps) {                                                         \
            K3_COMPUTE(a0, a1, a2, a3, v0_, 0)                                     \
            K3_COMPUTE(a0, a1, a2, a3, v1_, 1)                                     \
            K3_COMPUTE(a0, a1, a2, a3, v2_, 2)                                     \
            K3_COMPUTE(a0, a1, a2, a3, v3_, 3)                                     \
            K3_COMPUTE(a0, a1, a2, a3, v4_, 4)                                     \
        }                                                                          \
    }

/* K3M2: exact i8 MFMA GEMM; A via 4-buffer global_load_lds pipeline with
   counted vmcnt (3 steps in flight, never drained to 0 in the loop); B via
   3-deep role-named register prefetch. Lane-linear conflict-free LDS reads. */
__global__ __launch_bounds__(512, 2) void k3m2(const char* __restrict__ aq,
                                               const u64* __restrict__ xbw,
                                               u64* __restrict__ z1i) {
    __shared__ __align__(16) char Abuf[4][8192];
    int m = blockIdx.x >> 1, nh = blockIdx.x & 1, ksl = blockIdx.y;
    int tid = threadIdx.x;
    int l = tid & 63, wid = tid >> 6;
    int q = wid & 3, oh = wid >> 2;

    int wl0 = ksl * WPS;
    int wend = wl0 + WPS; if (wend > NWRD) wend = NWRD;
    int steps = wend - wl0;          /* 98 or 93 */

    i32x4 acc[5][NDIG];
    #pragma unroll
    for (int i = 0; i < 5; ++i)
        #pragma unroll
        for (int d = 0; d < NDIG; ++d) acc[i][d] = (i32x4){0, 0, 0, 0};

    const char* abase = aq + (((size_t)wl0 * MB + m) * NDIG) * 2048 + (size_t)tid * 16;
    const unsigned short* bp0 =
        (const unsigned short*)((const char*)xbw
            + ((size_t)wl0 * NPAD
               + (size_t)(nh * 320 + q * 80 + (l & 15))) * 8
            + (l >> 4) * 2);
    const int lofs = oh * 1024 + l * 16;

    unsigned bA0, bA1, bA2, bA3, bA4;
    unsigned bB0, bB1, bB2, bB3, bB4;
    unsigned bC0, bC1, bC2, bC3, bC4;

    /* prologue: fill 3 pipeline stages (18 vmem ops in flight) */
    K3_ISSUE(0, 0, bA0, bA1, bA2, bA3, bA4)
    K3_ISSUE(1, 1, bB0, bB1, bB2, bB3, bB4)
    K3_ISSUE(2, 2, bC0, bC1, bC2, bC3, bC4)

    int smax3 = ((steps + 2) / 3) * 3;
    #pragma unroll 1
    for (int sb = 0; sb < smax3; sb += 3) {
        K3_BODY(sb,     bA0, bA1, bA2, bA3, bA4)
        K3_BODY(sb + 1, bB0, bB1, bB2, bB3, bB4)
        K3_BODY(sb + 2, bC0, bC1, bC2, bC3, bC4)
    }
    asm volatile("s_waitcnt vmcnt(0)" ::: "memory");

    #pragma unroll
    for (int tt = 0; tt < 5; ++tt) {
        int n = nh * 320 + q * 80 + tt * 16 + (l & 15);
        #pragma unroll
        for (int r = 0; r < 4; ++r) {
            int o = oh * 16 + (l >> 4) * 4 + r;
            long long c = (long long)acc[tt][0][r]
                        + ((long long)acc[tt][1][r] << 8)
                        + ((long long)acc[tt][2][r] << 16)
                        + ((long long)acc[tt][3][r] << 24);
            atomicAdd(&z1i[(size_t)(m * 32 + o) * NPAD + n], (u64)c);
        }
    }
}

/* dense fallback GEMM1 (used only if ws too small) -> z1f fp64 */
__global__ __launch_bounds__(256) void k_dense_gemm1(const float* __restrict__ x,
                                                     const float* __restrict__ w1,
                                                     double* __restrict__ z1) {
    int lin = blockIdx.x;
    int ot = lin % 25; int tt = (lin / 25) % 5; int b = lin / 125;
    int t0 = tt * 64, o0 = ot * 32;
    __shared__ float xs[64][64];
    __shared__ float wsh[32][64];
    int ti = threadIdx.x & 63, og = threadIdx.x >> 6;
    double dacc[8] = {0, 0, 0, 0, 0, 0, 0, 0};
    for (int fc = 0; fc < F1; fc += 64) {
        __syncthreads();
        for (int e = threadIdx.x; e < 64 * 64; e += 256) {
            int r = e >> 6, c = e & 63;
            int t = t0 + c;
            xs[r][c] = (t < TT) ? x[((size_t)b * F1 + fc + r) * TT + t] : 0.0f;
        }
        for (int e = threadIdx.x; e < 32 * 64; e += 256) {
            int r = e >> 6, c = e & 63;
            wsh[r][c] = w1[(size_t)(o0 + r) * F1 + fc + c];
        }
        __syncthreads();
        float facc[8] = {0, 0, 0, 0, 0, 0, 0, 0};
        for (int ff = 0; ff < 64; ++ff) {
            float xv = xs[ff][ti];
            #pragma unroll
            for (int oo = 0; oo < 8; ++oo) facc[oo] += wsh[og * 8 + oo][ff] * xv;
        }
        #pragma unroll
        for (int oo = 0; oo < 8; ++oo) dacc[oo] += (double)facc[oo];
    }
    int t = t0 + ti;
    if (t < TT) {
        #pragma unroll
        for (int oo = 0; oo < 8; ++oo) {
            int o = o0 + og * 8 + oo;
            z1[((size_t)(b * O1 + o)) * TT + t] = dacc[oo];
        }
    }
}

/* K_CONV1: scale + psp conv for layer 1 (t-parallel, per-row block). */
__global__ __launch_bounds__(320) void k_conv1(const u64* __restrict__ z1i,
                                               const double* __restrict__ z1f,
                                               double* __restrict__ u1,
                                               const double* __restrict__ cst,
                                               int mode) {
    __shared__ double zs[TT];
    __shared__ double ck[KSRM];
    int row = blockIdx.x;
    int b = row / O1, o = row % O1;
    int t = threadIdx.x;
    if (t < KSRM) ck[t] = cst[t];
    if (t < TT) {
        double z;
        if (mode == 0)
            z = (double)(long long)z1i[(size_t)o * NPAD + b * 320 + t]
                * 4.656612873077393e-10;                    /* 2^-31 */
        else
            z = z1f[(size_t)row * TT + t];
        zs[t] = z;
    }
    __syncthreads();
    if (t < TT) {
        int kmax = t < (KSRM - 1) ? t : (KSRM - 1);
        double acc = 0.0;
        for (int k = 0; k <= kmax; ++k) acc += ck[k] * zs[t - k];
        u1[(size_t)row * TT + t] = acc;
    }
}

/* K_SCAN: thread-per-row spike scan, branch-free cndmask chains with
   tree-summed refractory term (fp64 reassoc ~1e-14 << spike margin). */
__global__ __launch_bounds__(64) void k_scan(const double* __restrict__ u,
                                             float* __restrict__ s,
                                             const double* __restrict__ cst,
                                             int nrows) {
    int row = blockIdx.x * 64 + threadIdx.x;
    if (row >= nrows) return;
    double rk1 = cst[81], rk2 = cst[82], rk3 = cst[83], rk4 = cst[84];
    double rk5 = cst[85], rk6 = cst[86], rk7 = cst[87], rk8 = cst[88];
    double rk9 = cst[89], rk10 = cst[90];
    const double* ur = u + (size_t)row * TT;
    float* sr = s + (size_t)row * TT;
    unsigned h = 0;
    #pragma unroll 4
    for (int t = 0; t < TT; ++t) {
        double a  = ((h & 1u)   ? rk1 : 0.0) + ((h & 2u)   ? rk2  : 0.0);
        double b2 = ((h & 4u)   ? rk3 : 0.0) + ((h & 8u)   ? rk4  : 0.0);
        double c2 = ((h & 16u)  ? rk5 : 0.0) + ((h & 32u)  ? rk6  : 0.0);
        double d2 = ((h & 64u)  ? rk7 : 0.0) + ((h & 128u) ? rk8  : 0.0);
        double e2 = ((h & 256u) ? rk9 : 0.0) + ((h & 512u) ? rk10 : 0.0);
        double ueff = ur[t] + (((a + b2) + (c2 + d2)) + e2);
        unsigned sp = (ueff >= 10.0) ? 1u : 0u;
        sr[t] = (float)sp;
        h = (h << 1) | sp;
    }
}

/* K_GEMM2C: fused GEMM2 + psp conv for layer 2 (both t-parallel). */
__global__ __launch_bounds__(320) void k_gemm2c(const float* __restrict__ s1t,
                                                const float* __restrict__ w2,
                                                double* __restrict__ u2,
                                                const double* __restrict__ cst) {
    __shared__ float wsm[O1];
    __shared__ double zs[TT];
    __shared__ double ck[KSRM];
    int bo = blockIdx.x;
    int b = bo / O2N, o2 = bo % O2N;
    int t = threadIdx.x;
    if (t < KSRM) ck[t] = cst[t];
    for (int f = t; f < O1; f += 320) wsm[f] = w2[(size_t)o2 * O1 + f];
    __syncthreads();
    if (t < TT) {
        double acc = 0.0;
        #pragma unroll 4
        for (int f = 0; f < O1; ++f)
            acc += (double)(wsm[f] * s1t[((size_t)(b * O1 + f)) * TT + t]);
        zs[t] = acc;
    }
    __syncthreads();
    if (t < TT) {
        int kmax = t < (KSRM - 1) ? t : (KSRM - 1);
        double acc = 0.0;
        for (int k = 0; k <= kmax; ++k) acc += ck[k] * zs[t - k];
        u2[(size_t)bo * TT + t] = acc;
    }
}

extern "C" void kernel_launch(void* const* d_in, const int* in_sizes, int n_in,
                              void* d_out, int out_size, void* d_ws, size_t ws_size,
                              hipStream_t stream) {
    const float* x  = (const float*)d_in[0];
    const float* w1 = (const float*)d_in[1];
    const float* w2 = (const float*)d_in[2];
    float* out = (float*)d_out;
    char* ws = (char*)d_ws;

    double* cst = (double*)(ws + OFF_CONST);
    u64*    z1i = (u64*)   (ws + OFF_Z1I);
    float*  s1t = (float*) (ws + OFF_S1T);
    u64*    xbw = (u64*)   (ws + OFF_XBW);
    double* z1f = (double*)(ws + OFF_Z1F);
    double* u1  = (double*)(ws + OFF_U1);
    double* u2  = (double*)(ws + OFF_U2);
    char*   aq  = (char*)  (ws + OFF_AQ);

    k0_init<<<1, 128, 0, stream>>>(cst);

    int mode;
    if (ws_size >= NEED_SPARSE) {
        mode = 0;
        int b1 = (BB * NWRD * 5 * 64 + 255) / 256;
        k1_xbw<<<b1, 256, 0, stream>>>(x, xbw);
        hipMemsetAsync(z1i, 0, (size_t)O1 * NPAD * 8, stream);
        k_qa<<<(NWRD * 3200 + 255) / 256, 256, 0, stream>>>(w1, aq);
        k3m2<<<dim3(2 * MB, KSPL), 512, 0, stream>>>(aq, xbw, z1i);
    } else {
        mode = 1;
        k_dense_gemm1<<<250, 256, 0, stream>>>(x, w1, z1f);
    }

    k_conv1<<<BB * O1, 320, 0, stream>>>(z1i, z1f, u1, cst, mode);
    k_scan<<<(BB * O1 + 63) / 64, 64, 0, stream>>>(u1, s1t, cst, BB * O1);
    k_gemm2c<<<BB * O2N, 320, 0, stream>>>(s1t, w2, u2, cst);
    k_scan<<<(BB * O2N + 63) / 64, 64, 0, stream>>>(u2, out, cst, BB * O2N);
    (void)in_sizes; (void)n_in; (void)out_size;
}

// Round 18
// 415.172 us; speedup vs baseline: 1.1366x; 1.1366x over previous
//
#include <hip/hip_runtime.h>

#define F1 62400
#define O1 800
#define O2N 100
#define TT 300
#define BB 2
#define NWRD 975        /* 64-bit f-words */
#define KSRM 77
#define KREF 11
#define MB 25           /* M-blocks of 32 o */
#define NPAD 640        /* n = b*320 + t */
#define NDIG 4          /* base-256 digits of rint(w1 * 2^31) — exact (R4-proven) */
#define KSPL 16         /* k-splits (800 blocks ~ 3.1/CU) */
#define WPS 61          /* words per split (last split: 60) */
#define ASTRIDE ((size_t)MB * NDIG * 2048)
#define BSTRIDE ((size_t)NPAD * 4)

/* k_pre grid partition */
#define NB_K1 2438      /* ceil(2*975*5*64 / 256) */
#define NB_QA 12188     /* ceil(975*3200 / 256) */
#define NB_Z  1000      /* 512000 u64 / (256*2) */

typedef unsigned long long u64;
typedef int i32x4 __attribute__((ext_vector_type(4)));

/* ---- ws layout (bytes); NEED ~218.8 MB (proven available) ---- */
#define OFF_CONST 0ull
#define OFF_Z1I  1024ull
#define OFF_S1T  (OFF_Z1I + 4096000ull)
#define OFF_XBW  (OFF_S1T + 1920000ull)          /* 975*640*8 (320-stride, pad stored 0) */
#define OFF_Z1F  (OFF_XBW + 4992000ull)
#define OFF_U1   (OFF_Z1F + 3840000ull)
#define OFF_U2   (OFF_U1 + 3840000ull)
#define OFF_AQ   (OFF_U2 + 480000ull)            /* 975*25*4*2048 = 199,680,000 */
#define NEED_SPARSE (OFF_AQ + 199680000ull)

#define GLOAD_LDS16(g, s) __builtin_amdgcn_global_load_lds( \
    (const __attribute__((address_space(1))) unsigned int*)(g), \
    (__attribute__((address_space(3))) unsigned int*)(s), 16, 0, 0)

/* K0: SRM/REF kernels, fp64 rounded through fp32 (fallback path only). */
__global__ void k0_init(double* c) {
    int k = threadIdx.x;
    if (k < KSRM) {
        double v = ((double)k / 10.0) * exp(1.0 - (double)k / 10.0);
        c[k] = (double)(float)v;
    }
    if (k < KREF) {
        double v = -20.0 * (double)k * exp(1.0 - (double)k);
        c[80 + k] = (double)(float)v;
    }
}

/* K_PRE: fused pre-pass (one launch, independent block partitions):
   [0,NB_K1)            : bitmask xbw build (k1)
   [NB_K1,+NB_QA)       : w1 quantization into lane-linear aq (k_qa)
   [+NB_Z)              : z1i zero-init
   last block           : SRM/REF constant table (k0)                      */
__global__ __launch_bounds__(256) void k_pre(const float* __restrict__ x,
                                             const float* __restrict__ w1,
                                             u64* __restrict__ xbw,
                                             char* __restrict__ aq,
                                             u64* __restrict__ z1i,
                                             double* __restrict__ cst) {
    int blk = blockIdx.x;
    if (blk < NB_K1) {
        /* ---- k1: bitmask xbw[w][b*320+t]; pad t -> 0 ---- */
        const int NTG = 5;
        int gw = (blk * 256 + (int)threadIdx.x) >> 6;
        int lane = threadIdx.x & 63;
        if (gw >= BB * NWRD * NTG) return;
        int b  = gw / (NWRD * NTG);
        int r  = gw % (NWRD * NTG);
        int fw = r / NTG;
        int tg = r % NTG;
        int t = tg * 64 + lane;
        bool act = (t < TT);
        int tc = act ? t : 0;
        const float* xp = x + ((size_t)(b * F1 + (fw << 6))) * TT + tc;
        unsigned lo = 0, hi = 0;
        #pragma unroll
        for (int j = 0; j < 32; ++j)
            lo |= (xp[(size_t)j * TT] > 0.5f ? 1u : 0u) << j;
        #pragma unroll
        for (int j = 0; j < 32; ++j)
            hi |= (xp[(size_t)(j + 32) * TT] > 0.5f ? 1u : 0u) << j;
        u64 mval = act ? (((u64)hi << 32) | lo) : 0ull;
        xbw[(size_t)fw * NPAD + b * 320 + t] = mval;
    } else if (blk < NB_K1 + NB_QA) {
        /* ---- k_qa: quantize (scale 2^31, exact) into lane-linear planes ---- */
        int tid = (blk - NB_K1) * 256 + (int)threadIdx.x;
        if (tid >= NWRD * 3200) return;
        int kc = tid & 3;
        int o  = (tid >> 2) & 31;
        int m  = (tid >> 7) % MB;
        int wl = tid / 3200;
        const float* src = w1 + (size_t)(m * 32 + o) * F1 + (size_t)wl * 64 + kc * 16;
        unsigned dw[NDIG][4];
        #pragma unroll
        for (int g = 0; g < 4; ++g) {
            float4 f4 = *(const float4*)(src + g * 4);
            float ff[4] = {f4.x, f4.y, f4.z, f4.w};
            unsigned w0 = 0, w1_ = 0, w2 = 0, w3 = 0;
            #pragma unroll
            for (int e = 0; e < 4; ++e) {
                int v = (int)rint((double)ff[e] * 2147483648.0);   /* 2^31, exact */
                int d0 = (v << 24) >> 24;  int v1 = (v - d0) >> 8;
                int d1 = (v1 << 24) >> 24; int v2 = (v1 - d1) >> 8;
                int d2 = (v2 << 24) >> 24; int d3 = (v2 - d2) >> 8;
                w0 |= (unsigned)(d0 & 0xFF) << (8 * e);
                w1_ |= (unsigned)(d1 & 0xFF) << (8 * e);
                w2 |= (unsigned)(d2 & 0xFF) << (8 * e);
                w3 |= (unsigned)(d3 & 0xFF) << (8 * e);
            }
            dw[0][g] = w0; dw[1][g] = w1_; dw[2][g] = w2; dw[3][g] = w3;
        }
        char* dst = aq + (((size_t)wl * MB + m) * NDIG) * 2048
                    + (o >> 4) * 1024 + (size_t)(kc * 16 + (o & 15)) * 16;
        #pragma unroll
        for (int d = 0; d < NDIG; ++d)
            *(i32x4*)(dst + (size_t)d * 2048) =
                (i32x4){(int)dw[d][0], (int)dw[d][1], (int)dw[d][2], (int)dw[d][3]};
    } else if (blk < NB_K1 + NB_QA + NB_Z) {
        /* ---- z1i zero ---- */
        int idx = ((blk - NB_K1 - NB_QA) * 256 + (int)threadIdx.x) * 2;
        z1i[idx] = 0ull; z1i[idx + 1] = 0ull;
    } else {
        /* ---- k0: constants ---- */
        int k = threadIdx.x;
        if (k < KSRM) {
            double v = ((double)k / 10.0) * exp(1.0 - (double)k / 10.0);
            cst[k] = (double)(float)v;
        }
        if (k < KREF) {
            double v = -20.0 * (double)k * exp(1.0 - (double)k);
            cst[80 + k] = (double)(float)v;
        }
    }
}

/* unpack 16 mask bits -> 16 i8 (R4-verified byte order) + 4 digit MFMAs */
#define K3_COMPUTE(A0, A1, A2, A3, BV, TTI)                                        \
    {                                                                              \
        i32x4 bf;                                                                  \
        _Pragma("unroll")                                                          \
        for (int i_ = 0; i_ < 4; ++i_)                                             \
            bf[i_] = (int)((((BV >> (4 * i_)) & 0xFu) * 0x00204081u) & 0x01010101u); \
        acc[TTI][0] = __builtin_amdgcn_mfma_i32_16x16x64_i8(A0, bf, acc[TTI][0], 0, 0, 0); \
        acc[TTI][1] = __builtin_amdgcn_mfma_i32_16x16x64_i8(A1, bf, acc[TTI][1], 0, 0, 0); \
        acc[TTI][2] = __builtin_amdgcn_mfma_i32_16x16x64_i8(A2, bf, acc[TTI][2], 0, 0, 0); \
        acc[TTI][3] = __builtin_amdgcn_mfma_i32_16x16x64_i8(A3, bf, acc[TTI][3], 0, 0, 0); \
    }

/* K3M2: exact i8 MFMA GEMM; A via global_load_lds double-buffer (linear both
   sides), lane-linear conflict-free ds_read_b128; B reg prefetch. R16-proven
   structure; KSPL=16 -> ~3.1 blocks/CU for cross-block latency hiding. */
__global__ __launch_bounds__(512, 4) void k3m2(const char* __restrict__ aq,
                                               const u64* __restrict__ xbw,
                                               u64* __restrict__ z1i) {
    __shared__ __align__(16) char Abuf[2][8192];
    int m = blockIdx.x >> 1, nh = blockIdx.x & 1, ksl = blockIdx.y;
    int tid = threadIdx.x;
    int l = tid & 63, wid = tid >> 6;
    int q = wid & 3, oh = wid >> 2;

    int wl0 = ksl * WPS;
    int wend = wl0 + WPS; if (wend > NWRD) wend = NWRD;
    int steps = wend - wl0;

    i32x4 acc[5][NDIG];
    #pragma unroll
    for (int i = 0; i < 5; ++i)
        #pragma unroll
        for (int d = 0; d < NDIG; ++d) acc[i][d] = (i32x4){0, 0, 0, 0};

    const char* abase = aq + (((size_t)wl0 * MB + m) * NDIG) * 2048 + (size_t)tid * 16;
    const unsigned short* bp0 =
        (const unsigned short*)((const char*)xbw
            + ((size_t)wl0 * NPAD
               + (size_t)(nh * 320 + q * 80 + (l & 15))) * 8
            + (l >> 4) * 2);

    GLOAD_LDS16(abase, &Abuf[0][tid * 16]);
    unsigned b0 = bp0[0], b1 = bp0[64], b2 = bp0[128], b3 = bp0[192], b4 = bp0[256];
    __syncthreads();

    int cur = 0;
    const int lofs = oh * 1024 + l * 16;

    for (int s = 0; s < steps; ++s) {
        if (s + 1 < steps)
            GLOAD_LDS16(abase + (size_t)(s + 1) * ASTRIDE, &Abuf[cur ^ 1][tid * 16]);
        int sn = (s + 1 < steps) ? (s + 1) : s;
        const unsigned short* bpn = bp0 + (size_t)sn * BSTRIDE;
        unsigned nb0 = bpn[0], nb1 = bpn[64], nb2 = bpn[128], nb3 = bpn[192], nb4 = bpn[256];
        const char* lp = &Abuf[cur][0] + lofs;
        i32x4 a0 = *(const i32x4*)(lp);
        i32x4 a1 = *(const i32x4*)(lp + 2048);
        i32x4 a2 = *(const i32x4*)(lp + 4096);
        i32x4 a3 = *(const i32x4*)(lp + 6144);
        K3_COMPUTE(a0, a1, a2, a3, b0, 0)
        K3_COMPUTE(a0, a1, a2, a3, b1, 1)
        K3_COMPUTE(a0, a1, a2, a3, b2, 2)
        K3_COMPUTE(a0, a1, a2, a3, b3, 3)
        K3_COMPUTE(a0, a1, a2, a3, b4, 4)
        b0 = nb0; b1 = nb1; b2 = nb2; b3 = nb3; b4 = nb4;
        __syncthreads();
        cur ^= 1;
    }

    #pragma unroll
    for (int tt = 0; tt < 5; ++tt) {
        int n = nh * 320 + q * 80 + tt * 16 + (l & 15);
        #pragma unroll
        for (int r = 0; r < 4; ++r) {
            int o = oh * 16 + (l >> 4) * 4 + r;
            long long c = (long long)acc[tt][0][r]
                        + ((long long)acc[tt][1][r] << 8)
                        + ((long long)acc[tt][2][r] << 16)
                        + ((long long)acc[tt][3][r] << 24);
            atomicAdd(&z1i[(size_t)(m * 32 + o) * NPAD + n], (u64)c);
        }
    }
}

/* dense fallback GEMM1 (used only if ws too small) -> z1f fp64 */
__global__ __launch_bounds__(256) void k_dense_gemm1(const float* __restrict__ x,
                                                     const float* __restrict__ w1,
                                                     double* __restrict__ z1) {
    int lin = blockIdx.x;
    int ot = lin % 25; int tt = (lin / 25) % 5; int b = lin / 125;
    int t0 = tt * 64, o0 = ot * 32;
    __shared__ float xs[64][64];
    __shared__ float wsh[32][64];
    int ti = threadIdx.x & 63, og = threadIdx.x >> 6;
    double dacc[8] = {0, 0, 0, 0, 0, 0, 0, 0};
    for (int fc = 0; fc < F1; fc += 64) {
        __syncthreads();
        for (int e = threadIdx.x; e < 64 * 64; e += 256) {
            int r = e >> 6, c = e & 63;
            int t = t0 + c;
            xs[r][c] = (t < TT) ? x[((size_t)b * F1 + fc + r) * TT + t] : 0.0f;
        }
        for (int e = threadIdx.x; e < 32 * 64; e += 256) {
            int r = e >> 6, c = e & 63;
            wsh[r][c] = w1[(size_t)(o0 + r) * F1 + fc + c];
        }
        __syncthreads();
        float facc[8] = {0, 0, 0, 0, 0, 0, 0, 0};
        for (int ff = 0; ff < 64; ++ff) {
            float xv = xs[ff][ti];
            #pragma unroll
            for (int oo = 0; oo < 8; ++oo) facc[oo] += wsh[og * 8 + oo][ff] * xv;
        }
        #pragma unroll
        for (int oo = 0; oo < 8; ++oo) dacc[oo] += (double)facc[oo];
    }
    int t = t0 + ti;
    if (t < TT) {
        #pragma unroll
        for (int oo = 0; oo < 8; ++oo) {
            int o = o0 + og * 8 + oo;
            z1[((size_t)(b * O1 + o)) * TT + t] = dacc[oo];
        }
    }
}

/* K_CONV1: scale + psp conv for layer 1 (t-parallel, per-row block). */
__global__ __launch_bounds__(320) void k_conv1(const u64* __restrict__ z1i,
                                               const double* __restrict__ z1f,
                                               double* __restrict__ u1,
                                               const double* __restrict__ cst,
                                               int mode) {
    __shared__ double zs[TT];
    __shared__ double ck[KSRM];
    int row = blockIdx.x;
    int b = row / O1, o = row % O1;
    int t = threadIdx.x;
    if (t < KSRM) ck[t] = cst[t];
    if (t < TT) {
        double z;
        if (mode == 0)
            z = (double)(long long)z1i[(size_t)o * NPAD + b * 320 + t]
                * 4.656612873077393e-10;                    /* 2^-31 */
        else
            z = z1f[(size_t)row * TT + t];
        zs[t] = z;
    }
    __syncthreads();
    if (t < TT) {
        int kmax = t < (KSRM - 1) ? t : (KSRM - 1);
        double acc = 0.0;
        for (int k = 0; k <= kmax; ++k) acc += ck[k] * zs[t - k];
        u1[(size_t)row * TT + t] = acc;
    }
}

/* K_SCAN: thread-per-row spike scan, branch-free cndmask chains with
   tree-summed refractory term (fp64 reassoc ~1e-14 << spike margin). */
__global__ __launch_bounds__(64) void k_scan(const double* __restrict__ u,
                                             float* __restrict__ s,
                                             const double* __restrict__ cst,
                                             int nrows) {
    int row = blockIdx.x * 64 + threadIdx.x;
    if (row >= nrows) return;
    double rk1 = cst[81], rk2 = cst[82], rk3 = cst[83], rk4 = cst[84];
    double rk5 = cst[85], rk6 = cst[86], rk7 = cst[87], rk8 = cst[88];
    double rk9 = cst[89], rk10 = cst[90];
    const double* ur = u + (size_t)row * TT;
    float* sr = s + (size_t)row * TT;
    unsigned h = 0;
    #pragma unroll 4
    for (int t = 0; t < TT; ++t) {
        double a  = ((h & 1u)   ? rk1 : 0.0) + ((h & 2u)   ? rk2  : 0.0);
        double b2 = ((h & 4u)   ? rk3 : 0.0) + ((h & 8u)   ? rk4  : 0.0);
        double c2 = ((h & 16u)  ? rk5 : 0.0) + ((h & 32u)  ? rk6  : 0.0);
        double d2 = ((h & 64u)  ? rk7 : 0.0) + ((h & 128u) ? rk8  : 0.0);
        double e2 = ((h & 256u) ? rk9 : 0.0) + ((h & 512u) ? rk10 : 0.0);
        double ueff = ur[t] + (((a + b2) + (c2 + d2)) + e2);
        unsigned sp = (ueff >= 10.0) ? 1u : 0u;
        sr[t] = (float)sp;
        h = (h << 1) | sp;
    }
}

/* K_GEMM2C: fused GEMM2 + psp conv for layer 2 (both t-parallel). */
__global__ __launch_bounds__(320) void k_gemm2c(const float* __restrict__ s1t,
                                                const float* __restrict__ w2,
                                                double* __restrict__ u2,
                                                const double* __restrict__ cst) {
    __shared__ float wsm[O1];
    __shared__ double zs[TT];
    __shared__ double ck[KSRM];
    int bo = blockIdx.x;
    int b = bo / O2N, o2 = bo % O2N;
    int t = threadIdx.x;
    if (t < KSRM) ck[t] = cst[t];
    for (int f = t; f < O1; f += 320) wsm[f] = w2[(size_t)o2 * O1 + f];
    __syncthreads();
    if (t < TT) {
        double acc = 0.0;
        #pragma unroll 4
        for (int f = 0; f < O1; ++f)
            acc += (double)(wsm[f] * s1t[((size_t)(b * O1 + f)) * TT + t]);
        zs[t] = acc;
    }
    __syncthreads();
    if (t < TT) {
        int kmax = t < (KSRM - 1) ? t : (KSRM - 1);
        double acc = 0.0;
        for (int k = 0; k <= kmax; ++k) acc += ck[k] * zs[t - k];
        u2[(size_t)bo * TT + t] = acc;
    }
}

extern "C" void kernel_launch(void* const* d_in, const int* in_sizes, int n_in,
                              void* d_out, int out_size, void* d_ws, size_t ws_size,
                              hipStream_t stream) {
    const float* x  = (const float*)d_in[0];
    const float* w1 = (const float*)d_in[1];
    const float* w2 = (const float*)d_in[2];
    float* out = (float*)d_out;
    char* ws = (char*)d_ws;

    double* cst = (double*)(ws + OFF_CONST);
    u64*    z1i = (u64*)   (ws + OFF_Z1I);
    float*  s1t = (float*) (ws + OFF_S1T);
    u64*    xbw = (u64*)   (ws + OFF_XBW);
    double* z1f = (double*)(ws + OFF_Z1F);
    double* u1  = (double*)(ws + OFF_U1);
    double* u2  = (double*)(ws + OFF_U2);
    char*   aq  = (char*)  (ws + OFF_AQ);

    int mode;
    if (ws_size >= NEED_SPARSE) {
        mode = 0;
        k_pre<<<NB_K1 + NB_QA + NB_Z + 1, 256, 0, stream>>>(x, w1, xbw, aq, z1i, cst);
        k3m2<<<dim3(2 * MB, KSPL), 512, 0, stream>>>(aq, xbw, z1i);
    } else {
        mode = 1;
        k0_init<<<1, 128, 0, stream>>>(cst);
        k_dense_gemm1<<<250, 256, 0, stream>>>(x, w1, z1f);
    }

    k_conv1<<<BB * O1, 320, 0, stream>>>(z1i, z1f, u1, cst, mode);
    k_scan<<<(BB * O1 + 63) / 64, 64, 0, stream>>>(u1, s1t, cst, BB * O1);
    k_gemm2c<<<BB * O2N, 320, 0, stream>>>(s1t, w2, u2, cst);
    k_scan<<<(BB * O2N + 63) / 64, 64, 0, stream>>>(u2, out, cst, BB * O2N);
    (void)in_sizes; (void)n_in; (void)out_size;
}

// Round 19
// 373.884 us; speedup vs baseline: 1.2621x; 1.1104x over previous
//
#include <hip/hip_runtime.h>

#define F1 62400
#define O1 800
#define O2N 100
#define TT 300
#define BB 2
#define NWRD 975        /* 64-bit f-words */
#define KSRM 77
#define KREF 11
#define MB 25           /* M-blocks of 32 o */
#define NPAD 640        /* n = b*320 + t */
#define NDIG 4          /* base-256 digits of rint(w1 * 2^31) — exact (R4-proven) */
#define KSPL 10         /* k-splits (proven best) */
#define WPS 98          /* words per split (last split: 93) */
#define ASTRIDE ((size_t)MB * NDIG * 2048)
#define BSTRIDE ((size_t)NPAD * 4)

/* k_pre grid partition */
#define NB_K1 2438      /* ceil(2*975*5*64 / 256) */
#define NB_QA 12188     /* ceil(975*3200 / 256) */

typedef unsigned long long u64;
typedef int i32x4 __attribute__((ext_vector_type(4)));

/* ---- ws layout (bytes); NEED ~255.7 MB (ws ~798 MB per harness fill) ---- */
#define OFF_CONST 0ull
#define OFF_Z1P  1024ull                          /* 10*800*640*8 = 40,960,000 */
#define OFF_S1T  (OFF_Z1P + 40960000ull)
#define OFF_XBW  (OFF_S1T + 1920000ull)           /* 975*640*8 (320-stride, pad 0) */
#define OFF_Z1F  (OFF_XBW + 4992000ull)
#define OFF_U1   (OFF_Z1F + 3840000ull)
#define OFF_U2   (OFF_U1 + 3840000ull)
#define OFF_AQ   (OFF_U2 + 480000ull)             /* 975*25*4*2048 = 199,680,000 */
#define NEED_SPARSE (OFF_AQ + 199680000ull)       /* 255,713,024 */

#define GLOAD_LDS16(g, s) __builtin_amdgcn_global_load_lds( \
    (const __attribute__((address_space(1))) unsigned int*)(g), \
    (__attribute__((address_space(3))) unsigned int*)(s), 16, 0, 0)

/* K0: SRM/REF kernels, fp64 rounded through fp32 (fallback path only). */
__global__ void k0_init(double* c) {
    int k = threadIdx.x;
    if (k < KSRM) {
        double v = ((double)k / 10.0) * exp(1.0 - (double)k / 10.0);
        c[k] = (double)(float)v;
    }
    if (k < KREF) {
        double v = -20.0 * (double)k * exp(1.0 - (double)k);
        c[80 + k] = (double)(float)v;
    }
}

/* K_PRE: fused pre-pass: [0,NB_K1) bitmask; [NB_K1,+NB_QA) quantize; last
   block: constants. (z1p needs no init — k3m2 writes every slot.) */
__global__ __launch_bounds__(256) void k_pre(const float* __restrict__ x,
                                             const float* __restrict__ w1,
                                             u64* __restrict__ xbw,
                                             char* __restrict__ aq,
                                             double* __restrict__ cst) {
    int blk = blockIdx.x;
    if (blk < NB_K1) {
        const int NTG = 5;
        int gw = (blk * 256 + (int)threadIdx.x) >> 6;
        int lane = threadIdx.x & 63;
        if (gw >= BB * NWRD * NTG) return;
        int b  = gw / (NWRD * NTG);
        int r  = gw % (NWRD * NTG);
        int fw = r / NTG;
        int tg = r % NTG;
        int t = tg * 64 + lane;
        bool act = (t < TT);
        int tc = act ? t : 0;
        const float* xp = x + ((size_t)(b * F1 + (fw << 6))) * TT + tc;
        unsigned lo = 0, hi = 0;
        #pragma unroll
        for (int j = 0; j < 32; ++j)
            lo |= (xp[(size_t)j * TT] > 0.5f ? 1u : 0u) << j;
        #pragma unroll
        for (int j = 0; j < 32; ++j)
            hi |= (xp[(size_t)(j + 32) * TT] > 0.5f ? 1u : 0u) << j;
        u64 mval = act ? (((u64)hi << 32) | lo) : 0ull;
        xbw[(size_t)fw * NPAD + b * 320 + t] = mval;
    } else if (blk < NB_K1 + NB_QA) {
        int tid = (blk - NB_K1) * 256 + (int)threadIdx.x;
        if (tid >= NWRD * 3200) return;
        int kc = tid & 3;
        int o  = (tid >> 2) & 31;
        int m  = (tid >> 7) % MB;
        int wl = tid / 3200;
        const float* src = w1 + (size_t)(m * 32 + o) * F1 + (size_t)wl * 64 + kc * 16;
        unsigned dw[NDIG][4];
        #pragma unroll
        for (int g = 0; g < 4; ++g) {
            float4 f4 = *(const float4*)(src + g * 4);
            float ff[4] = {f4.x, f4.y, f4.z, f4.w};
            unsigned w0 = 0, w1_ = 0, w2 = 0, w3 = 0;
            #pragma unroll
            for (int e = 0; e < 4; ++e) {
                int v = (int)rint((double)ff[e] * 2147483648.0);   /* 2^31, exact */
                int d0 = (v << 24) >> 24;  int v1 = (v - d0) >> 8;
                int d1 = (v1 << 24) >> 24; int v2 = (v1 - d1) >> 8;
                int d2 = (v2 << 24) >> 24; int d3 = (v2 - d2) >> 8;
                w0 |= (unsigned)(d0 & 0xFF) << (8 * e);
                w1_ |= (unsigned)(d1 & 0xFF) << (8 * e);
                w2 |= (unsigned)(d2 & 0xFF) << (8 * e);
                w3 |= (unsigned)(d3 & 0xFF) << (8 * e);
            }
            dw[0][g] = w0; dw[1][g] = w1_; dw[2][g] = w2; dw[3][g] = w3;
        }
        char* dst = aq + (((size_t)wl * MB + m) * NDIG) * 2048
                    + (o >> 4) * 1024 + (size_t)(kc * 16 + (o & 15)) * 16;
        #pragma unroll
        for (int d = 0; d < NDIG; ++d)
            *(i32x4*)(dst + (size_t)d * 2048) =
                (i32x4){(int)dw[d][0], (int)dw[d][1], (int)dw[d][2], (int)dw[d][3]};
    } else {
        int k = threadIdx.x;
        if (k < KSRM) {
            double v = ((double)k / 10.0) * exp(1.0 - (double)k / 10.0);
            cst[k] = (double)(float)v;
        }
        if (k < KREF) {
            double v = -20.0 * (double)k * exp(1.0 - (double)k);
            cst[80 + k] = (double)(float)v;
        }
    }
}

/* unpack 16 mask bits -> 16 i8 (R4-verified byte order) + 4 digit MFMAs */
#define K3_COMPUTE(A0, A1, A2, A3, BV, TTI)                                        \
    {                                                                              \
        i32x4 bf;                                                                  \
        _Pragma("unroll")                                                          \
        for (int i_ = 0; i_ < 4; ++i_)                                             \
            bf[i_] = (int)((((BV >> (4 * i_)) & 0xFu) * 0x00204081u) & 0x01010101u); \
        acc[TTI][0] = __builtin_amdgcn_mfma_i32_16x16x64_i8(A0, bf, acc[TTI][0], 0, 0, 0); \
        acc[TTI][1] = __builtin_amdgcn_mfma_i32_16x16x64_i8(A1, bf, acc[TTI][1], 0, 0, 0); \
        acc[TTI][2] = __builtin_amdgcn_mfma_i32_16x16x64_i8(A2, bf, acc[TTI][2], 0, 0, 0); \
        acc[TTI][3] = __builtin_amdgcn_mfma_i32_16x16x64_i8(A3, bf, acc[TTI][3], 0, 0, 0); \
    }

/* K3M2: exact i8 MFMA GEMM (R16-proven body); epilogue now ATOMIC-FREE:
   plain coalesced u64 stores into per-ksplit partial planes z1p[ksl][o][n]. */
__global__ __launch_bounds__(512, 4) void k3m2(const char* __restrict__ aq,
                                               const u64* __restrict__ xbw,
                                               u64* __restrict__ z1p) {
    __shared__ __align__(16) char Abuf[2][8192];
    int m = blockIdx.x >> 1, nh = blockIdx.x & 1, ksl = blockIdx.y;
    int tid = threadIdx.x;
    int l = tid & 63, wid = tid >> 6;
    int q = wid & 3, oh = wid >> 2;

    int wl0 = ksl * WPS;
    int wend = wl0 + WPS; if (wend > NWRD) wend = NWRD;
    int steps = wend - wl0;

    i32x4 acc[5][NDIG];
    #pragma unroll
    for (int i = 0; i < 5; ++i)
        #pragma unroll
        for (int d = 0; d < NDIG; ++d) acc[i][d] = (i32x4){0, 0, 0, 0};

    const char* abase = aq + (((size_t)wl0 * MB + m) * NDIG) * 2048 + (size_t)tid * 16;
    const unsigned short* bp0 =
        (const unsigned short*)((const char*)xbw
            + ((size_t)wl0 * NPAD
               + (size_t)(nh * 320 + q * 80 + (l & 15))) * 8
            + (l >> 4) * 2);

    GLOAD_LDS16(abase, &Abuf[0][tid * 16]);
    unsigned b0 = bp0[0], b1 = bp0[64], b2 = bp0[128], b3 = bp0[192], b4 = bp0[256];
    __syncthreads();

    int cur = 0;
    const int lofs = oh * 1024 + l * 16;

    for (int s = 0; s < steps; ++s) {
        if (s + 1 < steps)
            GLOAD_LDS16(abase + (size_t)(s + 1) * ASTRIDE, &Abuf[cur ^ 1][tid * 16]);
        int sn = (s + 1 < steps) ? (s + 1) : s;
        const unsigned short* bpn = bp0 + (size_t)sn * BSTRIDE;
        unsigned nb0 = bpn[0], nb1 = bpn[64], nb2 = bpn[128], nb3 = bpn[192], nb4 = bpn[256];
        const char* lp = &Abuf[cur][0] + lofs;
        i32x4 a0 = *(const i32x4*)(lp);
        i32x4 a1 = *(const i32x4*)(lp + 2048);
        i32x4 a2 = *(const i32x4*)(lp + 4096);
        i32x4 a3 = *(const i32x4*)(lp + 6144);
        K3_COMPUTE(a0, a1, a2, a3, b0, 0)
        K3_COMPUTE(a0, a1, a2, a3, b1, 1)
        K3_COMPUTE(a0, a1, a2, a3, b2, 2)
        K3_COMPUTE(a0, a1, a2, a3, b3, 3)
        K3_COMPUTE(a0, a1, a2, a3, b4, 4)
        b0 = nb0; b1 = nb1; b2 = nb2; b3 = nb3; b4 = nb4;
        __syncthreads();
        cur ^= 1;
    }

    /* atomic-free epilogue: plain stores into this ksplit's partial plane */
    u64* zp = z1p + (size_t)ksl * O1 * NPAD;
    #pragma unroll
    for (int tt = 0; tt < 5; ++tt) {
        int n = nh * 320 + q * 80 + tt * 16 + (l & 15);
        #pragma unroll
        for (int r = 0; r < 4; ++r) {
            int o = oh * 16 + (l >> 4) * 4 + r;
            long long c = (long long)acc[tt][0][r]
                        + ((long long)acc[tt][1][r] << 8)
                        + ((long long)acc[tt][2][r] << 16)
                        + ((long long)acc[tt][3][r] << 24);
            zp[(size_t)(m * 32 + o) * NPAD + n] = (u64)c;
        }
    }
}

/* dense fallback GEMM1 (used only if ws too small) -> z1f fp64 */
__global__ __launch_bounds__(256) void k_dense_gemm1(const float* __restrict__ x,
                                                     const float* __restrict__ w1,
                                                     double* __restrict__ z1) {
    int lin = blockIdx.x;
    int ot = lin % 25; int tt = (lin / 25) % 5; int b = lin / 125;
    int t0 = tt * 64, o0 = ot * 32;
    __shared__ float xs[64][64];
    __shared__ float wsh[32][64];
    int ti = threadIdx.x & 63, og = threadIdx.x >> 6;
    double dacc[8] = {0, 0, 0, 0, 0, 0, 0, 0};
    for (int fc = 0; fc < F1; fc += 64) {
        __syncthreads();
        for (int e = threadIdx.x; e < 64 * 64; e += 256) {
            int r = e >> 6, c = e & 63;
            int t = t0 + c;
            xs[r][c] = (t < TT) ? x[((size_t)b * F1 + fc + r) * TT + t] : 0.0f;
        }
        for (int e = threadIdx.x; e < 32 * 64; e += 256) {
            int r = e >> 6, c = e & 63;
            wsh[r][c] = w1[(size_t)(o0 + r) * F1 + fc + c];
        }
        __syncthreads();
        float facc[8] = {0, 0, 0, 0, 0, 0, 0, 0};
        for (int ff = 0; ff < 64; ++ff) {
            float xv = xs[ff][ti];
            #pragma unroll
            for (int oo = 0; oo < 8; ++oo) facc[oo] += wsh[og * 8 + oo][ff] * xv;
        }
        #pragma unroll
        for (int oo = 0; oo < 8; ++oo) dacc[oo] += (double)facc[oo];
    }
    int t = t0 + ti;
    if (t < TT) {
        #pragma unroll
        for (int oo = 0; oo < 8; ++oo) {
            int o = o0 + og * 8 + oo;
            z1[((size_t)(b * O1 + o)) * TT + t] = dacc[oo];
        }
    }
}

/* K_CONV1: exact i64 partial-sum + scale + psp conv (t-parallel). */
__global__ __launch_bounds__(320) void k_conv1(const u64* __restrict__ z1p,
                                               const double* __restrict__ z1f,
                                               double* __restrict__ u1,
                                               const double* __restrict__ cst,
                                               int mode) {
    __shared__ double zs[TT];
    __shared__ double ck[KSRM];
    int row = blockIdx.x;                 /* b*800 + o */
    int b = row / O1, o = row % O1;
    int t = threadIdx.x;
    if (t < KSRM) ck[t] = cst[t];
    if (t < TT) {
        double z;
        if (mode == 0) {
            long long c = 0;
            size_t base = (size_t)o * NPAD + b * 320 + t;
            #pragma unroll
            for (int g = 0; g < KSPL; ++g)
                c += (long long)z1p[(size_t)g * O1 * NPAD + base];
            z = (double)c * 4.656612873077393e-10;          /* 2^-31 */
        } else {
            z = z1f[(size_t)row * TT + t];
        }
        zs[t] = z;
    }
    __syncthreads();
    if (t < TT) {
        int kmax = t < (KSRM - 1) ? t : (KSRM - 1);
        double acc = 0.0;
        for (int k = 0; k <= kmax; ++k) acc += ck[k] * zs[t - k];
        u1[(size_t)row * TT + t] = acc;
    }
}

/* K_SCAN: thread-per-row spike scan, branch-free cndmask chains with
   tree-summed refractory term (fp64 reassoc ~1e-14 << spike margin). */
__global__ __launch_bounds__(64) void k_scan(const double* __restrict__ u,
                                             float* __restrict__ s,
                                             const double* __restrict__ cst,
                                             int nrows) {
    int row = blockIdx.x * 64 + threadIdx.x;
    if (row >= nrows) return;
    double rk1 = cst[81], rk2 = cst[82], rk3 = cst[83], rk4 = cst[84];
    double rk5 = cst[85], rk6 = cst[86], rk7 = cst[87], rk8 = cst[88];
    double rk9 = cst[89], rk10 = cst[90];
    const double* ur = u + (size_t)row * TT;
    float* sr = s + (size_t)row * TT;
    unsigned h = 0;
    #pragma unroll 4
    for (int t = 0; t < TT; ++t) {
        double a  = ((h & 1u)   ? rk1 : 0.0) + ((h & 2u)   ? rk2  : 0.0);
        double b2 = ((h & 4u)   ? rk3 : 0.0) + ((h & 8u)   ? rk4  : 0.0);
        double c2 = ((h & 16u)  ? rk5 : 0.0) + ((h & 32u)  ? rk6  : 0.0);
        double d2 = ((h & 64u)  ? rk7 : 0.0) + ((h & 128u) ? rk8  : 0.0);
        double e2 = ((h & 256u) ? rk9 : 0.0) + ((h & 512u) ? rk10 : 0.0);
        double ueff = ur[t] + (((a + b2) + (c2 + d2)) + e2);
        unsigned sp = (ueff >= 10.0) ? 1u : 0u;
        sr[t] = (float)sp;
        h = (h << 1) | sp;
    }
}

/* K_GEMM2C: fused GEMM2 + psp conv for layer 2 (both t-parallel). */
__global__ __launch_bounds__(320) void k_gemm2c(const float* __restrict__ s1t,
                                                const float* __restrict__ w2,
                                                double* __restrict__ u2,
                                                const double* __restrict__ cst) {
    __shared__ float wsm[O1];
    __shared__ double zs[TT];
    __shared__ double ck[KSRM];
    int bo = blockIdx.x;
    int b = bo / O2N, o2 = bo % O2N;
    int t = threadIdx.x;
    if (t < KSRM) ck[t] = cst[t];
    for (int f = t; f < O1; f += 320) wsm[f] = w2[(size_t)o2 * O1 + f];
    __syncthreads();
    if (t < TT) {
        double acc = 0.0;
        #pragma unroll 4
        for (int f = 0; f < O1; ++f)
            acc += (double)(wsm[f] * s1t[((size_t)(b * O1 + f)) * TT + t]);
        zs[t] = acc;
    }
    __syncthreads();
    if (t < TT) {
        int kmax = t < (KSRM - 1) ? t : (KSRM - 1);
        double acc = 0.0;
        for (int k = 0; k <= kmax; ++k) acc += ck[k] * zs[t - k];
        u2[(size_t)bo * TT + t] = acc;
    }
}

extern "C" void kernel_launch(void* const* d_in, const int* in_sizes, int n_in,
                              void* d_out, int out_size, void* d_ws, size_t ws_size,
                              hipStream_t stream) {
    const float* x  = (const float*)d_in[0];
    const float* w1 = (const float*)d_in[1];
    const float* w2 = (const float*)d_in[2];
    float* out = (float*)d_out;
    char* ws = (char*)d_ws;

    double* cst = (double*)(ws + OFF_CONST);
    u64*    z1p = (u64*)   (ws + OFF_Z1P);
    float*  s1t = (float*) (ws + OFF_S1T);
    u64*    xbw = (u64*)   (ws + OFF_XBW);
    double* z1f = (double*)(ws + OFF_Z1F);
    double* u1  = (double*)(ws + OFF_U1);
    double* u2  = (double*)(ws + OFF_U2);
    char*   aq  = (char*)  (ws + OFF_AQ);

    int mode;
    if (ws_size >= NEED_SPARSE) {
        mode = 0;
        k_pre<<<NB_K1 + NB_QA + 1, 256, 0, stream>>>(x, w1, xbw, aq, cst);
        k3m2<<<dim3(2 * MB, KSPL), 512, 0, stream>>>(aq, xbw, z1p);
    } else {
        mode = 1;
        k0_init<<<1, 128, 0, stream>>>(cst);
        k_dense_gemm1<<<250, 256, 0, stream>>>(x, w1, z1f);
    }

    k_conv1<<<BB * O1, 320, 0, stream>>>(z1p, z1f, u1, cst, mode);
    k_scan<<<(BB * O1 + 63) / 64, 64, 0, stream>>>(u1, s1t, cst, BB * O1);
    k_gemm2c<<<BB * O2N, 320, 0, stream>>>(s1t, w2, u2, cst);
    k_scan<<<(BB * O2N + 63) / 64, 64, 0, stream>>>(u2, out, cst, BB * O2N);
    (void)in_sizes; (void)n_in; (void)out_size;
}

// Round 20
// 370.773 us; speedup vs baseline: 1.2727x; 1.0084x over previous
//
#include <hip/hip_runtime.h>

#define F1 62400
#define O1 800
#define O2N 100
#define TT 300
#define BB 2
#define NWRD 975        /* 64-bit f-words */
#define KSRM 77
#define KREF 11
#define MB 25           /* M-blocks of 32 o */
#define NPAD 640        /* n = b*320 + t */
#define NDIG 4          /* base-256 digits of rint(w1 * 2^31) — exact (R4-proven) */
#define KSPL 10         /* k-splits (proven best) */
#define WPS 98          /* words per split (last split: 93) */
#define ASTRIDE ((size_t)MB * NDIG * 2048)
#define BSTRIDE ((size_t)NPAD * 4)

/* k_pre grid partition */
#define NB_K1 2438      /* ceil(2*975*5*64 / 256) */
#define NB_QA 12188     /* ceil(975*3200 / 256) */

typedef unsigned long long u64;
typedef int i32x4 __attribute__((ext_vector_type(4)));

/* ---- ws layout (bytes); NEED ~255.7 MB (ws ~798 MB per harness fill) ---- */
#define OFF_CONST 0ull
#define OFF_Z1P  1024ull                          /* 10*800*640*8 = 40,960,000 */
#define OFF_S1T  (OFF_Z1P + 40960000ull)
#define OFF_XBW  (OFF_S1T + 1920000ull)           /* 975*640*8 (320-stride, pad 0) */
#define OFF_Z1F  (OFF_XBW + 4992000ull)
#define OFF_U1   (OFF_Z1F + 3840000ull)
#define OFF_U2   (OFF_U1 + 3840000ull)
#define OFF_AQ   (OFF_U2 + 480000ull)             /* 975*25*4*2048 = 199,680,000 */
#define NEED_SPARSE (OFF_AQ + 199680000ull)       /* 255,713,024 */

#define GLOAD_LDS16(g, s) __builtin_amdgcn_global_load_lds( \
    (const __attribute__((address_space(1))) unsigned int*)(g), \
    (__attribute__((address_space(3))) unsigned int*)(s), 16, 0, 0)

/* K0: SRM/REF kernels, fp64 rounded through fp32 (fallback path only). */
__global__ void k0_init(double* c) {
    int k = threadIdx.x;
    if (k < KSRM) {
        double v = ((double)k / 10.0) * exp(1.0 - (double)k / 10.0);
        c[k] = (double)(float)v;
    }
    if (k < KREF) {
        double v = -20.0 * (double)k * exp(1.0 - (double)k);
        c[80 + k] = (double)(float)v;
    }
}

/* K_PRE: fused pre-pass: [0,NB_K1) bitmask; [NB_K1,+NB_QA) quantize; last
   block: constants. (z1p needs no init — k3m2 writes every slot.) */
__global__ __launch_bounds__(256) void k_pre(const float* __restrict__ x,
                                             const float* __restrict__ w1,
                                             u64* __restrict__ xbw,
                                             char* __restrict__ aq,
                                             double* __restrict__ cst) {
    int blk = blockIdx.x;
    if (blk < NB_K1) {
        const int NTG = 5;
        int gw = (blk * 256 + (int)threadIdx.x) >> 6;
        int lane = threadIdx.x & 63;
        if (gw >= BB * NWRD * NTG) return;
        int b  = gw / (NWRD * NTG);
        int r  = gw % (NWRD * NTG);
        int fw = r / NTG;
        int tg = r % NTG;
        int t = tg * 64 + lane;
        bool act = (t < TT);
        int tc = act ? t : 0;
        const float* xp = x + ((size_t)(b * F1 + (fw << 6))) * TT + tc;
        unsigned lo = 0, hi = 0;
        #pragma unroll
        for (int j = 0; j < 32; ++j)
            lo |= (xp[(size_t)j * TT] > 0.5f ? 1u : 0u) << j;
        #pragma unroll
        for (int j = 0; j < 32; ++j)
            hi |= (xp[(size_t)(j + 32) * TT] > 0.5f ? 1u : 0u) << j;
        u64 mval = act ? (((u64)hi << 32) | lo) : 0ull;
        xbw[(size_t)fw * NPAD + b * 320 + t] = mval;
    } else if (blk < NB_K1 + NB_QA) {
        int tid = (blk - NB_K1) * 256 + (int)threadIdx.x;
        if (tid >= NWRD * 3200) return;
        int kc = tid & 3;
        int o  = (tid >> 2) & 31;
        int m  = (tid >> 7) % MB;
        int wl = tid / 3200;
        const float* src = w1 + (size_t)(m * 32 + o) * F1 + (size_t)wl * 64 + kc * 16;
        unsigned dw[NDIG][4];
        #pragma unroll
        for (int g = 0; g < 4; ++g) {
            float4 f4 = *(const float4*)(src + g * 4);
            float ff[4] = {f4.x, f4.y, f4.z, f4.w};
            unsigned w0 = 0, w1_ = 0, w2 = 0, w3 = 0;
            #pragma unroll
            for (int e = 0; e < 4; ++e) {
                int v = (int)rint((double)ff[e] * 2147483648.0);   /* 2^31, exact */
                int d0 = (v << 24) >> 24;  int v1 = (v - d0) >> 8;
                int d1 = (v1 << 24) >> 24; int v2 = (v1 - d1) >> 8;
                int d2 = (v2 << 24) >> 24; int d3 = (v2 - d2) >> 8;
                w0 |= (unsigned)(d0 & 0xFF) << (8 * e);
                w1_ |= (unsigned)(d1 & 0xFF) << (8 * e);
                w2 |= (unsigned)(d2 & 0xFF) << (8 * e);
                w3 |= (unsigned)(d3 & 0xFF) << (8 * e);
            }
            dw[0][g] = w0; dw[1][g] = w1_; dw[2][g] = w2; dw[3][g] = w3;
        }
        char* dst = aq + (((size_t)wl * MB + m) * NDIG) * 2048
                    + (o >> 4) * 1024 + (size_t)(kc * 16 + (o & 15)) * 16;
        #pragma unroll
        for (int d = 0; d < NDIG; ++d)
            *(i32x4*)(dst + (size_t)d * 2048) =
                (i32x4){(int)dw[d][0], (int)dw[d][1], (int)dw[d][2], (int)dw[d][3]};
    } else {
        int k = threadIdx.x;
        if (k < KSRM) {
            double v = ((double)k / 10.0) * exp(1.0 - (double)k / 10.0);
            cst[k] = (double)(float)v;
        }
        if (k < KREF) {
            double v = -20.0 * (double)k * exp(1.0 - (double)k);
            cst[80 + k] = (double)(float)v;
        }
    }
}

/* unpack 16 mask bits -> 16 i8 (R4-verified byte order) + 4 digit MFMAs */
#define K3_COMPUTE(A0, A1, A2, A3, BV, TTI)                                        \
    {                                                                              \
        i32x4 bf;                                                                  \
        _Pragma("unroll")                                                          \
        for (int i_ = 0; i_ < 4; ++i_)                                             \
            bf[i_] = (int)((((BV >> (4 * i_)) & 0xFu) * 0x00204081u) & 0x01010101u); \
        acc[TTI][0] = __builtin_amdgcn_mfma_i32_16x16x64_i8(A0, bf, acc[TTI][0], 0, 0, 0); \
        acc[TTI][1] = __builtin_amdgcn_mfma_i32_16x16x64_i8(A1, bf, acc[TTI][1], 0, 0, 0); \
        acc[TTI][2] = __builtin_amdgcn_mfma_i32_16x16x64_i8(A2, bf, acc[TTI][2], 0, 0, 0); \
        acc[TTI][3] = __builtin_amdgcn_mfma_i32_16x16x64_i8(A3, bf, acc[TTI][3], 0, 0, 0); \
    }

/* K3M2: exact i8 MFMA GEMM; A via 3-buffer global_load_lds pipeline with
   COUNTED vmcnt(6) + raw s_barrier (T4: DMA(s+1) retires a full step after
   issue; never drain to 0 in-loop). No sched_barrier pinning (m141 lesson).
   24 KB LDS keeps 4 blocks/CU. Atomic-free epilogue into z1p[ksl]. */
__global__ __launch_bounds__(512, 4) void k3m2(const char* __restrict__ aq,
                                               const u64* __restrict__ xbw,
                                               u64* __restrict__ z1p) {
    __shared__ __align__(16) char Abuf[3][8192];
    int m = blockIdx.x >> 1, nh = blockIdx.x & 1, ksl = blockIdx.y;
    int tid = threadIdx.x;
    int l = tid & 63, wid = tid >> 6;
    int q = wid & 3, oh = wid >> 2;

    int wl0 = ksl * WPS;
    int wend = wl0 + WPS; if (wend > NWRD) wend = NWRD;
    int steps = wend - wl0;          /* 98 or 93 (always >= 2) */

    i32x4 acc[5][NDIG];
    #pragma unroll
    for (int i = 0; i < 5; ++i)
        #pragma unroll
        for (int d = 0; d < NDIG; ++d) acc[i][d] = (i32x4){0, 0, 0, 0};

    const char* abase = aq + (((size_t)wl0 * MB + m) * NDIG) * 2048 + (size_t)tid * 16;
    const unsigned short* bp0 =
        (const unsigned short*)((const char*)xbw
            + ((size_t)wl0 * NPAD
               + (size_t)(nh * 320 + q * 80 + (l & 15))) * 8
            + (l >> 4) * 2);
    const int lofs = oh * 1024 + l * 16;

    /* prologue: stage steps 0 and 1; load B(0); full drain once */
    GLOAD_LDS16(abase, &Abuf[0][tid * 16]);
    GLOAD_LDS16(abase + ASTRIDE, &Abuf[1][tid * 16]);
    unsigned b0 = bp0[0], b1 = bp0[64], b2 = bp0[128], b3 = bp0[192], b4 = bp0[256];
    __syncthreads();

    int cur = 0;
    for (int s = 0; s < steps; ++s) {
        /* issue DMA for step s+2 into the third buffer (clamped at tail;
           clamped writes land in never-read slots — (s+2)%3 != s%3) */
        int pf = s + 2; if (pf > steps - 1) pf = steps - 1;
        int sl = cur + 2; if (sl >= 3) sl -= 3;
        GLOAD_LDS16(abase + (size_t)pf * ASTRIDE, &Abuf[sl][tid * 16]);
        /* prefetch B for step s+1 */
        int sn = s + 1; if (sn > steps - 1) sn = steps - 1;
        const unsigned short* bpn = bp0 + (size_t)sn * BSTRIDE;
        unsigned nb0 = bpn[0], nb1 = bpn[64], nb2 = bpn[128], nb3 = bpn[192], nb4 = bpn[256];
        /* compute step s from buffer cur */
        const char* lp = &Abuf[cur][0] + lofs;
        i32x4 a0 = *(const i32x4*)(lp);
        i32x4 a1 = *(const i32x4*)(lp + 2048);
        i32x4 a2 = *(const i32x4*)(lp + 4096);
        i32x4 a3 = *(const i32x4*)(lp + 6144);
        K3_COMPUTE(a0, a1, a2, a3, b0, 0)
        K3_COMPUTE(a0, a1, a2, a3, b1, 1)
        K3_COMPUTE(a0, a1, a2, a3, b2, 2)
        K3_COMPUTE(a0, a1, a2, a3, b3, 3)
        K3_COMPUTE(a0, a1, a2, a3, b4, 4)
        b0 = nb0; b1 = nb1; b2 = nb2; b3 = nb3; b4 = nb4;
        /* counted wait: retire DMA(s+1) (issued a full step ago); keep this
           step's 6 ops (DMA(s+2)+5 B) in flight across the barrier */
        asm volatile("s_waitcnt vmcnt(6)" ::: "memory");
        __builtin_amdgcn_s_barrier();
        cur = (cur + 1 == 3) ? 0 : cur + 1;
    }

    /* atomic-free epilogue: plain stores into this ksplit's partial plane */
    u64* zp = z1p + (size_t)ksl * O1 * NPAD;
    #pragma unroll
    for (int tt = 0; tt < 5; ++tt) {
        int n = nh * 320 + q * 80 + tt * 16 + (l & 15);
        #pragma unroll
        for (int r = 0; r < 4; ++r) {
            int o = oh * 16 + (l >> 4) * 4 + r;
            long long c = (long long)acc[tt][0][r]
                        + ((long long)acc[tt][1][r] << 8)
                        + ((long long)acc[tt][2][r] << 16)
                        + ((long long)acc[tt][3][r] << 24);
            zp[(size_t)(m * 32 + o) * NPAD + n] = (u64)c;
        }
    }
}

/* dense fallback GEMM1 (used only if ws too small) -> z1f fp64 */
__global__ __launch_bounds__(256) void k_dense_gemm1(const float* __restrict__ x,
                                                     const float* __restrict__ w1,
                                                     double* __restrict__ z1) {
    int lin = blockIdx.x;
    int ot = lin % 25; int tt = (lin / 25) % 5; int b = lin / 125;
    int t0 = tt * 64, o0 = ot * 32;
    __shared__ float xs[64][64];
    __shared__ float wsh[32][64];
    int ti = threadIdx.x & 63, og = threadIdx.x >> 6;
    double dacc[8] = {0, 0, 0, 0, 0, 0, 0, 0};
    for (int fc = 0; fc < F1; fc += 64) {
        __syncthreads();
        for (int e = threadIdx.x; e < 64 * 64; e += 256) {
            int r = e >> 6, c = e & 63;
            int t = t0 + c;
            xs[r][c] = (t < TT) ? x[((size_t)b * F1 + fc + r) * TT + t] : 0.0f;
        }
        for (int e = threadIdx.x; e < 32 * 64; e += 256) {
            int r = e >> 6, c = e & 63;
            wsh[r][c] = w1[(size_t)(o0 + r) * F1 + fc + c];
        }
        __syncthreads();
        float facc[8] = {0, 0, 0, 0, 0, 0, 0, 0};
        for (int ff = 0; ff < 64; ++ff) {
            float xv = xs[ff][ti];
            #pragma unroll
            for (int oo = 0; oo < 8; ++oo) facc[oo] += wsh[og * 8 + oo][ff] * xv;
        }
        #pragma unroll
        for (int oo = 0; oo < 8; ++oo) dacc[oo] += (double)facc[oo];
    }
    int t = t0 + ti;
    if (t < TT) {
        #pragma unroll
        for (int oo = 0; oo < 8; ++oo) {
            int o = o0 + og * 8 + oo;
            z1[((size_t)(b * O1 + o)) * TT + t] = dacc[oo];
        }
    }
}

/* K_CONV1: exact i64 partial-sum + scale + psp conv (t-parallel). */
__global__ __launch_bounds__(320) void k_conv1(const u64* __restrict__ z1p,
                                               const double* __restrict__ z1f,
                                               double* __restrict__ u1,
                                               const double* __restrict__ cst,
                                               int mode) {
    __shared__ double zs[TT];
    __shared__ double ck[KSRM];
    int row = blockIdx.x;                 /* b*800 + o */
    int b = row / O1, o = row % O1;
    int t = threadIdx.x;
    if (t < KSRM) ck[t] = cst[t];
    if (t < TT) {
        double z;
        if (mode == 0) {
            long long c = 0;
            size_t base = (size_t)o * NPAD + b * 320 + t;
            #pragma unroll
            for (int g = 0; g < KSPL; ++g)
                c += (long long)z1p[(size_t)g * O1 * NPAD + base];
            z = (double)c * 4.656612873077393e-10;          /* 2^-31 */
        } else {
            z = z1f[(size_t)row * TT + t];
        }
        zs[t] = z;
    }
    __syncthreads();
    if (t < TT) {
        int kmax = t < (KSRM - 1) ? t : (KSRM - 1);
        double acc = 0.0;
        for (int k = 0; k <= kmax; ++k) acc += ck[k] * zs[t - k];
        u1[(size_t)row * TT + t] = acc;
    }
}

/* K_SCAN: thread-per-row spike scan, branch-free cndmask chains with
   tree-summed refractory term (fp64 reassoc ~1e-14 << spike margin). */
__global__ __launch_bounds__(64) void k_scan(const double* __restrict__ u,
                                             float* __restrict__ s,
                                             const double* __restrict__ cst,
                                             int nrows) {
    int row = blockIdx.x * 64 + threadIdx.x;
    if (row >= nrows) return;
    double rk1 = cst[81], rk2 = cst[82], rk3 = cst[83], rk4 = cst[84];
    double rk5 = cst[85], rk6 = cst[86], rk7 = cst[87], rk8 = cst[88];
    double rk9 = cst[89], rk10 = cst[90];
    const double* ur = u + (size_t)row * TT;
    float* sr = s + (size_t)row * TT;
    unsigned h = 0;
    #pragma unroll 4
    for (int t = 0; t < TT; ++t) {
        double a  = ((h & 1u)   ? rk1 : 0.0) + ((h & 2u)   ? rk2  : 0.0);
        double b2 = ((h & 4u)   ? rk3 : 0.0) + ((h & 8u)   ? rk4  : 0.0);
        double c2 = ((h & 16u)  ? rk5 : 0.0) + ((h & 32u)  ? rk6  : 0.0);
        double d2 = ((h & 64u)  ? rk7 : 0.0) + ((h & 128u) ? rk8  : 0.0);
        double e2 = ((h & 256u) ? rk9 : 0.0) + ((h & 512u) ? rk10 : 0.0);
        double ueff = ur[t] + (((a + b2) + (c2 + d2)) + e2);
        unsigned sp = (ueff >= 10.0) ? 1u : 0u;
        sr[t] = (float)sp;
        h = (h << 1) | sp;
    }
}

/* K_GEMM2C: fused GEMM2 + psp conv for layer 2 (both t-parallel). */
__global__ __launch_bounds__(320) void k_gemm2c(const float* __restrict__ s1t,
                                                const float* __restrict__ w2,
                                                double* __restrict__ u2,
                                                const double* __restrict__ cst) {
    __shared__ float wsm[O1];
    __shared__ double zs[TT];
    __shared__ double ck[KSRM];
    int bo = blockIdx.x;
    int b = bo / O2N, o2 = bo % O2N;
    int t = threadIdx.x;
    if (t < KSRM) ck[t] = cst[t];
    for (int f = t; f < O1; f += 320) wsm[f] = w2[(size_t)o2 * O1 + f];
    __syncthreads();
    if (t < TT) {
        double acc = 0.0;
        #pragma unroll 4
        for (int f = 0; f < O1; ++f)
            acc += (double)(wsm[f] * s1t[((size_t)(b * O1 + f)) * TT + t]);
        zs[t] = acc;
    }
    __syncthreads();
    if (t < TT) {
        int kmax = t < (KSRM - 1) ? t : (KSRM - 1);
        double acc = 0.0;
        for (int k = 0; k <= kmax; ++k) acc += ck[k] * zs[t - k];
        u2[(size_t)bo * TT + t] = acc;
    }
}

extern "C" void kernel_launch(void* const* d_in, const int* in_sizes, int n_in,
                              void* d_out, int out_size, void* d_ws, size_t ws_size,
                              hipStream_t stream) {
    const float* x  = (const float*)d_in[0];
    const float* w1 = (const float*)d_in[1];
    const float* w2 = (const float*)d_in[2];
    float* out = (float*)d_out;
    char* ws = (char*)d_ws;

    double* cst = (double*)(ws + OFF_CONST);
    u64*    z1p = (u64*)   (ws + OFF_Z1P);
    float*  s1t = (float*) (ws + OFF_S1T);
    u64*    xbw = (u64*)   (ws + OFF_XBW);
    double* z1f = (double*)(ws + OFF_Z1F);
    double* u1  = (double*)(ws + OFF_U1);
    double* u2  = (double*)(ws + OFF_U2);
    char*   aq  = (char*)  (ws + OFF_AQ);

    int mode;
    if (ws_size >= NEED_SPARSE) {
        mode = 0;
        k_pre<<<NB_K1 + NB_QA + 1, 256, 0, stream>>>(x, w1, xbw, aq, cst);
        k3m2<<<dim3(2 * MB, KSPL), 512, 0, stream>>>(aq, xbw, z1p);
    } else {
        mode = 1;
        k0_init<<<1, 128, 0, stream>>>(cst);
        k_dense_gemm1<<<250, 256, 0, stream>>>(x, w1, z1f);
    }

    k_conv1<<<BB * O1, 320, 0, stream>>>(z1p, z1f, u1, cst, mode);
    k_scan<<<(BB * O1 + 63) / 64, 64, 0, stream>>>(u1, s1t, cst, BB * O1);
    k_gemm2c<<<BB * O2N, 320, 0, stream>>>(s1t, w2, u2, cst);
    k_scan<<<(BB * O2N + 63) / 64, 64, 0, stream>>>(u2, out, cst, BB * O2N);
    (void)in_sizes; (void)n_in; (void)out_size;
}

// Round 21
// 368.339 us; speedup vs baseline: 1.2811x; 1.0066x over previous
//
#include <hip/hip_runtime.h>

#define F1 62400
#define O1 800
#define O2N 100
#define TT 300
#define BB 2
#define NWRD 975        /* 64-bit f-words */
#define KSRM 77
#define KREF 11
#define M16 50          /* M-blocks of 16 o */
#define NPAD 640        /* n = b*320 + t */
#define NDIG 4          /* base-256 digits of rint(w1 * 2^31) — exact (R4-proven) */
#define KSPL 10         /* k-splits (proven best) */
#define WPS 98          /* words per split (last split: 93) */
#define ASTRIDE ((size_t)M16 * 4096)             /* 204,800 B per word */
#define BSTRIDE ((size_t)NPAD * 4)

/* k_pre grid partition */
#define NB_K1 2438      /* ceil(2*975*5*64 / 256) */
#define NB_QA 12188     /* ceil(975*3200 / 256) */

typedef unsigned long long u64;
typedef int i32x4 __attribute__((ext_vector_type(4)));

/* ---- ws layout (bytes); NEED ~255.7 MB (ws ~798 MB per harness fill) ---- */
#define OFF_CONST 0ull
#define OFF_Z1P  1024ull                          /* 10*800*640*8 = 40,960,000 */
#define OFF_S1T  (OFF_Z1P + 40960000ull)
#define OFF_XBW  (OFF_S1T + 1920000ull)           /* 975*640*8 (320-stride, pad 0) */
#define OFF_Z1F  (OFF_XBW + 4992000ull)
#define OFF_U1   (OFF_Z1F + 3840000ull)
#define OFF_U2   (OFF_U1 + 3840000ull)
#define OFF_AQ   (OFF_U2 + 480000ull)             /* 975*50*4096 = 199,680,000 */
#define NEED_SPARSE (OFF_AQ + 199680000ull)       /* 255,713,024 */

#define GLOAD_LDS16(g, s) __builtin_amdgcn_global_load_lds( \
    (const __attribute__((address_space(1))) unsigned int*)(g), \
    (__attribute__((address_space(3))) unsigned int*)(s), 16, 0, 0)

/* K0: SRM/REF kernels, fp64 rounded through fp32 (fallback path only). */
__global__ void k0_init(double* c) {
    int k = threadIdx.x;
    if (k < KSRM) {
        double v = ((double)k / 10.0) * exp(1.0 - (double)k / 10.0);
        c[k] = (double)(float)v;
    }
    if (k < KREF) {
        double v = -20.0 * (double)k * exp(1.0 - (double)k);
        c[80 + k] = (double)(float)v;
    }
}

/* K_PRE: fused pre-pass: [0,NB_K1) bitmask; [NB_K1,+NB_QA) quantize; last
   block: constants. aq tile = 4KB per (w, m16): [dig0 1KB][dig1][dig2][dig3],
   chunk (kc*16 + o&15) within each dig plane (lane-linear for k3m2). */
__global__ __launch_bounds__(256) void k_pre(const float* __restrict__ x,
                                             const float* __restrict__ w1,
                                             u64* __restrict__ xbw,
                                             char* __restrict__ aq,
                                             double* __restrict__ cst) {
    int blk = blockIdx.x;
    if (blk < NB_K1) {
        const int NTG = 5;
        int gw = (blk * 256 + (int)threadIdx.x) >> 6;
        int lane = threadIdx.x & 63;
        if (gw >= BB * NWRD * NTG) return;
        int b  = gw / (NWRD * NTG);
        int r  = gw % (NWRD * NTG);
        int fw = r / NTG;
        int tg = r % NTG;
        int t = tg * 64 + lane;
        bool act = (t < TT);
        int tc = act ? t : 0;
        const float* xp = x + ((size_t)(b * F1 + (fw << 6))) * TT + tc;
        unsigned lo = 0, hi = 0;
        #pragma unroll
        for (int j = 0; j < 32; ++j)
            lo |= (xp[(size_t)j * TT] > 0.5f ? 1u : 0u) << j;
        #pragma unroll
        for (int j = 0; j < 32; ++j)
            hi |= (xp[(size_t)(j + 32) * TT] > 0.5f ? 1u : 0u) << j;
        u64 mval = act ? (((u64)hi << 32) | lo) : 0ull;
        xbw[(size_t)fw * NPAD + b * 320 + t] = mval;
    } else if (blk < NB_K1 + NB_QA) {
        int tid = (blk - NB_K1) * 256 + (int)threadIdx.x;
        if (tid >= NWRD * 3200) return;
        int kc = tid & 3;
        int o  = (tid >> 2) & 31;
        int m  = (tid >> 7) % 25;
        int wl = tid / 3200;
        const float* src = w1 + (size_t)(m * 32 + o) * F1 + (size_t)wl * 64 + kc * 16;
        unsigned dw[NDIG][4];
        #pragma unroll
        for (int g = 0; g < 4; ++g) {
            float4 f4 = *(const float4*)(src + g * 4);
            float ff[4] = {f4.x, f4.y, f4.z, f4.w};
            unsigned w0 = 0, w1_ = 0, w2 = 0, w3 = 0;
            #pragma unroll
            for (int e = 0; e < 4; ++e) {
                int v = (int)rint((double)ff[e] * 2147483648.0);   /* 2^31, exact */
                int d0 = (v << 24) >> 24;  int v1 = (v - d0) >> 8;
                int d1 = (v1 << 24) >> 24; int v2 = (v1 - d1) >> 8;
                int d2 = (v2 << 24) >> 24; int d3 = (v2 - d2) >> 8;
                w0 |= (unsigned)(d0 & 0xFF) << (8 * e);
                w1_ |= (unsigned)(d1 & 0xFF) << (8 * e);
                w2 |= (unsigned)(d2 & 0xFF) << (8 * e);
                w3 |= (unsigned)(d3 & 0xFF) << (8 * e);
            }
            dw[0][g] = w0; dw[1][g] = w1_; dw[2][g] = w2; dw[3][g] = w3;
        }
        int og = m * 32 + o;
        int m16 = og >> 4, op = og & 15;
        char* dst = aq + ((size_t)wl * M16 + m16) * 4096 + (size_t)(kc * 16 + op) * 16;
        #pragma unroll
        for (int d = 0; d < NDIG; ++d)
            *(i32x4*)(dst + (size_t)d * 1024) =
                (i32x4){(int)dw[d][0], (int)dw[d][1], (int)dw[d][2], (int)dw[d][3]};
    } else {
        int k = threadIdx.x;
        if (k < KSRM) {
            double v = ((double)k / 10.0) * exp(1.0 - (double)k / 10.0);
            cst[k] = (double)(float)v;
        }
        if (k < KREF) {
            double v = -20.0 * (double)k * exp(1.0 - (double)k);
            cst[80 + k] = (double)(float)v;
        }
    }
}

/* unpack 16 mask bits -> 16 i8 (R4-verified byte order) + 4 digit MFMAs */
#define K3_COMPUTE(A0, A1, A2, A3, BV, TTI)                                        \
    {                                                                              \
        i32x4 bf;                                                                  \
        _Pragma("unroll")                                                          \
        for (int i_ = 0; i_ < 4; ++i_)                                             \
            bf[i_] = (int)((((BV >> (4 * i_)) & 0xFu) * 0x00204081u) & 0x01010101u); \
        acc[TTI][0] = __builtin_amdgcn_mfma_i32_16x16x64_i8(A0, bf, acc[TTI][0], 0, 0, 0); \
        acc[TTI][1] = __builtin_amdgcn_mfma_i32_16x16x64_i8(A1, bf, acc[TTI][1], 0, 0, 0); \
        acc[TTI][2] = __builtin_amdgcn_mfma_i32_16x16x64_i8(A2, bf, acc[TTI][2], 0, 0, 0); \
        acc[TTI][3] = __builtin_amdgcn_mfma_i32_16x16x64_i8(A3, bf, acc[TTI][3], 0, 0, 0); \
    }

/* K3M2: exact i8 MFMA GEMM. Block = (m16, ksl): 16 o x 640 n — each aq byte
   read ONCE grid-wide (was twice). A via 3-buffer global_load_lds pipeline
   (4KB/step, tid<256), counted vmcnt(6) + raw s_barrier (T4). 8 waves own
   disjoint 80-n slices. Atomic-free epilogue into z1p[ksl]. */
__global__ __launch_bounds__(512, 4) void k3m2(const char* __restrict__ aq,
                                               const u64* __restrict__ xbw,
                                               u64* __restrict__ z1p) {
    __shared__ __align__(16) char Abuf[3][4096];
    int m16 = blockIdx.x, ksl = blockIdx.y;
    int tid = threadIdx.x;
    int l = tid & 63, wid = tid >> 6;          /* wid = n-slice 0..7 */

    int wl0 = ksl * WPS;
    int wend = wl0 + WPS; if (wend > NWRD) wend = NWRD;
    int steps = wend - wl0;          /* 98 or 93 (always >= 2) */

    i32x4 acc[5][NDIG];
    #pragma unroll
    for (int i = 0; i < 5; ++i)
        #pragma unroll
        for (int d = 0; d < NDIG; ++d) acc[i][d] = (i32x4){0, 0, 0, 0};

    const char* abase = aq + ((size_t)wl0 * M16 + m16) * 4096 + (size_t)tid * 16;
    const unsigned short* bp0 =
        (const unsigned short*)((const char*)xbw
            + ((size_t)wl0 * NPAD
               + (size_t)(wid * 80 + (l & 15))) * 8
            + (l >> 4) * 2);
    const int lofs = l * 16;

    /* prologue: stage steps 0 and 1 (tid<256 covers the 4KB tile); B(0) */
    if (tid < 256) {
        GLOAD_LDS16(abase, &Abuf[0][tid * 16]);
        GLOAD_LDS16(abase + ASTRIDE, &Abuf[1][tid * 16]);
    }
    unsigned b0 = bp0[0], b1 = bp0[64], b2 = bp0[128], b3 = bp0[192], b4 = bp0[256];
    __syncthreads();

    int cur = 0;
    for (int s = 0; s < steps; ++s) {
        int pf = s + 2; if (pf > steps - 1) pf = steps - 1;
        int sl = cur + 2; if (sl >= 3) sl -= 3;
        if (tid < 256)
            GLOAD_LDS16(abase + (size_t)pf * ASTRIDE, &Abuf[sl][tid * 16]);
        int sn = s + 1; if (sn > steps - 1) sn = steps - 1;
        const unsigned short* bpn = bp0 + (size_t)sn * BSTRIDE;
        unsigned nb0 = bpn[0], nb1 = bpn[64], nb2 = bpn[128], nb3 = bpn[192], nb4 = bpn[256];
        const char* lp = &Abuf[cur][0] + lofs;
        i32x4 a0 = *(const i32x4*)(lp);
        i32x4 a1 = *(const i32x4*)(lp + 1024);
        i32x4 a2 = *(const i32x4*)(lp + 2048);
        i32x4 a3 = *(const i32x4*)(lp + 3072);
        K3_COMPUTE(a0, a1, a2, a3, b0, 0)
        K3_COMPUTE(a0, a1, a2, a3, b1, 1)
        K3_COMPUTE(a0, a1, a2, a3, b2, 2)
        K3_COMPUTE(a0, a1, a2, a3, b3, 3)
        K3_COMPUTE(a0, a1, a2, a3, b4, 4)
        b0 = nb0; b1 = nb1; b2 = nb2; b3 = nb3; b4 = nb4;
        /* counted wait: retire DMA(s+1) (issued a full step ago); keep this
           step's ops in flight across the barrier (never drain to 0) */
        asm volatile("s_waitcnt vmcnt(6)" ::: "memory");
        __builtin_amdgcn_s_barrier();
        cur = (cur + 1 == 3) ? 0 : cur + 1;
    }

    /* atomic-free epilogue: plain stores into this ksplit's partial plane */
    u64* zp = z1p + (size_t)ksl * O1 * NPAD;
    #pragma unroll
    for (int tt = 0; tt < 5; ++tt) {
        int n = wid * 80 + tt * 16 + (l & 15);
        #pragma unroll
        for (int r = 0; r < 4; ++r) {
            int o = m16 * 16 + (l >> 4) * 4 + r;
            long long c = (long long)acc[tt][0][r]
                        + ((long long)acc[tt][1][r] << 8)
                        + ((long long)acc[tt][2][r] << 16)
                        + ((long long)acc[tt][3][r] << 24);
            zp[(size_t)o * NPAD + n] = (u64)c;
        }
    }
}

/* dense fallback GEMM1 (used only if ws too small) -> z1f fp64 */
__global__ __launch_bounds__(256) void k_dense_gemm1(const float* __restrict__ x,
                                                     const float* __restrict__ w1,
                                                     double* __restrict__ z1) {
    int lin = blockIdx.x;
    int ot = lin % 25; int tt = (lin / 25) % 5; int b = lin / 125;
    int t0 = tt * 64, o0 = ot * 32;
    __shared__ float xs[64][64];
    __shared__ float wsh[32][64];
    int ti = threadIdx.x & 63, og = threadIdx.x >> 6;
    double dacc[8] = {0, 0, 0, 0, 0, 0, 0, 0};
    for (int fc = 0; fc < F1; fc += 64) {
        __syncthreads();
        for (int e = threadIdx.x; e < 64 * 64; e += 256) {
            int r = e >> 6, c = e & 63;
            int t = t0 + c;
            xs[r][c] = (t < TT) ? x[((size_t)b * F1 + fc + r) * TT + t] : 0.0f;
        }
        for (int e = threadIdx.x; e < 32 * 64; e += 256) {
            int r = e >> 6, c = e & 63;
            wsh[r][c] = w1[(size_t)(o0 + r) * F1 + fc + c];
        }
        __syncthreads();
        float facc[8] = {0, 0, 0, 0, 0, 0, 0, 0};
        for (int ff = 0; ff < 64; ++ff) {
            float xv = xs[ff][ti];
            #pragma unroll
            for (int oo = 0; oo < 8; ++oo) facc[oo] += wsh[og * 8 + oo][ff] * xv;
        }
        #pragma unroll
        for (int oo = 0; oo < 8; ++oo) dacc[oo] += (double)facc[oo];
    }
    int t = t0 + ti;
    if (t < TT) {
        #pragma unroll
        for (int oo = 0; oo < 8; ++oo) {
            int o = o0 + og * 8 + oo;
            z1[((size_t)(b * O1 + o)) * TT + t] = dacc[oo];
        }
    }
}

/* K_CONV1: exact i64 partial-sum + scale + psp conv (t-parallel). */
__global__ __launch_bounds__(320) void k_conv1(const u64* __restrict__ z1p,
                                               const double* __restrict__ z1f,
                                               double* __restrict__ u1,
                                               const double* __restrict__ cst,
                                               int mode) {
    __shared__ double zs[TT];
    __shared__ double ck[KSRM];
    int row = blockIdx.x;                 /* b*800 + o */
    int b = row / O1, o = row % O1;
    int t = threadIdx.x;
    if (t < KSRM) ck[t] = cst[t];
    if (t < TT) {
        double z;
        if (mode == 0) {
            long long c = 0;
            size_t base = (size_t)o * NPAD + b * 320 + t;
            #pragma unroll
            for (int g = 0; g < KSPL; ++g)
                c += (long long)z1p[(size_t)g * O1 * NPAD + base];
            z = (double)c * 4.656612873077393e-10;          /* 2^-31 */
        } else {
            z = z1f[(size_t)row * TT + t];
        }
        zs[t] = z;
    }
    __syncthreads();
    if (t < TT) {
        int kmax = t < (KSRM - 1) ? t : (KSRM - 1);
        double acc = 0.0;
        for (int k = 0; k <= kmax; ++k) acc += ck[k] * zs[t - k];
        u1[(size_t)row * TT + t] = acc;
    }
}

/* K_SCAN: thread-per-row spike scan, branch-free cndmask chains with
   tree-summed refractory term (fp64 reassoc ~1e-14 << spike margin). */
__global__ __launch_bounds__(64) void k_scan(const double* __restrict__ u,
                                             float* __restrict__ s,
                                             const double* __restrict__ cst,
                                             int nrows) {
    int row = blockIdx.x * 64 + threadIdx.x;
    if (row >= nrows) return;
    double rk1 = cst[81], rk2 = cst[82], rk3 = cst[83], rk4 = cst[84];
    double rk5 = cst[85], rk6 = cst[86], rk7 = cst[87], rk8 = cst[88];
    double rk9 = cst[89], rk10 = cst[90];
    const double* ur = u + (size_t)row * TT;
    float* sr = s + (size_t)row * TT;
    unsigned h = 0;
    #pragma unroll 4
    for (int t = 0; t < TT; ++t) {
        double a  = ((h & 1u)   ? rk1 : 0.0) + ((h & 2u)   ? rk2  : 0.0);
        double b2 = ((h & 4u)   ? rk3 : 0.0) + ((h & 8u)   ? rk4  : 0.0);
        double c2 = ((h & 16u)  ? rk5 : 0.0) + ((h & 32u)  ? rk6  : 0.0);
        double d2 = ((h & 64u)  ? rk7 : 0.0) + ((h & 128u) ? rk8  : 0.0);
        double e2 = ((h & 256u) ? rk9 : 0.0) + ((h & 512u) ? rk10 : 0.0);
        double ueff = ur[t] + (((a + b2) + (c2 + d2)) + e2);
        unsigned sp = (ueff >= 10.0) ? 1u : 0u;
        sr[t] = (float)sp;
        h = (h << 1) | sp;
    }
}

/* K_GEMM2C: fused GEMM2 + psp conv for layer 2 (both t-parallel). */
__global__ __launch_bounds__(320) void k_gemm2c(const float* __restrict__ s1t,
                                                const float* __restrict__ w2,
                                                double* __restrict__ u2,
                                                const double* __restrict__ cst) {
    __shared__ float wsm[O1];
    __shared__ double zs[TT];
    __shared__ double ck[KSRM];
    int bo = blockIdx.x;
    int b = bo / O2N, o2 = bo % O2N;
    int t = threadIdx.x;
    if (t < KSRM) ck[t] = cst[t];
    for (int f = t; f < O1; f += 320) wsm[f] = w2[(size_t)o2 * O1 + f];
    __syncthreads();
    if (t < TT) {
        double acc = 0.0;
        #pragma unroll 4
        for (int f = 0; f < O1; ++f)
            acc += (double)(wsm[f] * s1t[((size_t)(b * O1 + f)) * TT + t]);
        zs[t] = acc;
    }
    __syncthreads();
    if (t < TT) {
        int kmax = t < (KSRM - 1) ? t : (KSRM - 1);
        double acc = 0.0;
        for (int k = 0; k <= kmax; ++k) acc += ck[k] * zs[t - k];
        u2[(size_t)bo * TT + t] = acc;
    }
}

extern "C" void kernel_launch(void* const* d_in, const int* in_sizes, int n_in,
                              void* d_out, int out_size, void* d_ws, size_t ws_size,
                              hipStream_t stream) {
    const float* x  = (const float*)d_in[0];
    const float* w1 = (const float*)d_in[1];
    const float* w2 = (const float*)d_in[2];
    float* out = (float*)d_out;
    char* ws = (char*)d_ws;

    double* cst = (double*)(ws + OFF_CONST);
    u64*    z1p = (u64*)   (ws + OFF_Z1P);
    float*  s1t = (float*) (ws + OFF_S1T);
    u64*    xbw = (u64*)   (ws + OFF_XBW);
    double* z1f = (double*)(ws + OFF_Z1F);
    double* u1  = (double*)(ws + OFF_U1);
    double* u2  = (double*)(ws + OFF_U2);
    char*   aq  = (char*)  (ws + OFF_AQ);

    int mode;
    if (ws_size >= NEED_SPARSE) {
        mode = 0;
        k_pre<<<NB_K1 + NB_QA + 1, 256, 0, stream>>>(x, w1, xbw, aq, cst);
        k3m2<<<dim3(M16, KSPL), 512, 0, stream>>>(aq, xbw, z1p);
    } else {
        mode = 1;
        k0_init<<<1, 128, 0, stream>>>(cst);
        k_dense_gemm1<<<250, 256, 0, stream>>>(x, w1, z1f);
    }

    k_conv1<<<BB * O1, 320, 0, stream>>>(z1p, z1f, u1, cst, mode);
    k_scan<<<(BB * O1 + 63) / 64, 64, 0, stream>>>(u1, s1t, cst, BB * O1);
    k_gemm2c<<<BB * O2N, 320, 0, stream>>>(s1t, w2, u2, cst);
    k_scan<<<(BB * O2N + 63) / 64, 64, 0, stream>>>(u2, out, cst, BB * O2N);
    (void)in_sizes; (void)n_in; (void)out_size;
}

// Round 22
// 307.855 us; speedup vs baseline: 1.5328x; 1.1965x over previous
//
#include <hip/hip_runtime.h>

#define F1 62400
#define O1 800
#define O2N 100
#define TT 300
#define BB 2
#define NWRD 975        /* 64-bit f-words */
#define KSRM 77
#define KREF 11
#define M16 50          /* M-blocks of 16 o */
#define NPAD 640        /* n = b*320 + t */
#define NDIG 4          /* base-256 digits of rint(w1 * 2^31) — exact (R4-proven) */
#define KSPL 10         /* k-splits (proven best) */
#define WPS 98          /* words per split (last split: 93) */
#define BSTRIDE ((size_t)NPAD * 4)

/* k_pre grid partition */
#define NB_K1 2438      /* ceil(2*975*5*64 / 256) */

typedef unsigned long long u64;
typedef int i32x4 __attribute__((ext_vector_type(4)));

/* ---- ws layout (bytes); NEED ~56 MB ---- */
#define OFF_CONST 0ull
#define OFF_Z1P  1024ull                          /* 10*800*640*8 = 40,960,000 */
#define OFF_S1T  (OFF_Z1P + 40960000ull)
#define OFF_XBW  (OFF_S1T + 1920000ull)           /* 975*640*8 (320-stride, pad 0) */
#define OFF_Z1F  (OFF_XBW + 4992000ull)
#define OFF_U1   (OFF_Z1F + 3840000ull)
#define OFF_U2   (OFF_U1 + 3840000ull)
#define NEED_SPARSE (OFF_U2 + 480000ull)          /* ~56.0 MB */

/* K0: SRM/REF kernels, fp64 rounded through fp32 (fallback path only). */
__global__ void k0_init(double* c) {
    int k = threadIdx.x;
    if (k < KSRM) {
        double v = ((double)k / 10.0) * exp(1.0 - (double)k / 10.0);
        c[k] = (double)(float)v;
    }
    if (k < KREF) {
        double v = -20.0 * (double)k * exp(1.0 - (double)k);
        c[80 + k] = (double)(float)v;
    }
}

/* K_PRE: bitmask build + constants (quantization moved into k3m2). */
__global__ __launch_bounds__(256) void k_pre(const float* __restrict__ x,
                                             u64* __restrict__ xbw,
                                             double* __restrict__ cst) {
    int blk = blockIdx.x;
    if (blk < NB_K1) {
        const int NTG = 5;
        int gw = (blk * 256 + (int)threadIdx.x) >> 6;
        int lane = threadIdx.x & 63;
        if (gw >= BB * NWRD * NTG) return;
        int b  = gw / (NWRD * NTG);
        int r  = gw % (NWRD * NTG);
        int fw = r / NTG;
        int tg = r % NTG;
        int t = tg * 64 + lane;
        bool act = (t < TT);
        int tc = act ? t : 0;
        const float* xp = x + ((size_t)(b * F1 + (fw << 6))) * TT + tc;
        unsigned lo = 0, hi = 0;
        #pragma unroll
        for (int j = 0; j < 32; ++j)
            lo |= (xp[(size_t)j * TT] > 0.5f ? 1u : 0u) << j;
        #pragma unroll
        for (int j = 0; j < 32; ++j)
            hi |= (xp[(size_t)(j + 32) * TT] > 0.5f ? 1u : 0u) << j;
        u64 mval = act ? (((u64)hi << 32) | lo) : 0ull;
        xbw[(size_t)fw * NPAD + b * 320 + t] = mval;
    } else {
        int k = threadIdx.x;
        if (k < KSRM) {
            double v = ((double)k / 10.0) * exp(1.0 - (double)k / 10.0);
            cst[k] = (double)(float)v;
        }
        if (k < KREF) {
            double v = -20.0 * (double)k * exp(1.0 - (double)k);
            cst[80 + k] = (double)(float)v;
        }
    }
}

/* quantize 2 floats -> 4 digit-u16s (byte order identical to R4-verified) */
__device__ __forceinline__ void quant2(float2 f, unsigned short dg[4]) {
    int v0 = (int)rint((double)f.x * 2147483648.0);     /* 2^31, exact */
    int v1 = (int)rint((double)f.y * 2147483648.0);
    int a0 = (v0 << 24) >> 24; int r0 = (v0 - a0) >> 8;
    int a1 = (r0 << 24) >> 24; int r1 = (r0 - a1) >> 8;
    int a2 = (r1 << 24) >> 24; int a3 = (r1 - a2) >> 8;
    int b0 = (v1 << 24) >> 24; int s0 = (v1 - b0) >> 8;
    int b1 = (s0 << 24) >> 24; int s1 = (s0 - b1) >> 8;
    int b2 = (s1 << 24) >> 24; int b3 = (s1 - b2) >> 8;
    dg[0] = (unsigned short)((a0 & 0xFF) | ((b0 & 0xFF) << 8));
    dg[1] = (unsigned short)((a1 & 0xFF) | ((b1 & 0xFF) << 8));
    dg[2] = (unsigned short)((a2 & 0xFF) | ((b2 & 0xFF) << 8));
    dg[3] = (unsigned short)((a3 & 0xFF) | ((b3 & 0xFF) << 8));
}

/* unpack 16 mask bits -> 16 i8 (R4-verified byte order) + 4 digit MFMAs */
#define K3_COMPUTE(A0, A1, A2, A3, BV, TTI)                                        \
    {                                                                              \
        i32x4 bf;                                                                  \
        _Pragma("unroll")                                                          \
        for (int i_ = 0; i_ < 4; ++i_)                                             \
            bf[i_] = (int)((((BV >> (4 * i_)) & 0xFu) * 0x00204081u) & 0x01010101u); \
        acc[TTI][0] = __builtin_amdgcn_mfma_i32_16x16x64_i8(A0, bf, acc[TTI][0], 0, 0, 0); \
        acc[TTI][1] = __builtin_amdgcn_mfma_i32_16x16x64_i8(A1, bf, acc[TTI][1], 0, 0, 0); \
        acc[TTI][2] = __builtin_amdgcn_mfma_i32_16x16x64_i8(A2, bf, acc[TTI][2], 0, 0, 0); \
        acc[TTI][3] = __builtin_amdgcn_mfma_i32_16x16x64_i8(A3, bf, acc[TTI][3], 0, 0, 0); \
    }

/* one pipeline iteration at compile-time roles: compute step S from
   buf[S&1] + BU regs; quantize floats(S+1)=FQ into buf[(S+1)&1]; issue
   float-load(S+2) into FI and B-load(S+1) into BL. Guarded (uniform). */
#define K_ITER(S, FQ, FI, BU0, BU1, BU2, BU3, BU4, BL0, BL1, BL2, BL3, BL4)        \
    {                                                                              \
        int s_ = (S);                                                              \
        if (s_ < steps) {                                                          \
            int pf = s_ + 2; if (pf > steps - 1) pf = steps - 1;                   \
            FI = *(const float2*)(fbase + (size_t)pf * 64);                        \
            int sn = s_ + 1; if (sn > steps - 1) sn = steps - 1;                   \
            const unsigned short* bpn = bp0 + (size_t)sn * BSTRIDE;                \
            BL0 = bpn[0]; BL1 = bpn[64]; BL2 = bpn[128]; BL3 = bpn[192]; BL4 = bpn[256]; \
            const char* lp = &Abuf[s_ & 1][0] + lofs;                              \
            i32x4 a0 = *(const i32x4*)(lp);                                        \
            i32x4 a1 = *(const i32x4*)(lp + 1024);                                 \
            i32x4 a2 = *(const i32x4*)(lp + 2048);                                 \
            i32x4 a3 = *(const i32x4*)(lp + 3072);                                 \
            K3_COMPUTE(a0, a1, a2, a3, BU0, 0)                                     \
            K3_COMPUTE(a0, a1, a2, a3, BU1, 1)                                     \
            K3_COMPUTE(a0, a1, a2, a3, BU2, 2)                                     \
            K3_COMPUTE(a0, a1, a2, a3, BU3, 3)                                     \
            K3_COMPUTE(a0, a1, a2, a3, BU4, 4)                                     \
            unsigned short dg[4];                                                  \
            quant2(FQ, dg);                                                        \
            char* wb = &Abuf[(s_ + 1) & 1][0] + wofs;                              \
            *(unsigned short*)(wb)        = dg[0];                                 \
            *(unsigned short*)(wb + 1024) = dg[1];                                 \
            *(unsigned short*)(wb + 2048) = dg[2];                                 \
            *(unsigned short*)(wb + 3072) = dg[3];                                 \
        }                                                                          \
        __syncthreads();                                                           \
    }

/* K3M2: exact i8 MFMA GEMM with FUSED on-the-fly quantization.
   Block = (m16, ksl): 16 o x 640 n; per step each thread loads float2 of w1
   (same bytes as the old digit tile), quantizes in-register (fp64, exact,
   identical to old k_qa), ds_write_b16 into 2-buffer lane-linear LDS.
   Depth-2 float prefetch via 3 named roles (register auto-waitcnt). */
__global__ __launch_bounds__(512, 4) void k3m2(const float* __restrict__ w1,
                                               const u64* __restrict__ xbw,
                                               u64* __restrict__ z1p) {
    __shared__ __align__(16) char Abuf[2][4096];
    int m16 = blockIdx.x, ksl = blockIdx.y;
    int tid = threadIdx.x;
    int l = tid & 63, wid = tid >> 6;          /* wid = n-slice 0..7 */
    int o  = tid >> 5;                         /* 0..15: my w1 row    */
    int kp = tid & 31;                         /* float2 index: k = 2kp */

    int wl0 = ksl * WPS;
    int wend = wl0 + WPS; if (wend > NWRD) wend = NWRD;
    int steps = wend - wl0;          /* 98 or 93 */

    i32x4 acc[5][NDIG];
    #pragma unroll
    for (int i = 0; i < 5; ++i)
        #pragma unroll
        for (int d = 0; d < NDIG; ++d) acc[i][d] = (i32x4){0, 0, 0, 0};

    /* per-thread float2 source: w1[m16*16+o][wl*64 + kp*2]; step stride 64 */
    const float* fbase = w1 + (size_t)(m16 * 16 + o) * F1 + (size_t)wl0 * 64 + kp * 2;
    const unsigned short* bp0 =
        (const unsigned short*)((const char*)xbw
            + ((size_t)wl0 * NPAD
               + (size_t)(wid * 80 + (l & 15))) * 8
            + (l >> 4) * 2);
    const int lofs = l * 16;
    /* LDS write offset: dig plane 0 byte for k=2kp of row o */
    const int wofs = (kp >> 3) * 256 + o * 16 + (kp & 7) * 2;

    float2 fA, fB, fC;
    unsigned bA0, bA1, bA2, bA3, bA4;
    unsigned bB0, bB1, bB2, bB3, bB4;
    unsigned bC0, bC1, bC2, bC3, bC4;

    /* prologue: quantize step 0 into buf0; prefetch floats(1); B(0) */
    fA = *(const float2*)(fbase);
    {
        unsigned short dg[4];
        quant2(fA, dg);
        char* wb = &Abuf[0][0] + wofs;
        *(unsigned short*)(wb)        = dg[0];
        *(unsigned short*)(wb + 1024) = dg[1];
        *(unsigned short*)(wb + 2048) = dg[2];
        *(unsigned short*)(wb + 3072) = dg[3];
    }
    fB = *(const float2*)(fbase + ((steps > 1) ? 64 : 0));
    bA0 = bp0[0]; bA1 = bp0[64]; bA2 = bp0[128]; bA3 = bp0[192]; bA4 = bp0[256];
    __syncthreads();

    int smax3 = ((steps + 2) / 3) * 3;
    #pragma unroll 1
    for (int sb = 0; sb < smax3; sb += 3) {
        K_ITER(sb,     fB, fC, bA0, bA1, bA2, bA3, bA4, bB0, bB1, bB2, bB3, bB4)
        K_ITER(sb + 1, fC, fA, bB0, bB1, bB2, bB3, bB4, bC0, bC1, bC2, bC3, bC4)
        K_ITER(sb + 2, fA, fB, bC0, bC1, bC2, bC3, bC4, bA0, bA1, bA2, bA3, bA4)
    }

    /* atomic-free epilogue: plain stores into this ksplit's partial plane */
    u64* zp = z1p + (size_t)ksl * O1 * NPAD;
    #pragma unroll
    for (int tt = 0; tt < 5; ++tt) {
        int n = wid * 80 + tt * 16 + (l & 15);
        #pragma unroll
        for (int r = 0; r < 4; ++r) {
            int oo = m16 * 16 + (l >> 4) * 4 + r;
            long long c = (long long)acc[tt][0][r]
                        + ((long long)acc[tt][1][r] << 8)
                        + ((long long)acc[tt][2][r] << 16)
                        + ((long long)acc[tt][3][r] << 24);
            zp[(size_t)oo * NPAD + n] = (u64)c;
        }
    }
}

/* dense fallback GEMM1 (used only if ws too small) -> z1f fp64 */
__global__ __launch_bounds__(256) void k_dense_gemm1(const float* __restrict__ x,
                                                     const float* __restrict__ w1,
                                                     double* __restrict__ z1) {
    int lin = blockIdx.x;
    int ot = lin % 25; int tt = (lin / 25) % 5; int b = lin / 125;
    int t0 = tt * 64, o0 = ot * 32;
    __shared__ float xs[64][64];
    __shared__ float wsh[32][64];
    int ti = threadIdx.x & 63, og = threadIdx.x >> 6;
    double dacc[8] = {0, 0, 0, 0, 0, 0, 0, 0};
    for (int fc = 0; fc < F1; fc += 64) {
        __syncthreads();
        for (int e = threadIdx.x; e < 64 * 64; e += 256) {
            int r = e >> 6, c = e & 63;
            int t = t0 + c;
            xs[r][c] = (t < TT) ? x[((size_t)b * F1 + fc + r) * TT + t] : 0.0f;
        }
        for (int e = threadIdx.x; e < 32 * 64; e += 256) {
            int r = e >> 6, c = e & 63;
            wsh[r][c] = w1[(size_t)(o0 + r) * F1 + fc + c];
        }
        __syncthreads();
        float facc[8] = {0, 0, 0, 0, 0, 0, 0, 0};
        for (int ff = 0; ff < 64; ++ff) {
            float xv = xs[ff][ti];
            #pragma unroll
            for (int oo = 0; oo < 8; ++oo) facc[oo] += wsh[og * 8 + oo][ff] * xv;
        }
        #pragma unroll
        for (int oo = 0; oo < 8; ++oo) dacc[oo] += (double)facc[oo];
    }
    int t = t0 + ti;
    if (t < TT) {
        #pragma unroll
        for (int oo = 0; oo < 8; ++oo) {
            int o = o0 + og * 8 + oo;
            z1[((size_t)(b * O1 + o)) * TT + t] = dacc[oo];
        }
    }
}

/* K_CONV1: exact i64 partial-sum + scale + psp conv (t-parallel). */
__global__ __launch_bounds__(320) void k_conv1(const u64* __restrict__ z1p,
                                               const double* __restrict__ z1f,
                                               double* __restrict__ u1,
                                               const double* __restrict__ cst,
                                               int mode) {
    __shared__ double zs[TT];
    __shared__ double ck[KSRM];
    int row = blockIdx.x;                 /* b*800 + o */
    int b = row / O1, o = row % O1;
    int t = threadIdx.x;
    if (t < KSRM) ck[t] = cst[t];
    if (t < TT) {
        double z;
        if (mode == 0) {
            long long c = 0;
            size_t base = (size_t)o * NPAD + b * 320 + t;
            #pragma unroll
            for (int g = 0; g < KSPL; ++g)
                c += (long long)z1p[(size_t)g * O1 * NPAD + base];
            z = (double)c * 4.656612873077393e-10;          /* 2^-31 */
        } else {
            z = z1f[(size_t)row * TT + t];
        }
        zs[t] = z;
    }
    __syncthreads();
    if (t < TT) {
        int kmax = t < (KSRM - 1) ? t : (KSRM - 1);
        double acc = 0.0;
        for (int k = 0; k <= kmax; ++k) acc += ck[k] * zs[t - k];
        u1[(size_t)row * TT + t] = acc;
    }
}

/* K_SCAN: thread-per-row spike scan, branch-free cndmask chains with
   tree-summed refractory term (fp64 reassoc ~1e-14 << spike margin). */
__global__ __launch_bounds__(64) void k_scan(const double* __restrict__ u,
                                             float* __restrict__ s,
                                             const double* __restrict__ cst,
                                             int nrows) {
    int row = blockIdx.x * 64 + threadIdx.x;
    if (row >= nrows) return;
    double rk1 = cst[81], rk2 = cst[82], rk3 = cst[83], rk4 = cst[84];
    double rk5 = cst[85], rk6 = cst[86], rk7 = cst[87], rk8 = cst[88];
    double rk9 = cst[89], rk10 = cst[90];
    const double* ur = u + (size_t)row * TT;
    float* sr = s + (size_t)row * TT;
    unsigned h = 0;
    #pragma unroll 4
    for (int t = 0; t < TT; ++t) {
        double a  = ((h & 1u)   ? rk1 : 0.0) + ((h & 2u)   ? rk2  : 0.0);
        double b2 = ((h & 4u)   ? rk3 : 0.0) + ((h & 8u)   ? rk4  : 0.0);
        double c2 = ((h & 16u)  ? rk5 : 0.0) + ((h & 32u)  ? rk6  : 0.0);
        double d2 = ((h & 64u)  ? rk7 : 0.0) + ((h & 128u) ? rk8  : 0.0);
        double e2 = ((h & 256u) ? rk9 : 0.0) + ((h & 512u) ? rk10 : 0.0);
        double ueff = ur[t] + (((a + b2) + (c2 + d2)) + e2);
        unsigned sp = (ueff >= 10.0) ? 1u : 0u;
        sr[t] = (float)sp;
        h = (h << 1) | sp;
    }
}

/* K_GEMM2C: fused GEMM2 + psp conv for layer 2 (both t-parallel). */
__global__ __launch_bounds__(320) void k_gemm2c(const float* __restrict__ s1t,
                                                const float* __restrict__ w2,
                                                double* __restrict__ u2,
                                                const double* __restrict__ cst) {
    __shared__ float wsm[O1];
    __shared__ double zs[TT];
    __shared__ double ck[KSRM];
    int bo = blockIdx.x;
    int b = bo / O2N, o2 = bo % O2N;
    int t = threadIdx.x;
    if (t < KSRM) ck[t] = cst[t];
    for (int f = t; f < O1; f += 320) wsm[f] = w2[(size_t)o2 * O1 + f];
    __syncthreads();
    if (t < TT) {
        double acc = 0.0;
        #pragma unroll 4
        for (int f = 0; f < O1; ++f)
            acc += (double)(wsm[f] * s1t[((size_t)(b * O1 + f)) * TT + t]);
        zs[t] = acc;
    }
    __syncthreads();
    if (t < TT) {
        int kmax = t < (KSRM - 1) ? t : (KSRM - 1);
        double acc = 0.0;
        for (int k = 0; k <= kmax; ++k) acc += ck[k] * zs[t - k];
        u2[(size_t)bo * TT + t] = acc;
    }
}

extern "C" void kernel_launch(void* const* d_in, const int* in_sizes, int n_in,
                              void* d_out, int out_size, void* d_ws, size_t ws_size,
                              hipStream_t stream) {
    const float* x  = (const float*)d_in[0];
    const float* w1 = (const float*)d_in[1];
    const float* w2 = (const float*)d_in[2];
    float* out = (float*)d_out;
    char* ws = (char*)d_ws;

    double* cst = (double*)(ws + OFF_CONST);
    u64*    z1p = (u64*)   (ws + OFF_Z1P);
    float*  s1t = (float*) (ws + OFF_S1T);
    u64*    xbw = (u64*)   (ws + OFF_XBW);
    double* z1f = (double*)(ws + OFF_Z1F);
    double* u1  = (double*)(ws + OFF_U1);
    double* u2  = (double*)(ws + OFF_U2);

    int mode;
    if (ws_size >= NEED_SPARSE) {
        mode = 0;
        k_pre<<<NB_K1 + 1, 256, 0, stream>>>(x, xbw, cst);
        k3m2<<<dim3(M16, KSPL), 512, 0, stream>>>(w1, xbw, z1p);
    } else {
        mode = 1;
        k0_init<<<1, 128, 0, stream>>>(cst);
        k_dense_gemm1<<<250, 256, 0, stream>>>(x, w1, z1f);
    }

    k_conv1<<<BB * O1, 320, 0, stream>>>(z1p, z1f, u1, cst, mode);
    k_scan<<<(BB * O1 + 63) / 64, 64, 0, stream>>>(u1, s1t, cst, BB * O1);
    k_gemm2c<<<BB * O2N, 320, 0, stream>>>(s1t, w2, u2, cst);
    k_scan<<<(BB * O2N + 63) / 64, 64, 0, stream>>>(u2, out, cst, BB * O2N);
    (void)in_sizes; (void)n_in; (void)out_size;
}

// Round 23
// 304.913 us; speedup vs baseline: 1.5476x; 1.0096x over previous
//
#include <hip/hip_runtime.h>

#define F1 62400
#define O1 800
#define O2N 100
#define TT 300
#define BB 2
#define NWRD 975        /* 64-bit f-words */
#define KSRM 77
#define KREF 11
#define M16 50          /* M-blocks of 16 o */
#define NPAD 640        /* n = b*320 + t */
#define NDIG 4          /* base-256 digits of rint(w1 * 2^31) — exact (R4-proven) */
#define KSPL 10         /* k-splits (proven best) */
#define WPS 98          /* words per split (last split: 93) */
#define BSTRIDE ((size_t)NPAD * 4)

/* k_pre grid partition */
#define NB_K1 2438      /* ceil(2*975*5*64 / 256) */

typedef unsigned long long u64;
typedef int i32x4 __attribute__((ext_vector_type(4)));

/* chunk swizzle (T2, both-sides): bijective within each 16-chunk group */
#define CSWZ(c) ((c) ^ ((((c) >> 4) & 3) << 1))

/* ---- ws layout (bytes); NEED ~56 MB ---- */
#define OFF_CONST 0ull
#define OFF_Z1P  1024ull                          /* 10*800*640*8 = 40,960,000 */
#define OFF_S1T  (OFF_Z1P + 40960000ull)
#define OFF_XBW  (OFF_S1T + 1920000ull)           /* 975*640*8 (320-stride, pad 0) */
#define OFF_Z1F  (OFF_XBW + 4992000ull)
#define OFF_U1   (OFF_Z1F + 3840000ull)
#define OFF_U2   (OFF_U1 + 3840000ull)
#define NEED_SPARSE (OFF_U2 + 480000ull)          /* ~56.0 MB */

/* K0: SRM/REF kernels, fp64 rounded through fp32 (fallback path only). */
__global__ void k0_init(double* c) {
    int k = threadIdx.x;
    if (k < KSRM) {
        double v = ((double)k / 10.0) * exp(1.0 - (double)k / 10.0);
        c[k] = (double)(float)v;
    }
    if (k < KREF) {
        double v = -20.0 * (double)k * exp(1.0 - (double)k);
        c[80 + k] = (double)(float)v;
    }
}

/* K_PRE: bitmask build + constants. */
__global__ __launch_bounds__(256) void k_pre(const float* __restrict__ x,
                                             u64* __restrict__ xbw,
                                             double* __restrict__ cst) {
    int blk = blockIdx.x;
    if (blk < NB_K1) {
        const int NTG = 5;
        int gw = (blk * 256 + (int)threadIdx.x) >> 6;
        int lane = threadIdx.x & 63;
        if (gw >= BB * NWRD * NTG) return;
        int b  = gw / (NWRD * NTG);
        int r  = gw % (NWRD * NTG);
        int fw = r / NTG;
        int tg = r % NTG;
        int t = tg * 64 + lane;
        bool act = (t < TT);
        int tc = act ? t : 0;
        const float* xp = x + ((size_t)(b * F1 + (fw << 6))) * TT + tc;
        unsigned lo = 0, hi = 0;
        #pragma unroll
        for (int j = 0; j < 32; ++j)
            lo |= (xp[(size_t)j * TT] > 0.5f ? 1u : 0u) << j;
        #pragma unroll
        for (int j = 0; j < 32; ++j)
            hi |= (xp[(size_t)(j + 32) * TT] > 0.5f ? 1u : 0u) << j;
        u64 mval = act ? (((u64)hi << 32) | lo) : 0ull;
        xbw[(size_t)fw * NPAD + b * 320 + t] = mval;
    } else {
        int k = threadIdx.x;
        if (k < KSRM) {
            double v = ((double)k / 10.0) * exp(1.0 - (double)k / 10.0);
            cst[k] = (double)(float)v;
        }
        if (k < KREF) {
            double v = -20.0 * (double)k * exp(1.0 - (double)k);
            cst[80 + k] = (double)(float)v;
        }
    }
}

/* quantize 2 floats -> 4 digit-u16s. fp32 path: f*2^31 is a power-of-two
   scale (EXACT in fp32), rintf == rint(double) bit-for-bit here (|w1|<0.5).
   Digit recurrence via (v+128)>>8 (identical to sext8-subtract form). */
__device__ __forceinline__ void quant2(float2 f, unsigned short dg[4]) {
    int v0 = (int)rintf(f.x * 2147483648.0f);
    int v1 = (int)rintf(f.y * 2147483648.0f);
    int r0 = (v0 + 128) >> 8, s0 = (v1 + 128) >> 8;
    int r1 = (r0 + 128) >> 8, s1 = (s0 + 128) >> 8;
    int r2 = (r1 + 128) >> 8, s2 = (s1 + 128) >> 8;
    dg[0] = (unsigned short)((v0 & 0xFF) | ((v1 & 0xFF) << 8));
    dg[1] = (unsigned short)((r0 & 0xFF) | ((s0 & 0xFF) << 8));
    dg[2] = (unsigned short)((r1 & 0xFF) | ((s1 & 0xFF) << 8));
    dg[3] = (unsigned short)((r2 & 0xFF) | ((s2 & 0xFF) << 8));
}

/* unpack 16 mask bits -> 16 i8 (R4-verified byte order) + 4 digit MFMAs */
#define K3_COMPUTE(A0, A1, A2, A3, BV, TTI)                                        \
    {                                                                              \
        i32x4 bf;                                                                  \
        _Pragma("unroll")                                                          \
        for (int i_ = 0; i_ < 4; ++i_)                                             \
            bf[i_] = (int)((((BV >> (4 * i_)) & 0xFu) * 0x00204081u) & 0x01010101u); \
        acc[TTI][0] = __builtin_amdgcn_mfma_i32_16x16x64_i8(A0, bf, acc[TTI][0], 0, 0, 0); \
        acc[TTI][1] = __builtin_amdgcn_mfma_i32_16x16x64_i8(A1, bf, acc[TTI][1], 0, 0, 0); \
        acc[TTI][2] = __builtin_amdgcn_mfma_i32_16x16x64_i8(A2, bf, acc[TTI][2], 0, 0, 0); \
        acc[TTI][3] = __builtin_amdgcn_mfma_i32_16x16x64_i8(A3, bf, acc[TTI][3], 0, 0, 0); \
    }

/* one pipeline iteration at compile-time roles: compute step S from
   buf[S&1] + BU regs; quantize floats(S+1)=FQ into buf[(S+1)&1]; issue
   float-load(S+2) into FI and B-load(S+1) into BL. Guarded (uniform). */
#define K_ITER(S, FQ, FI, BU0, BU1, BU2, BU3, BU4, BL0, BL1, BL2, BL3, BL4)        \
    {                                                                              \
        int s_ = (S);                                                              \
        if (s_ < steps) {                                                          \
            int pf = s_ + 2; if (pf > steps - 1) pf = steps - 1;                   \
            FI = *(const float2*)(fbase + (size_t)pf * 64);                        \
            int sn = s_ + 1; if (sn > steps - 1) sn = steps - 1;                   \
            const unsigned short* bpn = bp0 + (size_t)sn * BSTRIDE;                \
            BL0 = bpn[0]; BL1 = bpn[64]; BL2 = bpn[128]; BL3 = bpn[192]; BL4 = bpn[256]; \
            const char* lp = &Abuf[s_ & 1][0] + lofs;                              \
            i32x4 a0 = *(const i32x4*)(lp);                                        \
            i32x4 a1 = *(const i32x4*)(lp + 1024);                                 \
            i32x4 a2 = *(const i32x4*)(lp + 2048);                                 \
            i32x4 a3 = *(const i32x4*)(lp + 3072);                                 \
            K3_COMPUTE(a0, a1, a2, a3, BU0, 0)                                     \
            K3_COMPUTE(a0, a1, a2, a3, BU1, 1)                                     \
            K3_COMPUTE(a0, a1, a2, a3, BU2, 2)                                     \
            K3_COMPUTE(a0, a1, a2, a3, BU3, 3)                                     \
            K3_COMPUTE(a0, a1, a2, a3, BU4, 4)                                     \
            unsigned short dg[4];                                                  \
            quant2(FQ, dg);                                                        \
            char* wb = &Abuf[(s_ + 1) & 1][0] + wofs;                              \
            *(unsigned short*)(wb)        = dg[0];                                 \
            *(unsigned short*)(wb + 1024) = dg[1];                                 \
            *(unsigned short*)(wb + 2048) = dg[2];                                 \
            *(unsigned short*)(wb + 3072) = dg[3];                                 \
        }                                                                          \
        __syncthreads();                                                           \
    }

/* K3M2: exact i8 MFMA GEMM with fused on-the-fly fp32 quantization.
   Chunk-swizzled LDS (CSWZ on write AND read) kills ds_write conflicts. */
__global__ __launch_bounds__(512, 4) void k3m2(const float* __restrict__ w1,
                                               const u64* __restrict__ xbw,
                                               u64* __restrict__ z1p) {
    __shared__ __align__(16) char Abuf[2][4096];
    int m16 = blockIdx.x, ksl = blockIdx.y;
    int tid = threadIdx.x;
    int l = tid & 63, wid = tid >> 6;          /* wid = n-slice 0..7 */
    int o  = tid >> 5;                         /* 0..15: my w1 row    */
    int kp = tid & 31;                         /* float2 index: k = 2kp */

    int wl0 = ksl * WPS;
    int wend = wl0 + WPS; if (wend > NWRD) wend = NWRD;
    int steps = wend - wl0;          /* 98 or 93 */

    i32x4 acc[5][NDIG];
    #pragma unroll
    for (int i = 0; i < 5; ++i)
        #pragma unroll
        for (int d = 0; d < NDIG; ++d) acc[i][d] = (i32x4){0, 0, 0, 0};

    const float* fbase = w1 + (size_t)(m16 * 16 + o) * F1 + (size_t)wl0 * 64 + kp * 2;
    const unsigned short* bp0 =
        (const unsigned short*)((const char*)xbw
            + ((size_t)wl0 * NPAD
               + (size_t)(wid * 80 + (l & 15))) * 8
            + (l >> 4) * 2);
    const int lofs = CSWZ(l) * 16;
    const int wc = (kp >> 3) * 16 + o;
    const int wofs = CSWZ(wc) * 16 + (kp & 7) * 2;

    float2 fA, fB, fC;
    unsigned bA0, bA1, bA2, bA3, bA4;
    unsigned bB0, bB1, bB2, bB3, bB4;
    unsigned bC0, bC1, bC2, bC3, bC4;

    /* prologue: quantize step 0 into buf0; prefetch floats(1); B(0) */
    fA = *(const float2*)(fbase);
    {
        unsigned short dg[4];
        quant2(fA, dg);
        char* wb = &Abuf[0][0] + wofs;
        *(unsigned short*)(wb)        = dg[0];
        *(unsigned short*)(wb + 1024) = dg[1];
        *(unsigned short*)(wb + 2048) = dg[2];
        *(unsigned short*)(wb + 3072) = dg[3];
    }
    fB = *(const float2*)(fbase + ((steps > 1) ? 64 : 0));
    bA0 = bp0[0]; bA1 = bp0[64]; bA2 = bp0[128]; bA3 = bp0[192]; bA4 = bp0[256];
    __syncthreads();

    int smax3 = ((steps + 2) / 3) * 3;
    #pragma unroll 1
    for (int sb = 0; sb < smax3; sb += 3) {
        K_ITER(sb,     fB, fC, bA0, bA1, bA2, bA3, bA4, bB0, bB1, bB2, bB3, bB4)
        K_ITER(sb + 1, fC, fA, bB0, bB1, bB2, bB3, bB4, bC0, bC1, bC2, bC3, bC4)
        K_ITER(sb + 2, fA, fB, bC0, bC1, bC2, bC3, bC4, bA0, bA1, bA2, bA3, bA4)
    }

    /* atomic-free epilogue: plain stores into this ksplit's partial plane */
    u64* zp = z1p + (size_t)ksl * O1 * NPAD;
    #pragma unroll
    for (int tt = 0; tt < 5; ++tt) {
        int n = wid * 80 + tt * 16 + (l & 15);
        #pragma unroll
        for (int r = 0; r < 4; ++r) {
            int oo = m16 * 16 + (l >> 4) * 4 + r;
            long long c = (long long)acc[tt][0][r]
                        + ((long long)acc[tt][1][r] << 8)
                        + ((long long)acc[tt][2][r] << 16)
                        + ((long long)acc[tt][3][r] << 24);
            zp[(size_t)oo * NPAD + n] = (u64)c;
        }
    }
}

/* dense fallback GEMM1 (used only if ws too small) -> z1f fp64 */
__global__ __launch_bounds__(256) void k_dense_gemm1(const float* __restrict__ x,
                                                     const float* __restrict__ w1,
                                                     double* __restrict__ z1) {
    int lin = blockIdx.x;
    int ot = lin % 25; int tt = (lin / 25) % 5; int b = lin / 125;
    int t0 = tt * 64, o0 = ot * 32;
    __shared__ float xs[64][64];
    __shared__ float wsh[32][64];
    int ti = threadIdx.x & 63, og = threadIdx.x >> 6;
    double dacc[8] = {0, 0, 0, 0, 0, 0, 0, 0};
    for (int fc = 0; fc < F1; fc += 64) {
        __syncthreads();
        for (int e = threadIdx.x; e < 64 * 64; e += 256) {
            int r = e >> 6, c = e & 63;
            int t = t0 + c;
            xs[r][c] = (t < TT) ? x[((size_t)b * F1 + fc + r) * TT + t] : 0.0f;
        }
        for (int e = threadIdx.x; e < 32 * 64; e += 256) {
            int r = e >> 6, c = e & 63;
            wsh[r][c] = w1[(size_t)(o0 + r) * F1 + fc + c];
        }
        __syncthreads();
        float facc[8] = {0, 0, 0, 0, 0, 0, 0, 0};
        for (int ff = 0; ff < 64; ++ff) {
            float xv = xs[ff][ti];
            #pragma unroll
            for (int oo = 0; oo < 8; ++oo) facc[oo] += wsh[og * 8 + oo][ff] * xv;
        }
        #pragma unroll
        for (int oo = 0; oo < 8; ++oo) dacc[oo] += (double)facc[oo];
    }
    int t = t0 + ti;
    if (t < TT) {
        #pragma unroll
        for (int oo = 0; oo < 8; ++oo) {
            int o = o0 + og * 8 + oo;
            z1[((size_t)(b * O1 + o)) * TT + t] = dacc[oo];
        }
    }
}

/* K_CONV1: exact i64 partial-sum + scale + psp conv (t-parallel). */
__global__ __launch_bounds__(320) void k_conv1(const u64* __restrict__ z1p,
                                               const double* __restrict__ z1f,
                                               double* __restrict__ u1,
                                               const double* __restrict__ cst,
                                               int mode) {
    __shared__ double zs[TT];
    __shared__ double ck[KSRM];
    int row = blockIdx.x;                 /* b*800 + o */
    int b = row / O1, o = row % O1;
    int t = threadIdx.x;
    if (t < KSRM) ck[t] = cst[t];
    if (t < TT) {
        double z;
        if (mode == 0) {
            long long c = 0;
            size_t base = (size_t)o * NPAD + b * 320 + t;
            #pragma unroll
            for (int g = 0; g < KSPL; ++g)
                c += (long long)z1p[(size_t)g * O1 * NPAD + base];
            z = (double)c * 4.656612873077393e-10;          /* 2^-31 */
        } else {
            z = z1f[(size_t)row * TT + t];
        }
        zs[t] = z;
    }
    __syncthreads();
    if (t < TT) {
        int kmax = t < (KSRM - 1) ? t : (KSRM - 1);
        double acc = 0.0;
        for (int k = 0; k <= kmax; ++k) acc += ck[k] * zs[t - k];
        u1[(size_t)row * TT + t] = acc;
    }
}

/* K_SCAN: thread-per-row spike scan, branch-free cndmask chains with
   tree-summed refractory term (fp64 reassoc ~1e-14 << spike margin). */
__global__ __launch_bounds__(64) void k_scan(const double* __restrict__ u,
                                             float* __restrict__ s,
                                             const double* __restrict__ cst,
                                             int nrows) {
    int row = blockIdx.x * 64 + threadIdx.x;
    if (row >= nrows) return;
    double rk1 = cst[81], rk2 = cst[82], rk3 = cst[83], rk4 = cst[84];
    double rk5 = cst[85], rk6 = cst[86], rk7 = cst[87], rk8 = cst[88];
    double rk9 = cst[89], rk10 = cst[90];
    const double* ur = u + (size_t)row * TT;
    float* sr = s + (size_t)row * TT;
    unsigned h = 0;
    #pragma unroll 4
    for (int t = 0; t < TT; ++t) {
        double a  = ((h & 1u)   ? rk1 : 0.0) + ((h & 2u)   ? rk2  : 0.0);
        double b2 = ((h & 4u)   ? rk3 : 0.0) + ((h & 8u)   ? rk4  : 0.0);
        double c2 = ((h & 16u)  ? rk5 : 0.0) + ((h & 32u)  ? rk6  : 0.0);
        double d2 = ((h & 64u)  ? rk7 : 0.0) + ((h & 128u) ? rk8  : 0.0);
        double e2 = ((h & 256u) ? rk9 : 0.0) + ((h & 512u) ? rk10 : 0.0);
        double ueff = ur[t] + (((a + b2) + (c2 + d2)) + e2);
        unsigned sp = (ueff >= 10.0) ? 1u : 0u;
        sr[t] = (float)sp;
        h = (h << 1) | sp;
    }
}

/* K_GEMM2C: fused GEMM2 + psp conv for layer 2 (both t-parallel). */
__global__ __launch_bounds__(320) void k_gemm2c(const float* __restrict__ s1t,
                                                const float* __restrict__ w2,
                                                double* __restrict__ u2,
                                                const double* __restrict__ cst) {
    __shared__ float wsm[O1];
    __shared__ double zs[TT];
    __shared__ double ck[KSRM];
    int bo = blockIdx.x;
    int b = bo / O2N, o2 = bo % O2N;
    int t = threadIdx.x;
    if (t < KSRM) ck[t] = cst[t];
    for (int f = t; f < O1; f += 320) wsm[f] = w2[(size_t)o2 * O1 + f];
    __syncthreads();
    if (t < TT) {
        double acc = 0.0;
        #pragma unroll 4
        for (int f = 0; f < O1; ++f)
            acc += (double)(wsm[f] * s1t[((size_t)(b * O1 + f)) * TT + t]);
        zs[t] = acc;
    }
    __syncthreads();
    if (t < TT) {
        int kmax = t < (KSRM - 1) ? t : (KSRM - 1);
        double acc = 0.0;
        for (int k = 0; k <= kmax; ++k) acc += ck[k] * zs[t - k];
        u2[(size_t)bo * TT + t] = acc;
    }
}

extern "C" void kernel_launch(void* const* d_in, const int* in_sizes, int n_in,
                              void* d_out, int out_size, void* d_ws, size_t ws_size,
                              hipStream_t stream) {
    const float* x  = (const float*)d_in[0];
    const float* w1 = (const float*)d_in[1];
    const float* w2 = (const float*)d_in[2];
    float* out = (float*)d_out;
    char* ws = (char*)d_ws;

    double* cst = (double*)(ws + OFF_CONST);
    u64*    z1p = (u64*)   (ws + OFF_Z1P);
    float*  s1t = (float*) (ws + OFF_S1T);
    u64*    xbw = (u64*)   (ws + OFF_XBW);
    double* z1f = (double*)(ws + OFF_Z1F);
    double* u1  = (double*)(ws + OFF_U1);
    double* u2  = (double*)(ws + OFF_U2);

    int mode;
    if (ws_size >= NEED_SPARSE) {
        mode = 0;
        k_pre<<<NB_K1 + 1, 256, 0, stream>>>(x, xbw, cst);
        k3m2<<<dim3(M16, KSPL), 512, 0, stream>>>(w1, xbw, z1p);
    } else {
        mode = 1;
        k0_init<<<1, 128, 0, stream>>>(cst);
        k_dense_gemm1<<<250, 256, 0, stream>>>(x, w1, z1f);
    }

    k_conv1<<<BB * O1, 320, 0, stream>>>(z1p, z1f, u1, cst, mode);
    k_scan<<<(BB * O1 + 63) / 64, 64, 0, stream>>>(u1, s1t, cst, BB * O1);
    k_gemm2c<<<BB * O2N, 320, 0, stream>>>(s1t, w2, u2, cst);
    k_scan<<<(BB * O2N + 63) / 64, 64, 0, stream>>>(u2, out, cst, BB * O2N);
    (void)in_sizes; (void)n_in; (void)out_size;
}

// Round 24
// 282.100 us; speedup vs baseline: 1.6728x; 1.0809x over previous
//
#include <hip/hip_runtime.h>

#define F1 62400
#define O1 800
#define O2N 100
#define TT 300
#define BB 2
#define NWRD 975        /* 64-bit f-words */
#define KSRM 77
#define KREF 11
#define M16 50          /* M-blocks of 16 o */
#define NPAD 640        /* n = b*320 + t */
#define NDIG 4          /* base-256 digits of rint(w1 * 2^31) — exact (R4-proven) */
#define KSPL 10         /* k-splits (proven best) */
#define WPS 98          /* words per split (last split: 93) */
#define BSTRIDE ((size_t)NPAD * 4)

/* k_pre grid partition */
#define NB_K1 2438      /* ceil(2*975*5*64 / 256) */

typedef unsigned long long u64;
typedef int i32x4 __attribute__((ext_vector_type(4)));

/* chunk swizzle (T2, both-sides): bijective within each 16-chunk group */
#define CSWZ(c) ((c) ^ ((((c) >> 4) & 3) << 1))

/* ---- ws layout (bytes); NEED ~56 MB ---- */
#define OFF_CONST 0ull
#define OFF_Z1P  1024ull                          /* 10*800*640*8 = 40,960,000 */
#define OFF_S1T  (OFF_Z1P + 40960000ull)
#define OFF_XBW  (OFF_S1T + 1920000ull)           /* 975*640*8 (320-stride, pad 0) */
#define OFF_Z1F  (OFF_XBW + 4992000ull)
#define OFF_U1   (OFF_Z1F + 3840000ull)
#define OFF_U2   (OFF_U1 + 3840000ull)
#define NEED_SPARSE (OFF_U2 + 480000ull)          /* ~56.0 MB */

/* K0: SRM/REF kernels, fp64 rounded through fp32 (fallback path only). */
__global__ void k0_init(double* c) {
    int k = threadIdx.x;
    if (k < KSRM) {
        double v = ((double)k / 10.0) * exp(1.0 - (double)k / 10.0);
        c[k] = (double)(float)v;
    }
    if (k < KREF) {
        double v = -20.0 * (double)k * exp(1.0 - (double)k);
        c[80 + k] = (double)(float)v;
    }
}

/* K_PRE: bitmask build + constants. */
__global__ __launch_bounds__(256) void k_pre(const float* __restrict__ x,
                                             u64* __restrict__ xbw,
                                             double* __restrict__ cst) {
    int blk = blockIdx.x;
    if (blk < NB_K1) {
        const int NTG = 5;
        int gw = (blk * 256 + (int)threadIdx.x) >> 6;
        int lane = threadIdx.x & 63;
        if (gw >= BB * NWRD * NTG) return;
        int b  = gw / (NWRD * NTG);
        int r  = gw % (NWRD * NTG);
        int fw = r / NTG;
        int tg = r % NTG;
        int t = tg * 64 + lane;
        bool act = (t < TT);
        int tc = act ? t : 0;
        const float* xp = x + ((size_t)(b * F1 + (fw << 6))) * TT + tc;
        unsigned lo = 0, hi = 0;
        #pragma unroll
        for (int j = 0; j < 32; ++j)
            lo |= (xp[(size_t)j * TT] > 0.5f ? 1u : 0u) << j;
        #pragma unroll
        for (int j = 0; j < 32; ++j)
            hi |= (xp[(size_t)(j + 32) * TT] > 0.5f ? 1u : 0u) << j;
        u64 mval = act ? (((u64)hi << 32) | lo) : 0ull;
        xbw[(size_t)fw * NPAD + b * 320 + t] = mval;
    } else {
        int k = threadIdx.x;
        if (k < KSRM) {
            double v = ((double)k / 10.0) * exp(1.0 - (double)k / 10.0);
            cst[k] = (double)(float)v;
        }
        if (k < KREF) {
            double v = -20.0 * (double)k * exp(1.0 - (double)k);
            cst[80 + k] = (double)(float)v;
        }
    }
}

/* quantize 2 floats -> 4 digit-u16s. fp32 path: f*2^31 is a power-of-two
   scale (EXACT in fp32), rintf == rint(double) bit-for-bit here (|w1|<0.5). */
__device__ __forceinline__ void quant2(float2 f, unsigned short dg[4]) {
    int v0 = (int)rintf(f.x * 2147483648.0f);
    int v1 = (int)rintf(f.y * 2147483648.0f);
    int r0 = (v0 + 128) >> 8, s0 = (v1 + 128) >> 8;
    int r1 = (r0 + 128) >> 8, s1 = (s0 + 128) >> 8;
    int r2 = (r1 + 128) >> 8, s2 = (s1 + 128) >> 8;
    dg[0] = (unsigned short)((v0 & 0xFF) | ((v1 & 0xFF) << 8));
    dg[1] = (unsigned short)((r0 & 0xFF) | ((s0 & 0xFF) << 8));
    dg[2] = (unsigned short)((r1 & 0xFF) | ((s1 & 0xFF) << 8));
    dg[3] = (unsigned short)((r2 & 0xFF) | ((s2 & 0xFF) << 8));
}

/* unpack 16 mask bits -> 16 i8 (R4-verified byte order) + 4 digit MFMAs */
#define K3_COMPUTE(A0, A1, A2, A3, BV, TTI)                                        \
    {                                                                              \
        i32x4 bf;                                                                  \
        _Pragma("unroll")                                                          \
        for (int i_ = 0; i_ < 4; ++i_)                                             \
            bf[i_] = (int)((((BV >> (4 * i_)) & 0xFu) * 0x00204081u) & 0x01010101u); \
        acc[TTI][0] = __builtin_amdgcn_mfma_i32_16x16x64_i8(A0, bf, acc[TTI][0], 0, 0, 0); \
        acc[TTI][1] = __builtin_amdgcn_mfma_i32_16x16x64_i8(A1, bf, acc[TTI][1], 0, 0, 0); \
        acc[TTI][2] = __builtin_amdgcn_mfma_i32_16x16x64_i8(A2, bf, acc[TTI][2], 0, 0, 0); \
        acc[TTI][3] = __builtin_amdgcn_mfma_i32_16x16x64_i8(A3, bf, acc[TTI][3], 0, 0, 0); \
    }

/* one pipeline iteration at compile-time roles (R22/R23-proven). */
#define K_ITER(S, FQ, FI, BU0, BU1, BU2, BU3, BU4, BL0, BL1, BL2, BL3, BL4)        \
    {                                                                              \
        int s_ = (S);                                                              \
        if (s_ < steps) {                                                          \
            int pf = s_ + 2; if (pf > steps - 1) pf = steps - 1;                   \
            FI = *(const float2*)(fbase + (size_t)pf * 64);                        \
            int sn = s_ + 1; if (sn > steps - 1) sn = steps - 1;                   \
            const unsigned short* bpn = bp0 + (size_t)sn * BSTRIDE;                \
            BL0 = bpn[0]; BL1 = bpn[64]; BL2 = bpn[128]; BL3 = bpn[192]; BL4 = bpn[256]; \
            const char* lp = &Abuf[s_ & 1][0] + lofs;                              \
            i32x4 a0 = *(const i32x4*)(lp);                                        \
            i32x4 a1 = *(const i32x4*)(lp + 1024);                                 \
            i32x4 a2 = *(const i32x4*)(lp + 2048);                                 \
            i32x4 a3 = *(const i32x4*)(lp + 3072);                                 \
            K3_COMPUTE(a0, a1, a2, a3, BU0, 0)                                     \
            K3_COMPUTE(a0, a1, a2, a3, BU1, 1)                                     \
            K3_COMPUTE(a0, a1, a2, a3, BU2, 2)                                     \
            K3_COMPUTE(a0, a1, a2, a3, BU3, 3)                                     \
            K3_COMPUTE(a0, a1, a2, a3, BU4, 4)                                     \
            unsigned short dg[4];                                                  \
            quant2(FQ, dg);                                                        \
            char* wb = &Abuf[(s_ + 1) & 1][0] + wofs;                              \
            *(unsigned short*)(wb)        = dg[0];                                 \
            *(unsigned short*)(wb + 1024) = dg[1];                                 \
            *(unsigned short*)(wb + 2048) = dg[2];                                 \
            *(unsigned short*)(wb + 3072) = dg[3];                                 \
        }                                                                          \
        __syncthreads();                                                           \
    }

/* K3M2: exact i8 MFMA GEMM with fused on-the-fly fp32 quantization
   (R23-proven, unchanged). */
__global__ __launch_bounds__(512, 4) void k3m2(const float* __restrict__ w1,
                                               const u64* __restrict__ xbw,
                                               u64* __restrict__ z1p) {
    __shared__ __align__(16) char Abuf[2][4096];
    int m16 = blockIdx.x, ksl = blockIdx.y;
    int tid = threadIdx.x;
    int l = tid & 63, wid = tid >> 6;
    int o  = tid >> 5;
    int kp = tid & 31;

    int wl0 = ksl * WPS;
    int wend = wl0 + WPS; if (wend > NWRD) wend = NWRD;
    int steps = wend - wl0;

    i32x4 acc[5][NDIG];
    #pragma unroll
    for (int i = 0; i < 5; ++i)
        #pragma unroll
        for (int d = 0; d < NDIG; ++d) acc[i][d] = (i32x4){0, 0, 0, 0};

    const float* fbase = w1 + (size_t)(m16 * 16 + o) * F1 + (size_t)wl0 * 64 + kp * 2;
    const unsigned short* bp0 =
        (const unsigned short*)((const char*)xbw
            + ((size_t)wl0 * NPAD
               + (size_t)(wid * 80 + (l & 15))) * 8
            + (l >> 4) * 2);
    const int lofs = CSWZ(l) * 16;
    const int wc = (kp >> 3) * 16 + o;
    const int wofs = CSWZ(wc) * 16 + (kp & 7) * 2;

    float2 fA, fB, fC;
    unsigned bA0, bA1, bA2, bA3, bA4;
    unsigned bB0, bB1, bB2, bB3, bB4;
    unsigned bC0, bC1, bC2, bC3, bC4;

    fA = *(const float2*)(fbase);
    {
        unsigned short dg[4];
        quant2(fA, dg);
        char* wb = &Abuf[0][0] + wofs;
        *(unsigned short*)(wb)        = dg[0];
        *(unsigned short*)(wb + 1024) = dg[1];
        *(unsigned short*)(wb + 2048) = dg[2];
        *(unsigned short*)(wb + 3072) = dg[3];
    }
    fB = *(const float2*)(fbase + ((steps > 1) ? 64 : 0));
    bA0 = bp0[0]; bA1 = bp0[64]; bA2 = bp0[128]; bA3 = bp0[192]; bA4 = bp0[256];
    __syncthreads();

    int smax3 = ((steps + 2) / 3) * 3;
    #pragma unroll 1
    for (int sb = 0; sb < smax3; sb += 3) {
        K_ITER(sb,     fB, fC, bA0, bA1, bA2, bA3, bA4, bB0, bB1, bB2, bB3, bB4)
        K_ITER(sb + 1, fC, fA, bB0, bB1, bB2, bB3, bB4, bC0, bC1, bC2, bC3, bC4)
        K_ITER(sb + 2, fA, fB, bC0, bC1, bC2, bC3, bC4, bA0, bA1, bA2, bA3, bA4)
    }

    u64* zp = z1p + (size_t)ksl * O1 * NPAD;
    #pragma unroll
    for (int tt = 0; tt < 5; ++tt) {
        int n = wid * 80 + tt * 16 + (l & 15);
        #pragma unroll
        for (int r = 0; r < 4; ++r) {
            int oo = m16 * 16 + (l >> 4) * 4 + r;
            long long c = (long long)acc[tt][0][r]
                        + ((long long)acc[tt][1][r] << 8)
                        + ((long long)acc[tt][2][r] << 16)
                        + ((long long)acc[tt][3][r] << 24);
            zp[(size_t)oo * NPAD + n] = (u64)c;
        }
    }
}

/* dense fallback GEMM1 (used only if ws too small) -> z1f fp64 */
__global__ __launch_bounds__(256) void k_dense_gemm1(const float* __restrict__ x,
                                                     const float* __restrict__ w1,
                                                     double* __restrict__ z1) {
    int lin = blockIdx.x;
    int ot = lin % 25; int tt = (lin / 25) % 5; int b = lin / 125;
    int t0 = tt * 64, o0 = ot * 32;
    __shared__ float xs[64][64];
    __shared__ float wsh[32][64];
    int ti = threadIdx.x & 63, og = threadIdx.x >> 6;
    double dacc[8] = {0, 0, 0, 0, 0, 0, 0, 0};
    for (int fc = 0; fc < F1; fc += 64) {
        __syncthreads();
        for (int e = threadIdx.x; e < 64 * 64; e += 256) {
            int r = e >> 6, c = e & 63;
            int t = t0 + c;
            xs[r][c] = (t < TT) ? x[((size_t)b * F1 + fc + r) * TT + t] : 0.0f;
        }
        for (int e = threadIdx.x; e < 32 * 64; e += 256) {
            int r = e >> 6, c = e & 63;
            wsh[r][c] = w1[(size_t)(o0 + r) * F1 + fc + c];
        }
        __syncthreads();
        float facc[8] = {0, 0, 0, 0, 0, 0, 0, 0};
        for (int ff = 0; ff < 64; ++ff) {
            float xv = xs[ff][ti];
            #pragma unroll
            for (int oo = 0; oo < 8; ++oo) facc[oo] += wsh[og * 8 + oo][ff] * xv;
        }
        #pragma unroll
        for (int oo = 0; oo < 8; ++oo) dacc[oo] += (double)facc[oo];
    }
    int t = t0 + ti;
    if (t < TT) {
        #pragma unroll
        for (int oo = 0; oo < 8; ++oo) {
            int o = o0 + og * 8 + oo;
            z1[((size_t)(b * O1 + o)) * TT + t] = dacc[oo];
        }
    }
}

/* K_CONV1: exact i64 partial-sum + scale + psp conv (t-parallel). */
__global__ __launch_bounds__(320) void k_conv1(const u64* __restrict__ z1p,
                                               const double* __restrict__ z1f,
                                               double* __restrict__ u1,
                                               const double* __restrict__ cst,
                                               int mode) {
    __shared__ double zs[TT];
    __shared__ double ck[KSRM];
    int row = blockIdx.x;                 /* b*800 + o */
    int b = row / O1, o = row % O1;
    int t = threadIdx.x;
    if (t < KSRM) ck[t] = cst[t];
    if (t < TT) {
        double z;
        if (mode == 0) {
            long long c = 0;
            size_t base = (size_t)o * NPAD + b * 320 + t;
            #pragma unroll
            for (int g = 0; g < KSPL; ++g)
                c += (long long)z1p[(size_t)g * O1 * NPAD + base];
            z = (double)c * 4.656612873077393e-10;          /* 2^-31 */
        } else {
            z = z1f[(size_t)row * TT + t];
        }
        zs[t] = z;
    }
    __syncthreads();
    if (t < TT) {
        int kmax = t < (KSRM - 1) ? t : (KSRM - 1);
        double acc = 0.0;
        for (int k = 0; k <= kmax; ++k) acc += ck[k] * zs[t - k];
        u1[(size_t)row * TT + t] = acc;
    }
}

/* K_SCAN: thread-per-row spike scan, 30-deep register load pipeline (G7):
   the next 30 row-values are issued before the current 30 are consumed, so
   the ~500-cyc L2 latency hides under 30 steps of VALU. All inner loops
   fully unrolled -> static register indices (no scratch). Arithmetic order
   per step identical to the passing R23 scan. */
__global__ __launch_bounds__(64) void k_scan(const double* __restrict__ u,
                                             float* __restrict__ s,
                                             const double* __restrict__ cst,
                                             int nrows) {
    int row = blockIdx.x * 64 + threadIdx.x;
    if (row >= nrows) return;
    double rk1 = cst[81], rk2 = cst[82], rk3 = cst[83], rk4 = cst[84];
    double rk5 = cst[85], rk6 = cst[86], rk7 = cst[87], rk8 = cst[88];
    double rk9 = cst[89], rk10 = cst[90];
    const double* ur = u + (size_t)row * TT;
    float* sr = s + (size_t)row * TT;
    double buf[30];
    #pragma unroll
    for (int j = 0; j < 30; ++j) buf[j] = ur[j];
    unsigned h = 0;
    #pragma unroll 1
    for (int tb = 0; tb < TT; tb += 30) {          /* 10 iterations */
        double nxt[30];
        #pragma unroll
        for (int j = 0; j < 30; ++j) {
            int tn = tb + 30 + j; if (tn > TT - 1) tn = TT - 1;
            nxt[j] = ur[tn];                       /* independent prefetch */
        }
        #pragma unroll
        for (int j = 0; j < 30; ++j) {
            double a  = ((h & 1u)   ? rk1 : 0.0) + ((h & 2u)   ? rk2  : 0.0);
            double b2 = ((h & 4u)   ? rk3 : 0.0) + ((h & 8u)   ? rk4  : 0.0);
            double c2 = ((h & 16u)  ? rk5 : 0.0) + ((h & 32u)  ? rk6  : 0.0);
            double d2 = ((h & 64u)  ? rk7 : 0.0) + ((h & 128u) ? rk8  : 0.0);
            double e2 = ((h & 256u) ? rk9 : 0.0) + ((h & 512u) ? rk10 : 0.0);
            double ueff = buf[j] + (((a + b2) + (c2 + d2)) + e2);
            unsigned sp = (ueff >= 10.0) ? 1u : 0u;
            sr[tb + j] = (float)sp;
            h = (h << 1) | sp;
        }
        #pragma unroll
        for (int j = 0; j < 30; ++j) buf[j] = nxt[j];
    }
}

/* K_GEMM2C: fused GEMM2 + psp conv for layer 2 (both t-parallel). */
__global__ __launch_bounds__(320) void k_gemm2c(const float* __restrict__ s1t,
                                                const float* __restrict__ w2,
                                                double* __restrict__ u2,
                                                const double* __restrict__ cst) {
    __shared__ float wsm[O1];
    __shared__ double zs[TT];
    __shared__ double ck[KSRM];
    int bo = blockIdx.x;
    int b = bo / O2N, o2 = bo % O2N;
    int t = threadIdx.x;
    if (t < KSRM) ck[t] = cst[t];
    for (int f = t; f < O1; f += 320) wsm[f] = w2[(size_t)o2 * O1 + f];
    __syncthreads();
    if (t < TT) {
        double acc = 0.0;
        #pragma unroll 4
        for (int f = 0; f < O1; ++f)
            acc += (double)(wsm[f] * s1t[((size_t)(b * O1 + f)) * TT + t]);
        zs[t] = acc;
    }
    __syncthreads();
    if (t < TT) {
        int kmax = t < (KSRM - 1) ? t : (KSRM - 1);
        double acc = 0.0;
        for (int k = 0; k <= kmax; ++k) acc += ck[k] * zs[t - k];
        u2[(size_t)bo * TT + t] = acc;
    }
}

extern "C" void kernel_launch(void* const* d_in, const int* in_sizes, int n_in,
                              void* d_out, int out_size, void* d_ws, size_t ws_size,
                              hipStream_t stream) {
    const float* x  = (const float*)d_in[0];
    const float* w1 = (const float*)d_in[1];
    const float* w2 = (const float*)d_in[2];
    float* out = (float*)d_out;
    char* ws = (char*)d_ws;

    double* cst = (double*)(ws + OFF_CONST);
    u64*    z1p = (u64*)   (ws + OFF_Z1P);
    float*  s1t = (float*) (ws + OFF_S1T);
    u64*    xbw = (u64*)   (ws + OFF_XBW);
    double* z1f = (double*)(ws + OFF_Z1F);
    double* u1  = (double*)(ws + OFF_U1);
    double* u2  = (double*)(ws + OFF_U2);

    int mode;
    if (ws_size >= NEED_SPARSE) {
        mode = 0;
        k_pre<<<NB_K1 + 1, 256, 0, stream>>>(x, xbw, cst);
        k3m2<<<dim3(M16, KSPL), 512, 0, stream>>>(w1, xbw, z1p);
    } else {
        mode = 1;
        k0_init<<<1, 128, 0, stream>>>(cst);
        k_dense_gemm1<<<250, 256, 0, stream>>>(x, w1, z1f);
    }

    k_conv1<<<BB * O1, 320, 0, stream>>>(z1p, z1f, u1, cst, mode);
    k_scan<<<(BB * O1 + 63) / 64, 64, 0, stream>>>(u1, s1t, cst, BB * O1);
    k_gemm2c<<<BB * O2N, 320, 0, stream>>>(s1t, w2, u2, cst);
    k_scan<<<(BB * O2N + 63) / 64, 64, 0, stream>>>(u2, out, cst, BB * O2N);
    (void)in_sizes; (void)n_in; (void)out_size;
}

// Round 25
// 270.314 us; speedup vs baseline: 1.7457x; 1.0436x over previous
//
#include <hip/hip_runtime.h>

#define F1 62400
#define O1 800
#define O2N 100
#define TT 300
#define BB 2
#define NWRD 975        /* 64-bit f-words */
#define KSRM 77
#define KREF 11
#define M32 25          /* M-blocks of 32 o */
#define NPAD 640        /* n = b*320 + t */
#define NDIG 4          /* base-256 digits of rint(w1 * 2^31) — exact (R4-proven) */
#define KSPL 10         /* k-splits */
#define WPS 98          /* words per split (last split: 93) */
#define BSTRIDE ((size_t)NPAD * 4)

/* k_pre grid partition */
#define NB_K1 2438      /* ceil(2*975*5*64 / 256) */

typedef unsigned long long u64;
typedef int i32x4 __attribute__((ext_vector_type(4)));

/* chunk swizzle (T2, both-sides): bijective within each 16-chunk group */
#define CSWZ(c) ((c) ^ ((((c) >> 4) & 3) << 1))

/* ---- ws layout (bytes); NEED ~56 MB ---- */
#define OFF_CONST 0ull
#define OFF_Z1P  1024ull                          /* 10*800*640*8 = 40,960,000 */
#define OFF_S1T  (OFF_Z1P + 40960000ull)
#define OFF_XBW  (OFF_S1T + 1920000ull)           /* 975*640*8 (320-stride, pad 0) */
#define OFF_Z1F  (OFF_XBW + 4992000ull)
#define OFF_U1   (OFF_Z1F + 3840000ull)
#define OFF_U2   (OFF_U1 + 3840000ull)
#define NEED_SPARSE (OFF_U2 + 480000ull)          /* ~56.0 MB */

/* K0: SRM/REF kernels, fp64 rounded through fp32 (fallback path only). */
__global__ void k0_init(double* c) {
    int k = threadIdx.x;
    if (k < KSRM) {
        double v = ((double)k / 10.0) * exp(1.0 - (double)k / 10.0);
        c[k] = (double)(float)v;
    }
    if (k < KREF) {
        double v = -20.0 * (double)k * exp(1.0 - (double)k);
        c[80 + k] = (double)(float)v;
    }
}

/* K_PRE: bitmask build + constants. */
__global__ __launch_bounds__(256) void k_pre(const float* __restrict__ x,
                                             u64* __restrict__ xbw,
                                             double* __restrict__ cst) {
    int blk = blockIdx.x;
    if (blk < NB_K1) {
        const int NTG = 5;
        int gw = (blk * 256 + (int)threadIdx.x) >> 6;
        int lane = threadIdx.x & 63;
        if (gw >= BB * NWRD * NTG) return;
        int b  = gw / (NWRD * NTG);
        int r  = gw % (NWRD * NTG);
        int fw = r / NTG;
        int tg = r % NTG;
        int t = tg * 64 + lane;
        bool act = (t < TT);
        int tc = act ? t : 0;
        const float* xp = x + ((size_t)(b * F1 + (fw << 6))) * TT + tc;
        unsigned lo = 0, hi = 0;
        #pragma unroll
        for (int j = 0; j < 32; ++j)
            lo |= (xp[(size_t)j * TT] > 0.5f ? 1u : 0u) << j;
        #pragma unroll
        for (int j = 0; j < 32; ++j)
            hi |= (xp[(size_t)(j + 32) * TT] > 0.5f ? 1u : 0u) << j;
        u64 mval = act ? (((u64)hi << 32) | lo) : 0ull;
        xbw[(size_t)fw * NPAD + b * 320 + t] = mval;
    } else {
        int k = threadIdx.x;
        if (k < KSRM) {
            double v = ((double)k / 10.0) * exp(1.0 - (double)k / 10.0);
            cst[k] = (double)(float)v;
        }
        if (k < KREF) {
            double v = -20.0 * (double)k * exp(1.0 - (double)k);
            cst[80 + k] = (double)(float)v;
        }
    }
}

/* quantize 4 floats -> 4 digit-dwords (byte e of dw[d] = digit d of float e).
   fp32 path: f*2^31 is a power-of-two scale (EXACT), rintf == fp64 rint. */
__device__ __forceinline__ void quant4(float4 f, unsigned dw[4]) {
    float ff[4] = {f.x, f.y, f.z, f.w};
    dw[0] = 0; dw[1] = 0; dw[2] = 0; dw[3] = 0;
    #pragma unroll
    for (int e = 0; e < 4; ++e) {
        int v  = (int)rintf(ff[e] * 2147483648.0f);
        int r0 = (v + 128) >> 8;
        int r1 = (r0 + 128) >> 8;
        int r2 = (r1 + 128) >> 8;
        dw[0] |= (unsigned)(v  & 0xFF) << (8 * e);
        dw[1] |= (unsigned)(r0 & 0xFF) << (8 * e);
        dw[2] |= (unsigned)(r1 & 0xFF) << (8 * e);
        dw[3] |= (unsigned)(r2 & 0xFF) << (8 * e);
    }
}

/* unpack 16 mask bits -> 16 i8 + 8 MFMAs (2 o-halves x 4 digits) */
#define K3_TILE(BV, TTI)                                                           \
    {                                                                              \
        i32x4 bf;                                                                  \
        _Pragma("unroll")                                                          \
        for (int i_ = 0; i_ < 4; ++i_)                                             \
            bf[i_] = (int)((((BV >> (4 * i_)) & 0xFu) * 0x00204081u) & 0x01010101u); \
        _Pragma("unroll")                                                          \
        for (int h_ = 0; h_ < 2; ++h_)                                             \
            _Pragma("unroll")                                                      \
            for (int d_ = 0; d_ < NDIG; ++d_)                                      \
                acc[TTI][h_][d_] = __builtin_amdgcn_mfma_i32_16x16x64_i8(          \
                    a[h_][d_], bf, acc[TTI][h_][d_], 0, 0, 0);                     \
    }

/* one pipeline iteration at compile-time roles: compute step S from
   buf[S&1] + BU regs; quantize floats(S+1)=FQ into buf[(S+1)&1]; issue
   float-load(S+2) into FI and B-load(S+1) into BL. */
#define K_ITER(S, FQ, FI, BU0, BU1, BU2, BU3, BU4, BL0, BL1, BL2, BL3, BL4)        \
    {                                                                              \
        int s_ = (S);                                                              \
        if (s_ < steps) {                                                          \
            int pf = s_ + 2; if (pf > steps - 1) pf = steps - 1;                   \
            FI = *(const float4*)(fbase + (size_t)pf * 64);                        \
            int sn = s_ + 1; if (sn > steps - 1) sn = steps - 1;                   \
            const unsigned short* bpn = bp0 + (size_t)sn * BSTRIDE;                \
            BL0 = bpn[0]; BL1 = bpn[64]; BL2 = bpn[128]; BL3 = bpn[192]; BL4 = bpn[256]; \
            const char* lp = &Abuf[s_ & 1][0];                                     \
            i32x4 a[2][4];                                                         \
            _Pragma("unroll")                                                      \
            for (int h_ = 0; h_ < 2; ++h_)                                         \
                _Pragma("unroll")                                                  \
                for (int d_ = 0; d_ < NDIG; ++d_)                                  \
                    a[h_][d_] = *(const i32x4*)(lp + h_ * 4096 + d_ * 1024 + lofs); \
            K3_TILE(BU0, 0)                                                        \
            K3_TILE(BU1, 1)                                                        \
            K3_TILE(BU2, 2)                                                        \
            K3_TILE(BU3, 3)                                                        \
            K3_TILE(BU4, 4)                                                        \
            unsigned dwq[4];                                                       \
            quant4(FQ, dwq);                                                       \
            char* wb = &Abuf[(s_ + 1) & 1][0] + wofs;                              \
            *(unsigned*)(wb)        = dwq[0];                                      \
            *(unsigned*)(wb + 1024) = dwq[1];                                      \
            *(unsigned*)(wb + 2048) = dwq[2];                                      \
            *(unsigned*)(wb + 3072) = dwq[3];                                      \
        }                                                                          \
        __syncthreads();                                                           \
    }

/* K3M2: exact i8 MFMA GEMM, M32 tile (32 o x 640 n): the per-step B-unpack
   (the dominant VALU cost) now feeds 8 MFMAs/tile instead of 4 — kernel-wide
   unpack work halves. Fused fp32 quantization; CSWZ both-sides LDS. */
__global__ __launch_bounds__(512, 2) void k3m2(const float* __restrict__ w1,
                                               const u64* __restrict__ xbw,
                                               u64* __restrict__ z1p) {
    __shared__ __align__(16) char Abuf[2][8192];
    int m32 = blockIdx.x, ksl = blockIdx.y;
    int tid = threadIdx.x;
    int l = tid & 63, wid = tid >> 6;          /* wid = n-slice 0..7 */
    int o  = tid >> 4;                         /* 0..31: my w1 row    */
    int kq = tid & 15;                         /* float4 index: k = 4*kq */

    int wl0 = ksl * WPS;
    int wend = wl0 + WPS; if (wend > NWRD) wend = NWRD;
    int steps = wend - wl0;          /* 98 or 93 */

    i32x4 acc[5][2][NDIG];
    #pragma unroll
    for (int i = 0; i < 5; ++i)
        #pragma unroll
        for (int h = 0; h < 2; ++h)
            #pragma unroll
            for (int d = 0; d < NDIG; ++d) acc[i][h][d] = (i32x4){0, 0, 0, 0};

    const float* fbase = w1 + (size_t)(m32 * 32 + o) * F1 + (size_t)wl0 * 64 + kq * 4;
    const unsigned short* bp0 =
        (const unsigned short*)((const char*)xbw
            + ((size_t)wl0 * NPAD
               + (size_t)(wid * 80 + (l & 15))) * 8
            + (l >> 4) * 2);
    const int lofs = CSWZ(l) * 16;
    const int wc = (kq >> 2) * 16 + (o & 15);
    const int wofs = (o >> 4) * 4096 + CSWZ(wc) * 16 + (kq & 3) * 4;

    float4 fA, fB, fC;
    unsigned bA0, bA1, bA2, bA3, bA4;
    unsigned bB0, bB1, bB2, bB3, bB4;
    unsigned bC0, bC1, bC2, bC3, bC4;

    /* prologue: quantize step 0 into buf0; prefetch floats(1); B(0) */
    fA = *(const float4*)(fbase);
    {
        unsigned dwq[4];
        quant4(fA, dwq);
        char* wb = &Abuf[0][0] + wofs;
        *(unsigned*)(wb)        = dwq[0];
        *(unsigned*)(wb + 1024) = dwq[1];
        *(unsigned*)(wb + 2048) = dwq[2];
        *(unsigned*)(wb + 3072) = dwq[3];
    }
    fB = *(const float4*)(fbase + ((steps > 1) ? 64 : 0));
    bA0 = bp0[0]; bA1 = bp0[64]; bA2 = bp0[128]; bA3 = bp0[192]; bA4 = bp0[256];
    __syncthreads();

    int smax3 = ((steps + 2) / 3) * 3;
    #pragma unroll 1
    for (int sb = 0; sb < smax3; sb += 3) {
        K_ITER(sb,     fB, fC, bA0, bA1, bA2, bA3, bA4, bB0, bB1, bB2, bB3, bB4)
        K_ITER(sb + 1, fC, fA, bB0, bB1, bB2, bB3, bB4, bC0, bC1, bC2, bC3, bC4)
        K_ITER(sb + 2, fA, fB, bC0, bC1, bC2, bC3, bC4, bA0, bA1, bA2, bA3, bA4)
    }

    /* atomic-free epilogue: plain stores into this ksplit's partial plane */
    u64* zp = z1p + (size_t)ksl * O1 * NPAD;
    #pragma unroll
    for (int tt = 0; tt < 5; ++tt) {
        int n = wid * 80 + tt * 16 + (l & 15);
        #pragma unroll
        for (int h = 0; h < 2; ++h) {
            #pragma unroll
            for (int r = 0; r < 4; ++r) {
                int oo = m32 * 32 + h * 16 + (l >> 4) * 4 + r;
                long long c = (long long)acc[tt][h][0][r]
                            + ((long long)acc[tt][h][1][r] << 8)
                            + ((long long)acc[tt][h][2][r] << 16)
                            + ((long long)acc[tt][h][3][r] << 24);
                zp[(size_t)oo * NPAD + n] = (u64)c;
            }
        }
    }
}

/* dense fallback GEMM1 (used only if ws too small) -> z1f fp64 */
__global__ __launch_bounds__(256) void k_dense_gemm1(const float* __restrict__ x,
                                                     const float* __restrict__ w1,
                                                     double* __restrict__ z1) {
    int lin = blockIdx.x;
    int ot = lin % 25; int tt = (lin / 25) % 5; int b = lin / 125;
    int t0 = tt * 64, o0 = ot * 32;
    __shared__ float xs[64][64];
    __shared__ float wsh[32][64];
    int ti = threadIdx.x & 63, og = threadIdx.x >> 6;
    double dacc[8] = {0, 0, 0, 0, 0, 0, 0, 0};
    for (int fc = 0; fc < F1; fc += 64) {
        __syncthreads();
        for (int e = threadIdx.x; e < 64 * 64; e += 256) {
            int r = e >> 6, c = e & 63;
            int t = t0 + c;
            xs[r][c] = (t < TT) ? x[((size_t)b * F1 + fc + r) * TT + t] : 0.0f;
        }
        for (int e = threadIdx.x; e < 32 * 64; e += 256) {
            int r = e >> 6, c = e & 63;
            wsh[r][c] = w1[(size_t)(o0 + r) * F1 + fc + c];
        }
        __syncthreads();
        float facc[8] = {0, 0, 0, 0, 0, 0, 0, 0};
        for (int ff = 0; ff < 64; ++ff) {
            float xv = xs[ff][ti];
            #pragma unroll
            for (int oo = 0; oo < 8; ++oo) facc[oo] += wsh[og * 8 + oo][ff] * xv;
        }
        #pragma unroll
        for (int oo = 0; oo < 8; ++oo) dacc[oo] += (double)facc[oo];
    }
    int t = t0 + ti;
    if (t < TT) {
        #pragma unroll
        for (int oo = 0; oo < 8; ++oo) {
            int o = o0 + og * 8 + oo;
            z1[((size_t)(b * O1 + o)) * TT + t] = dacc[oo];
        }
    }
}

/* K_CONV1: exact i64 partial-sum + scale + psp conv (t-parallel). */
__global__ __launch_bounds__(320) void k_conv1(const u64* __restrict__ z1p,
                                               const double* __restrict__ z1f,
                                               double* __restrict__ u1,
                                               const double* __restrict__ cst,
                                               int mode) {
    __shared__ double zs[TT];
    __shared__ double ck[KSRM];
    int row = blockIdx.x;                 /* b*800 + o */
    int b = row / O1, o = row % O1;
    int t = threadIdx.x;
    if (t < KSRM) ck[t] = cst[t];
    if (t < TT) {
        double z;
        if (mode == 0) {
            long long c = 0;
            size_t base = (size_t)o * NPAD + b * 320 + t;
            #pragma unroll
            for (int g = 0; g < KSPL; ++g)
                c += (long long)z1p[(size_t)g * O1 * NPAD + base];
            z = (double)c * 4.656612873077393e-10;          /* 2^-31 */
        } else {
            z = z1f[(size_t)row * TT + t];
        }
        zs[t] = z;
    }
    __syncthreads();
    if (t < TT) {
        int kmax = t < (KSRM - 1) ? t : (KSRM - 1);
        double acc = 0.0;
        for (int k = 0; k <= kmax; ++k) acc += ck[k] * zs[t - k];
        u1[(size_t)row * TT + t] = acc;
    }
}

/* K_SCAN: thread-per-row spike scan, 30-deep register load pipeline. */
__global__ __launch_bounds__(64) void k_scan(const double* __restrict__ u,
                                             float* __restrict__ s,
                                             const double* __restrict__ cst,
                                             int nrows) {
    int row = blockIdx.x * 64 + threadIdx.x;
    if (row >= nrows) return;
    double rk1 = cst[81], rk2 = cst[82], rk3 = cst[83], rk4 = cst[84];
    double rk5 = cst[85], rk6 = cst[86], rk7 = cst[87], rk8 = cst[88];
    double rk9 = cst[89], rk10 = cst[90];
    const double* ur = u + (size_t)row * TT;
    float* sr = s + (size_t)row * TT;
    double buf[30];
    #pragma unroll
    for (int j = 0; j < 30; ++j) buf[j] = ur[j];
    unsigned h = 0;
    #pragma unroll 1
    for (int tb = 0; tb < TT; tb += 30) {          /* 10 iterations */
        double nxt[30];
        #pragma unroll
        for (int j = 0; j < 30; ++j) {
            int tn = tb + 30 + j; if (tn > TT - 1) tn = TT - 1;
            nxt[j] = ur[tn];                       /* independent prefetch */
        }
        #pragma unroll
        for (int j = 0; j < 30; ++j) {
            double a  = ((h & 1u)   ? rk1 : 0.0) + ((h & 2u)   ? rk2  : 0.0);
            double b2 = ((h & 4u)   ? rk3 : 0.0) + ((h & 8u)   ? rk4  : 0.0);
            double c2 = ((h & 16u)  ? rk5 : 0.0) + ((h & 32u)  ? rk6  : 0.0);
            double d2 = ((h & 64u)  ? rk7 : 0.0) + ((h & 128u) ? rk8  : 0.0);
            double e2 = ((h & 256u) ? rk9 : 0.0) + ((h & 512u) ? rk10 : 0.0);
            double ueff = buf[j] + (((a + b2) + (c2 + d2)) + e2);
            unsigned sp = (ueff >= 10.0) ? 1u : 0u;
            sr[tb + j] = (float)sp;
            h = (h << 1) | sp;
        }
        #pragma unroll
        for (int j = 0; j < 30; ++j) buf[j] = nxt[j];
    }
}

/* K_GEMM2C: fused GEMM2 + psp conv for layer 2 (both t-parallel). */
__global__ __launch_bounds__(320) void k_gemm2c(const float* __restrict__ s1t,
                                                const float* __restrict__ w2,
                                                double* __restrict__ u2,
                                                const double* __restrict__ cst) {
    __shared__ float wsm[O1];
    __shared__ double zs[TT];
    __shared__ double ck[KSRM];
    int bo = blockIdx.x;
    int b = bo / O2N, o2 = bo % O2N;
    int t = threadIdx.x;
    if (t < KSRM) ck[t] = cst[t];
    for (int f = t; f < O1; f += 320) wsm[f] = w2[(size_t)o2 * O1 + f];
    __syncthreads();
    if (t < TT) {
        double acc = 0.0;
        #pragma unroll 4
        for (int f = 0; f < O1; ++f)
            acc += (double)(wsm[f] * s1t[((size_t)(b * O1 + f)) * TT + t]);
        zs[t] = acc;
    }
    __syncthreads();
    if (t < TT) {
        int kmax = t < (KSRM - 1) ? t : (KSRM - 1);
        double acc = 0.0;
        for (int k = 0; k <= kmax; ++k) acc += ck[k] * zs[t - k];
        u2[(size_t)bo * TT + t] = acc;
    }
}

extern "C" void kernel_launch(void* const* d_in, const int* in_sizes, int n_in,
                              void* d_out, int out_size, void* d_ws, size_t ws_size,
                              hipStream_t stream) {
    const float* x  = (const float*)d_in[0];
    const float* w1 = (const float*)d_in[1];
    const float* w2 = (const float*)d_in[2];
    float* out = (float*)d_out;
    char* ws = (char*)d_ws;

    double* cst = (double*)(ws + OFF_CONST);
    u64*    z1p = (u64*)   (ws + OFF_Z1P);
    float*  s1t = (float*) (ws + OFF_S1T);
    u64*    xbw = (u64*)   (ws + OFF_XBW);
    double* z1f = (double*)(ws + OFF_Z1F);
    double* u1  = (double*)(ws + OFF_U1);
    double* u2  = (double*)(ws + OFF_U2);

    int mode;
    if (ws_size >= NEED_SPARSE) {
        mode = 0;
        k_pre<<<NB_K1 + 1, 256, 0, stream>>>(x, xbw, cst);
        k3m2<<<dim3(M32, KSPL), 512, 0, stream>>>(w1, xbw, z1p);
    } else {
        mode = 1;
        k0_init<<<1, 128, 0, stream>>>(cst);
        k_dense_gemm1<<<250, 256, 0, stream>>>(x, w1, z1f);
    }

    k_conv1<<<BB * O1, 320, 0, stream>>>(z1p, z1f, u1, cst, mode);
    k_scan<<<(BB * O1 + 63) / 64, 64, 0, stream>>>(u1, s1t, cst, BB * O1);
    k_gemm2c<<<BB * O2N, 320, 0, stream>>>(s1t, w2, u2, cst);
    k_scan<<<(BB * O2N + 63) / 64, 64, 0, stream>>>(u2, out, cst, BB * O2N);
    (void)in_sizes; (void)n_in; (void)out_size;
}

// Round 26
// 257.383 us; speedup vs baseline: 1.8334x; 1.0502x over previous
//
#include <hip/hip_runtime.h>

#define F1 62400
#define O1 800
#define O2N 100
#define TT 300
#define BB 2
#define NWRD 975        /* 64-bit f-words */
#define KSRM 77
#define KREF 11
#define M32 25          /* M-blocks of 32 o */
#define NPAD 640        /* n = b*320 + t */
#define NDIG 4          /* base-256 digits of rint(w1 * 2^31) — exact (R4-proven) */
#define KSPL 20         /* k-splits (500 blocks = 2/CU) */
#define WPS 49          /* words per split (last split: 44) */
#define BSTRIDE ((size_t)NPAD * 4)

/* k_pre grid partition */
#define NB_K1 2438      /* ceil(2*975*5*64 / 256) */

typedef unsigned long long u64;
typedef int i32x4 __attribute__((ext_vector_type(4)));

/* chunk swizzle (T2, both-sides): bijective within each 16-chunk group */
#define CSWZ(c) ((c) ^ ((((c) >> 4) & 3) << 1))

/* ---- ws layout (bytes); NEED ~97 MB ---- */
#define OFF_CONST 0ull
#define OFF_Z1P  1024ull                          /* 20*800*640*8 = 81,920,000 */
#define OFF_S1T  (OFF_Z1P + 81920000ull)          /* 2*320*800*4 = 2,048,000 (t-major) */
#define OFF_XBW  (OFF_S1T + 2048000ull)           /* 975*640*8 (320-stride, pad 0) */
#define OFF_Z1F  (OFF_XBW + 4992000ull)
#define OFF_U1   (OFF_Z1F + 3840000ull)
#define OFF_U2   (OFF_U1 + 3840000ull)
#define NEED_SPARSE (OFF_U2 + 480000ull)          /* ~97.1 MB */

/* K0: SRM/REF kernels, fp64 rounded through fp32 (fallback path only). */
__global__ void k0_init(double* c) {
    int k = threadIdx.x;
    if (k < KSRM) {
        double v = ((double)k / 10.0) * exp(1.0 - (double)k / 10.0);
        c[k] = (double)(float)v;
    }
    if (k < KREF) {
        double v = -20.0 * (double)k * exp(1.0 - (double)k);
        c[80 + k] = (double)(float)v;
    }
}

/* K_PRE: bitmask build + constants. */
__global__ __launch_bounds__(256) void k_pre(const float* __restrict__ x,
                                             u64* __restrict__ xbw,
                                             double* __restrict__ cst) {
    int blk = blockIdx.x;
    if (blk < NB_K1) {
        const int NTG = 5;
        int gw = (blk * 256 + (int)threadIdx.x) >> 6;
        int lane = threadIdx.x & 63;
        if (gw >= BB * NWRD * NTG) return;
        int b  = gw / (NWRD * NTG);
        int r  = gw % (NWRD * NTG);
        int fw = r / NTG;
        int tg = r % NTG;
        int t = tg * 64 + lane;
        bool act = (t < TT);
        int tc = act ? t : 0;
        const float* xp = x + ((size_t)(b * F1 + (fw << 6))) * TT + tc;
        unsigned lo = 0, hi = 0;
        #pragma unroll
        for (int j = 0; j < 32; ++j)
            lo |= (xp[(size_t)j * TT] > 0.5f ? 1u : 0u) << j;
        #pragma unroll
        for (int j = 0; j < 32; ++j)
            hi |= (xp[(size_t)(j + 32) * TT] > 0.5f ? 1u : 0u) << j;
        u64 mval = act ? (((u64)hi << 32) | lo) : 0ull;
        xbw[(size_t)fw * NPAD + b * 320 + t] = mval;
    } else {
        int k = threadIdx.x;
        if (k < KSRM) {
            double v = ((double)k / 10.0) * exp(1.0 - (double)k / 10.0);
            cst[k] = (double)(float)v;
        }
        if (k < KREF) {
            double v = -20.0 * (double)k * exp(1.0 - (double)k);
            cst[80 + k] = (double)(float)v;
        }
    }
}

/* quantize 4 floats -> 4 digit-dwords. fp32 path exact (power-of-two scale). */
__device__ __forceinline__ void quant4(float4 f, unsigned dw[4]) {
    float ff[4] = {f.x, f.y, f.z, f.w};
    dw[0] = 0; dw[1] = 0; dw[2] = 0; dw[3] = 0;
    #pragma unroll
    for (int e = 0; e < 4; ++e) {
        int v  = (int)rintf(ff[e] * 2147483648.0f);
        int r0 = (v + 128) >> 8;
        int r1 = (r0 + 128) >> 8;
        int r2 = (r1 + 128) >> 8;
        dw[0] |= (unsigned)(v  & 0xFF) << (8 * e);
        dw[1] |= (unsigned)(r0 & 0xFF) << (8 * e);
        dw[2] |= (unsigned)(r1 & 0xFF) << (8 * e);
        dw[3] |= (unsigned)(r2 & 0xFF) << (8 * e);
    }
}

/* unpack 16 mask bits -> 16 i8 + 8 MFMAs (2 o-halves x 4 digits) */
#define K3_TILE(BV, TTI)                                                           \
    {                                                                              \
        i32x4 bf;                                                                  \
        _Pragma("unroll")                                                          \
        for (int i_ = 0; i_ < 4; ++i_)                                             \
            bf[i_] = (int)((((BV >> (4 * i_)) & 0xFu) * 0x00204081u) & 0x01010101u); \
        _Pragma("unroll")                                                          \
        for (int h_ = 0; h_ < 2; ++h_)                                             \
            _Pragma("unroll")                                                      \
            for (int d_ = 0; d_ < NDIG; ++d_)                                      \
                acc[TTI][h_][d_] = __builtin_amdgcn_mfma_i32_16x16x64_i8(          \
                    a[h_][d_], bf, acc[TTI][h_][d_], 0, 0, 0);                     \
    }

#define K_ITER(S, FQ, FI, BU0, BU1, BU2, BU3, BU4, BL0, BL1, BL2, BL3, BL4)        \
    {                                                                              \
        int s_ = (S);                                                              \
        if (s_ < steps) {                                                          \
            int pf = s_ + 2; if (pf > steps - 1) pf = steps - 1;                   \
            FI = *(const float4*)(fbase + (size_t)pf * 64);                        \
            int sn = s_ + 1; if (sn > steps - 1) sn = steps - 1;                   \
            const unsigned short* bpn = bp0 + (size_t)sn * BSTRIDE;                \
            BL0 = bpn[0]; BL1 = bpn[64]; BL2 = bpn[128]; BL3 = bpn[192]; BL4 = bpn[256]; \
            const char* lp = &Abuf[s_ & 1][0];                                     \
            i32x4 a[2][4];                                                         \
            _Pragma("unroll")                                                      \
            for (int h_ = 0; h_ < 2; ++h_)                                         \
                _Pragma("unroll")                                                  \
                for (int d_ = 0; d_ < NDIG; ++d_)                                  \
                    a[h_][d_] = *(const i32x4*)(lp + h_ * 4096 + d_ * 1024 + lofs); \
            K3_TILE(BU0, 0)                                                        \
            K3_TILE(BU1, 1)                                                        \
            K3_TILE(BU2, 2)                                                        \
            K3_TILE(BU3, 3)                                                        \
            K3_TILE(BU4, 4)                                                        \
            unsigned dwq[4];                                                       \
            quant4(FQ, dwq);                                                       \
            char* wb = &Abuf[(s_ + 1) & 1][0] + wofs;                              \
            *(unsigned*)(wb)        = dwq[0];                                      \
            *(unsigned*)(wb + 1024) = dwq[1];                                      \
            *(unsigned*)(wb + 2048) = dwq[2];                                      \
            *(unsigned*)(wb + 3072) = dwq[3];                                      \
        }                                                                          \
        __syncthreads();                                                           \
    }

/* K3M2: exact i8 MFMA GEMM, M32 tile, fused fp32 quantization (R25-proven).
   KSPL=20 -> 500 blocks = 2/CU for cross-block latency hiding. */
__global__ __launch_bounds__(512, 2) void k3m2(const float* __restrict__ w1,
                                               const u64* __restrict__ xbw,
                                               u64* __restrict__ z1p) {
    __shared__ __align__(16) char Abuf[2][8192];
    int m32 = blockIdx.x, ksl = blockIdx.y;
    int tid = threadIdx.x;
    int l = tid & 63, wid = tid >> 6;
    int o  = tid >> 4;
    int kq = tid & 15;

    int wl0 = ksl * WPS;
    int wend = wl0 + WPS; if (wend > NWRD) wend = NWRD;
    int steps = wend - wl0;          /* 49 or 44 */

    i32x4 acc[5][2][NDIG];
    #pragma unroll
    for (int i = 0; i < 5; ++i)
        #pragma unroll
        for (int h = 0; h < 2; ++h)
            #pragma unroll
            for (int d = 0; d < NDIG; ++d) acc[i][h][d] = (i32x4){0, 0, 0, 0};

    const float* fbase = w1 + (size_t)(m32 * 32 + o) * F1 + (size_t)wl0 * 64 + kq * 4;
    const unsigned short* bp0 =
        (const unsigned short*)((const char*)xbw
            + ((size_t)wl0 * NPAD
               + (size_t)(wid * 80 + (l & 15))) * 8
            + (l >> 4) * 2);
    const int lofs = CSWZ(l) * 16;
    const int wc = (kq >> 2) * 16 + (o & 15);
    const int wofs = (o >> 4) * 4096 + CSWZ(wc) * 16 + (kq & 3) * 4;

    float4 fA, fB, fC;
    unsigned bA0, bA1, bA2, bA3, bA4;
    unsigned bB0, bB1, bB2, bB3, bB4;
    unsigned bC0, bC1, bC2, bC3, bC4;

    fA = *(const float4*)(fbase);
    {
        unsigned dwq[4];
        quant4(fA, dwq);
        char* wb = &Abuf[0][0] + wofs;
        *(unsigned*)(wb)        = dwq[0];
        *(unsigned*)(wb + 1024) = dwq[1];
        *(unsigned*)(wb + 2048) = dwq[2];
        *(unsigned*)(wb + 3072) = dwq[3];
    }
    fB = *(const float4*)(fbase + ((steps > 1) ? 64 : 0));
    bA0 = bp0[0]; bA1 = bp0[64]; bA2 = bp0[128]; bA3 = bp0[192]; bA4 = bp0[256];
    __syncthreads();

    int smax3 = ((steps + 2) / 3) * 3;
    #pragma unroll 1
    for (int sb = 0; sb < smax3; sb += 3) {
        K_ITER(sb,     fB, fC, bA0, bA1, bA2, bA3, bA4, bB0, bB1, bB2, bB3, bB4)
        K_ITER(sb + 1, fC, fA, bB0, bB1, bB2, bB3, bB4, bC0, bC1, bC2, bC3, bC4)
        K_ITER(sb + 2, fA, fB, bC0, bC1, bC2, bC3, bC4, bA0, bA1, bA2, bA3, bA4)
    }

    u64* zp = z1p + (size_t)ksl * O1 * NPAD;
    #pragma unroll
    for (int tt = 0; tt < 5; ++tt) {
        int n = wid * 80 + tt * 16 + (l & 15);
        #pragma unroll
        for (int h = 0; h < 2; ++h) {
            #pragma unroll
            for (int r = 0; r < 4; ++r) {
                int oo = m32 * 32 + h * 16 + (l >> 4) * 4 + r;
                long long c = (long long)acc[tt][h][0][r]
                            + ((long long)acc[tt][h][1][r] << 8)
                            + ((long long)acc[tt][h][2][r] << 16)
                            + ((long long)acc[tt][h][3][r] << 24);
                zp[(size_t)oo * NPAD + n] = (u64)c;
            }
        }
    }
}

/* dense fallback GEMM1 (used only if ws too small) -> z1f fp64 */
__global__ __launch_bounds__(256) void k_dense_gemm1(const float* __restrict__ x,
                                                     const float* __restrict__ w1,
                                                     double* __restrict__ z1) {
    int lin = blockIdx.x;
    int ot = lin % 25; int tt = (lin / 25) % 5; int b = lin / 125;
    int t0 = tt * 64, o0 = ot * 32;
    __shared__ float xs[64][64];
    __shared__ float wsh[32][64];
    int ti = threadIdx.x & 63, og = threadIdx.x >> 6;
    double dacc[8] = {0, 0, 0, 0, 0, 0, 0, 0};
    for (int fc = 0; fc < F1; fc += 64) {
        __syncthreads();
        for (int e = threadIdx.x; e < 64 * 64; e += 256) {
            int r = e >> 6, c = e & 63;
            int t = t0 + c;
            xs[r][c] = (t < TT) ? x[((size_t)b * F1 + fc + r) * TT + t] : 0.0f;
        }
        for (int e = threadIdx.x; e < 32 * 64; e += 256) {
            int r = e >> 6, c = e & 63;
            wsh[r][c] = w1[(size_t)(o0 + r) * F1 + fc + c];
        }
        __syncthreads();
        float facc[8] = {0, 0, 0, 0, 0, 0, 0, 0};
        for (int ff = 0; ff < 64; ++ff) {
            float xv = xs[ff][ti];
            #pragma unroll
            for (int oo = 0; oo < 8; ++oo) facc[oo] += wsh[og * 8 + oo][ff] * xv;
        }
        #pragma unroll
        for (int oo = 0; oo < 8; ++oo) dacc[oo] += (double)facc[oo];
    }
    int t = t0 + ti;
    if (t < TT) {
        #pragma unroll
        for (int oo = 0; oo < 8; ++oo) {
            int o = o0 + og * 8 + oo;
            z1[((size_t)(b * O1 + o)) * TT + t] = dacc[oo];
        }
    }
}

/* K_CONV1: exact i64 partial-sum (20 planes) + scale + psp conv. */
__global__ __launch_bounds__(320) void k_conv1(const u64* __restrict__ z1p,
                                               const double* __restrict__ z1f,
                                               double* __restrict__ u1,
                                               const double* __restrict__ cst,
                                               int mode) {
    __shared__ double zs[TT];
    __shared__ double ck[KSRM];
    int row = blockIdx.x;                 /* b*800 + o */
    int b = row / O1, o = row % O1;
    int t = threadIdx.x;
    if (t < KSRM) ck[t] = cst[t];
    if (t < TT) {
        double z;
        if (mode == 0) {
            long long c = 0;
            size_t base = (size_t)o * NPAD + b * 320 + t;
            #pragma unroll
            for (int g = 0; g < KSPL; ++g)
                c += (long long)z1p[(size_t)g * O1 * NPAD + base];
            z = (double)c * 4.656612873077393e-10;          /* 2^-31 */
        } else {
            z = z1f[(size_t)row * TT + t];
        }
        zs[t] = z;
    }
    __syncthreads();
    if (t < TT) {
        int kmax = t < (KSRM - 1) ? t : (KSRM - 1);
        double acc = 0.0;
        for (int k = 0; k <= kmax; ++k) acc += ck[k] * zs[t - k];
        u1[(size_t)row * TT + t] = acc;
    }
}

/* K_SCAN: thread-per-row spike scan, 30-deep register load pipeline.
   tmode=1 (layer1): write t-major s1t[(b*320+t)*800 + f] — coalesced lanes.
   tmode=0 (layer2): write row-major out[row*300 + t]. */
__global__ __launch_bounds__(64) void k_scan(const double* __restrict__ u,
                                             float* __restrict__ s,
                                             const double* __restrict__ cst,
                                             int nrows, int tmode) {
    int row = blockIdx.x * 64 + threadIdx.x;
    if (row >= nrows) return;
    double rk1 = cst[81], rk2 = cst[82], rk3 = cst[83], rk4 = cst[84];
    double rk5 = cst[85], rk6 = cst[86], rk7 = cst[87], rk8 = cst[88];
    double rk9 = cst[89], rk10 = cst[90];
    const double* ur = u + (size_t)row * TT;
    float* sbase;
    size_t sstep;
    if (tmode) {
        int b = (row >= O1) ? 1 : 0;
        int f = row - b * O1;
        sbase = s + (size_t)(b * 320) * O1 + f;   /* + t*800 per step */
        sstep = O1;
    } else {
        sbase = s + (size_t)row * TT;             /* + t per step */
        sstep = 1;
    }
    double buf[30];
    #pragma unroll
    for (int j = 0; j < 30; ++j) buf[j] = ur[j];
    unsigned h = 0;
    #pragma unroll 1
    for (int tb = 0; tb < TT; tb += 30) {
        double nxt[30];
        #pragma unroll
        for (int j = 0; j < 30; ++j) {
            int tn = tb + 30 + j; if (tn > TT - 1) tn = TT - 1;
            nxt[j] = ur[tn];
        }
        #pragma unroll
        for (int j = 0; j < 30; ++j) {
            double a  = ((h & 1u)   ? rk1 : 0.0) + ((h & 2u)   ? rk2  : 0.0);
            double b2 = ((h & 4u)   ? rk3 : 0.0) + ((h & 8u)   ? rk4  : 0.0);
            double c2 = ((h & 16u)  ? rk5 : 0.0) + ((h & 32u)  ? rk6  : 0.0);
            double d2 = ((h & 64u)  ? rk7 : 0.0) + ((h & 128u) ? rk8  : 0.0);
            double e2 = ((h & 256u) ? rk9 : 0.0) + ((h & 512u) ? rk10 : 0.0);
            double ueff = buf[j] + (((a + b2) + (c2 + d2)) + e2);
            unsigned sp = (ueff >= 10.0) ? 1u : 0u;
            sbase[(size_t)(tb + j) * sstep] = (float)sp;
            h = (h << 1) | sp;
        }
        #pragma unroll
        for (int j = 0; j < 30; ++j) buf[j] = nxt[j];
    }
}

/* K_GEMM2C: fused GEMM2 + psp conv. s1t is t-major -> contiguous float4
   reads per thread; accumulation order f=0..799 unchanged (bit-identical). */
__global__ __launch_bounds__(320) void k_gemm2c(const float* __restrict__ s1t,
                                                const float* __restrict__ w2,
                                                double* __restrict__ u2,
                                                const double* __restrict__ cst) {
    __shared__ float wsm[O1];
    __shared__ double zs[TT];
    __shared__ double ck[KSRM];
    int bo = blockIdx.x;
    int b = bo / O2N, o2 = bo % O2N;
    int t = threadIdx.x;
    if (t < KSRM) ck[t] = cst[t];
    for (int f = t; f < O1; f += 320) wsm[f] = w2[(size_t)o2 * O1 + f];
    __syncthreads();
    if (t < TT) {
        const float4* sp = (const float4*)(s1t + (size_t)(b * 320 + t) * O1);
        double acc = 0.0;
        #pragma unroll 4
        for (int ff = 0; ff < O1 / 4; ++ff) {
            float4 v = sp[ff];
            acc += (double)(wsm[4 * ff]     * v.x);
            acc += (double)(wsm[4 * ff + 1] * v.y);
            acc += (double)(wsm[4 * ff + 2] * v.z);
            acc += (double)(wsm[4 * ff + 3] * v.w);
        }
        zs[t] = acc;
    }
    __syncthreads();
    if (t < TT) {
        int kmax = t < (KSRM - 1) ? t : (KSRM - 1);
        double acc = 0.0;
        for (int k = 0; k <= kmax; ++k) acc += ck[k] * zs[t - k];
        u2[(size_t)bo * TT + t] = acc;
    }
}

extern "C" void kernel_launch(void* const* d_in, const int* in_sizes, int n_in,
                              void* d_out, int out_size, void* d_ws, size_t ws_size,
                              hipStream_t stream) {
    const float* x  = (const float*)d_in[0];
    const float* w1 = (const float*)d_in[1];
    const float* w2 = (const float*)d_in[2];
    float* out = (float*)d_out;
    char* ws = (char*)d_ws;

    double* cst = (double*)(ws + OFF_CONST);
    u64*    z1p = (u64*)   (ws + OFF_Z1P);
    float*  s1t = (float*) (ws + OFF_S1T);
    u64*    xbw = (u64*)   (ws + OFF_XBW);
    double* z1f = (double*)(ws + OFF_Z1F);
    double* u1  = (double*)(ws + OFF_U1);
    double* u2  = (double*)(ws + OFF_U2);

    int mode;
    if (ws_size >= NEED_SPARSE) {
        mode = 0;
        k_pre<<<NB_K1 + 1, 256, 0, stream>>>(x, xbw, cst);
        k3m2<<<dim3(M32, KSPL), 512, 0, stream>>>(w1, xbw, z1p);
    } else {
        mode = 1;
        k0_init<<<1, 128, 0, stream>>>(cst);
        k_dense_gemm1<<<250, 256, 0, stream>>>(x, w1, z1f);
    }

    k_conv1<<<BB * O1, 320, 0, stream>>>(z1p, z1f, u1, cst, mode);
    k_scan<<<(BB * O1 + 63) / 64, 64, 0, stream>>>(u1, s1t, cst, BB * O1, 1);
    k_gemm2c<<<BB * O2N, 320, 0, stream>>>(s1t, w2, u2, cst);
    k_scan<<<(BB * O2N + 63) / 64, 64, 0, stream>>>(u2, out, cst, BB * O2N, 0);
    (void)in_sizes; (void)n_in; (void)out_size;
}